// Round 1
// baseline (6762.918 us; speedup 1.0000x reference)
//
#include <hip/hip_runtime.h>
#include <math.h>

constexpr int Bn = 16;
constexpr int Sn = 512;
constexpr int FCn = 24;
constexpr int FOn = 16;
constexpr int Dn = 512;
constexpr int Hn = 8;
constexpr int DKn = 64;
constexpr int FFn = 2048;
constexpr int Ln = 4;
constexpr int MAXPOSn = 512;
constexpr float EPSf = 1e-6f;

__device__ __forceinline__ float sigmoidf_(float x) { return 1.0f / (1.0f + __expf(-x)); }

__device__ __forceinline__ float blockReduceSum(float v) {
  #pragma unroll
  for (int off = 32; off >= 1; off >>= 1) v += __shfl_xor(v, off);
  __shared__ float red[8];
  const int w = threadIdx.x >> 6;
  const int nw = blockDim.x >> 6;
  if ((threadIdx.x & 63) == 0) red[w] = v;
  __syncthreads();
  float r = 0.0f;
  for (int i = 0; i < nw; ++i) r += red[i];
  __syncthreads();
  return r;
}

// x = x_cgm @ cgm_W + cgm_b   [8192,24]@[24,512]
__global__ __launch_bounds__(256) void embed_kernel(
    const float* __restrict__ xc, const float* __restrict__ W,
    const float* __restrict__ bias, float* __restrict__ x) {
  const int idx = blockIdx.x * 256 + threadIdx.x;
  const int n = idx & (Dn - 1);
  const int m = idx >> 9;
  const float* xr = xc + m * FCn;
  float acc = bias[n];
  #pragma unroll
  for (int k = 0; k < FCn; ++k) acc = fmaf(xr[k], W[k * Dn + n], acc);
  x[idx] = acc;
}

// rel_mean[p] = mean_d rel_emb[p][d]
__global__ void relmean_kernel(const float* __restrict__ rel, float* __restrict__ rm) {
  const int p = blockIdx.x * blockDim.x + threadIdx.x;
  if (p >= 2 * MAXPOSn - 1) return;
  float s = 0.0f;
  #pragma unroll 8
  for (int d = 0; d < DKn; ++d) s += rel[p * DKn + d];
  rm[p] = s * (1.0f / DKn);
}

// C[M,N] = epilogue(A[M,K] @ W[K,N] + bias) ; ACT: 0=none, 1=sigmoid, 2=C*=sigmoid(acc+bias)
// 128x128 tile, BK=16, 8x8/thread in 2x2 sub-blocks (stride-64 split keeps LDS reads 2-way max).
template <int ACT>
__global__ __launch_bounds__(256) void gemm_kernel(
    const float* __restrict__ A, const float* __restrict__ W,
    const float* __restrict__ bias, float* __restrict__ C,
    int M, int N, int K) {
  __shared__ float As[16][132];  // k-major: As[kk][mm], pad 4 keeps 16B alignment
  __shared__ float Ws[16][132];
  const int t = threadIdx.x;
  const int n0 = blockIdx.x * 128;
  const int m0 = blockIdx.y * 128;
  const int tx = t & 15;
  const int ty = t >> 4;

  float acc[8][8];
  #pragma unroll
  for (int i = 0; i < 8; ++i)
    #pragma unroll
    for (int j = 0; j < 8; ++j) acc[i][j] = 0.0f;

  const int amm = t >> 2;           // 0..63
  const int akk = (t & 3) * 4;      // 0,4,8,12
  const int wkk = t >> 5;           // 0..7
  const int wnn = (t & 31) * 4;     // 0..124

  for (int k0 = 0; k0 < K; k0 += 16) {
    float4 av0 = *(const float4*)&A[(size_t)(m0 + amm) * K + k0 + akk];
    float4 av1 = *(const float4*)&A[(size_t)(m0 + amm + 64) * K + k0 + akk];
    float4 wv0 = *(const float4*)&W[(size_t)(k0 + wkk) * N + n0 + wnn];
    float4 wv1 = *(const float4*)&W[(size_t)(k0 + wkk + 8) * N + n0 + wnn];
    __syncthreads();  // previous tile fully consumed before overwrite
    As[akk + 0][amm] = av0.x; As[akk + 1][amm] = av0.y;
    As[akk + 2][amm] = av0.z; As[akk + 3][amm] = av0.w;
    As[akk + 0][amm + 64] = av1.x; As[akk + 1][amm + 64] = av1.y;
    As[akk + 2][amm + 64] = av1.z; As[akk + 3][amm + 64] = av1.w;
    *(float4*)&Ws[wkk][wnn] = wv0;
    *(float4*)&Ws[wkk + 8][wnn] = wv1;
    __syncthreads();
    #pragma unroll
    for (int kk = 0; kk < 16; ++kk) {
      float4 a0 = *(const float4*)&As[kk][ty * 4];
      float4 a1 = *(const float4*)&As[kk][ty * 4 + 64];
      float4 w0 = *(const float4*)&Ws[kk][tx * 4];
      float4 w1 = *(const float4*)&Ws[kk][tx * 4 + 64];
      float av[8] = {a0.x, a0.y, a0.z, a0.w, a1.x, a1.y, a1.z, a1.w};
      float wv[8] = {w0.x, w0.y, w0.z, w0.w, w1.x, w1.y, w1.z, w1.w};
      #pragma unroll
      for (int i = 0; i < 8; ++i)
        #pragma unroll
        for (int j = 0; j < 8; ++j) acc[i][j] = fmaf(av[i], wv[j], acc[i][j]);
    }
  }

  #pragma unroll
  for (int ih = 0; ih < 2; ++ih) {
    #pragma unroll
    for (int ii = 0; ii < 4; ++ii) {
      const int i = ih * 4 + ii;
      const size_t row = (size_t)(m0 + ih * 64 + ty * 4 + ii) * N;
      #pragma unroll
      for (int jh = 0; jh < 2; ++jh) {
        const int n = n0 + jh * 64 + tx * 4;
        float4 cv;
        cv.x = acc[i][jh * 4 + 0] + bias[n + 0];
        cv.y = acc[i][jh * 4 + 1] + bias[n + 1];
        cv.z = acc[i][jh * 4 + 2] + bias[n + 2];
        cv.w = acc[i][jh * 4 + 3] + bias[n + 3];
        if (ACT == 1) {
          cv.x = sigmoidf_(cv.x); cv.y = sigmoidf_(cv.y);
          cv.z = sigmoidf_(cv.z); cv.w = sigmoidf_(cv.w);
        }
        if (ACT == 2) {
          float4 prev = *(const float4*)&C[row + n];
          cv.x = prev.x * sigmoidf_(cv.x); cv.y = prev.y * sigmoidf_(cv.y);
          cv.z = prev.z * sigmoidf_(cv.z); cv.w = prev.w * sigmoidf_(cv.w);
        }
        *(float4*)&C[row + n] = cv;
      }
    }
  }
}

// One block per (b, h, 16-query tile). K/V chunks of 64 staged in LDS; scores in LDS;
// wave-local softmax (16 lanes per row).
__global__ __launch_bounds__(256) void attn_kernel(
    const float* __restrict__ q, const float* __restrict__ k,
    const float* __restrict__ v, const float* __restrict__ rm,
    float* __restrict__ ctx) {
  __shared__ float qs[16][68];
  __shared__ float ks[64][68];
  __shared__ float sc[16][516];
  const int t = threadIdx.x;
  const int bid = blockIdx.x;
  const int qt = bid & 31;
  const int h = (bid >> 5) & 7;
  const int b = bid >> 8;
  const int q0 = qt * 16;
  const int tx = t & 15;
  const int qq = t >> 4;

  {  // load Q tile: one float4/thread
    const int d4 = tx * 4;
    *(float4*)&qs[qq][d4] =
        *(const float4*)&q[((size_t)(b * Sn + q0 + qq)) * Dn + h * DKn + d4];
  }

  // key rows for this thread: tx + 16j  (stride-16 assignment -> 2-way LDS banks)
  const float* ksr0 = &ks[tx][0];
  const float* ksr1 = &ks[tx + 16][0];
  const float* ksr2 = &ks[tx + 32][0];
  const float* ksr3 = &ks[tx + 48][0];

  for (int kc = 0; kc < 8; ++kc) {
    __syncthreads();
    #pragma unroll
    for (int e = 0; e < 4; ++e) {
      const int l = t + 256 * e;
      const int row = l >> 4;
      const int d4 = (l & 15) * 4;
      *(float4*)&ks[row][d4] =
          *(const float4*)&k[((size_t)(b * Sn + kc * 64 + row)) * Dn + h * DKn + d4];
    }
    __syncthreads();
    float a0 = 0.f, a1 = 0.f, a2 = 0.f, a3 = 0.f;
    #pragma unroll
    for (int d4 = 0; d4 < 64; d4 += 4) {
      float4 qv = *(const float4*)&qs[qq][d4];
      float4 k0v = *(const float4*)(ksr0 + d4);
      float4 k1v = *(const float4*)(ksr1 + d4);
      float4 k2v = *(const float4*)(ksr2 + d4);
      float4 k3v = *(const float4*)(ksr3 + d4);
      a0 += qv.x * k0v.x + qv.y * k0v.y + qv.z * k0v.z + qv.w * k0v.w;
      a1 += qv.x * k1v.x + qv.y * k1v.y + qv.z * k1v.z + qv.w * k1v.w;
      a2 += qv.x * k2v.x + qv.y * k2v.y + qv.z * k2v.z + qv.w * k2v.w;
      a3 += qv.x * k3v.x + qv.y * k3v.y + qv.z * k3v.z + qv.w * k3v.w;
    }
    const int rb = q0 + qq + MAXPOSn - 1 - kc * 64;
    sc[qq][kc * 64 + tx     ] = a0 * 0.125f + rm[rb - tx];
    sc[qq][kc * 64 + tx + 16] = a1 * 0.125f + rm[rb - tx - 16];
    sc[qq][kc * 64 + tx + 32] = a2 * 0.125f + rm[rb - tx - 32];
    sc[qq][kc * 64 + tx + 48] = a3 * 0.125f + rm[rb - tx - 48];
  }
  __syncthreads();

  {  // softmax: row qq handled by its own wave's 16 lanes
    float mx = -1e30f;
    #pragma unroll
    for (int i = 0; i < 32; ++i) mx = fmaxf(mx, sc[qq][tx + i * 16]);
    #pragma unroll
    for (int off = 1; off <= 8; off <<= 1) mx = fmaxf(mx, __shfl_xor(mx, off));
    float sum = 0.0f;
    #pragma unroll
    for (int i = 0; i < 32; ++i) {
      float e = __expf(sc[qq][tx + i * 16] - mx);
      sc[qq][tx + i * 16] = e;
      sum += e;
    }
    #pragma unroll
    for (int off = 1; off <= 8; off <<= 1) sum += __shfl_xor(sum, off);
    const float rinv = 1.0f / sum;
    #pragma unroll
    for (int i = 0; i < 32; ++i) sc[qq][tx + i * 16] *= rinv;
  }

  // ctx[qq][d4..d4+3] = sum_k probs * V
  float ca0 = 0.f, ca1 = 0.f, ca2 = 0.f, ca3 = 0.f;
  const int cd4 = tx * 4;
  for (int kc = 0; kc < 8; ++kc) {
    __syncthreads();
    #pragma unroll
    for (int e = 0; e < 4; ++e) {
      const int l = t + 256 * e;
      const int row = l >> 4;
      const int d4 = (l & 15) * 4;
      *(float4*)&ks[row][d4] =
          *(const float4*)&v[((size_t)(b * Sn + kc * 64 + row)) * Dn + h * DKn + d4];
    }
    __syncthreads();
    #pragma unroll
    for (int kk = 0; kk < 64; kk += 4) {
      float4 p = *(const float4*)&sc[qq][kc * 64 + kk];
      float4 v0 = *(const float4*)&ks[kk + 0][cd4];
      float4 v1 = *(const float4*)&ks[kk + 1][cd4];
      float4 v2 = *(const float4*)&ks[kk + 2][cd4];
      float4 v3 = *(const float4*)&ks[kk + 3][cd4];
      ca0 += p.x * v0.x + p.y * v1.x + p.z * v2.x + p.w * v3.x;
      ca1 += p.x * v0.y + p.y * v1.y + p.z * v2.y + p.w * v3.y;
      ca2 += p.x * v0.z + p.y * v1.z + p.z * v2.z + p.w * v3.z;
      ca3 += p.x * v0.w + p.y * v1.w + p.z * v2.w + p.w * v3.w;
    }
  }
  *(float4*)&ctx[((size_t)(b * Sn + q0 + qq)) * Dn + h * DKn + cd4] =
      make_float4(ca0, ca1, ca2, ca3);
}

// x = LN(x + (gate? gate*add : add)) in-place, one block per row of 512
template <int HASGATE>
__global__ __launch_bounds__(256) void ln_res_kernel(
    float* __restrict__ x, const float* __restrict__ add,
    const float* __restrict__ gate, const float* __restrict__ s,
    const float* __restrict__ bsh) {
  const int row = blockIdx.x;
  const int t = threadIdx.x;
  const size_t base = (size_t)row * Dn;
  float y0 = x[base + t];
  float y1 = x[base + t + 256];
  float a0 = add[base + t];
  float a1 = add[base + t + 256];
  if (HASGATE) {
    a0 *= gate[base + t];
    a1 *= gate[base + t + 256];
  }
  y0 += a0;
  y1 += a1;
  const float mu = blockReduceSum(y0 + y1) * (1.0f / Dn);
  const float d0 = y0 - mu, d1 = y1 - mu;
  const float var = blockReduceSum(d0 * d0 + d1 * d1) * (1.0f / Dn);
  const float rstd = rsqrtf(var + EPSf);
  x[base + t] = d0 * rstd * s[t] + bsh[t];
  x[base + t + 256] = d1 * rstd * s[t + 256] + bsh[t + 256];
}

// h[b][0:512] = mean_s x[b,s,:]
__global__ __launch_bounds__(256) void meanpool_kernel(const float* __restrict__ x,
                                                       float* __restrict__ h) {
  const int idx = blockIdx.x * 256 + threadIdx.x;  // 8192
  const int b = idx >> 9;
  const int d = idx & 511;
  float s = 0.0f;
  for (int si = 0; si < Sn; ++si) s += x[((size_t)(b * Sn + si)) * Dn + d];
  h[b * 1024 + d] = s * (1.0f / Sn);
}

// h[b][512:1024] = x_other @ other_W + other_b
__global__ __launch_bounds__(256) void xo_kernel(const float* __restrict__ xo,
                                                 const float* __restrict__ W,
                                                 const float* __restrict__ bias,
                                                 float* __restrict__ h) {
  const int idx = blockIdx.x * 256 + threadIdx.x;  // 8192
  const int b = idx >> 9;
  const int n = idx & 511;
  float acc = bias[n];
  #pragma unroll
  for (int k = 0; k < FOn; ++k) acc = fmaf(xo[b * FOn + k], W[k * Dn + n], acc);
  h[b * 1024 + 512 + n] = acc;
}

// o[b][n] = relu(LN_256(h[b] @ fW1 + fb1))
__global__ __launch_bounds__(256) void f1_kernel(
    const float* __restrict__ h, const float* __restrict__ W,
    const float* __restrict__ bias, const float* __restrict__ s,
    const float* __restrict__ bt, float* __restrict__ o) {
  const int b = blockIdx.x;
  const int n = threadIdx.x;  // 256
  float acc = bias[n];
  for (int k = 0; k < 2 * Dn; ++k) acc = fmaf(h[b * 1024 + k], W[k * 256 + n], acc);
  const float mu = blockReduceSum(acc) * (1.0f / 256.0f);
  const float d = acc - mu;
  const float var = blockReduceSum(d * d) * (1.0f / 256.0f);
  const float y = d * rsqrtf(var + EPSf) * s[n] + bt[n];
  o[b * 256 + n] = fmaxf(y, 0.0f);
}

// o[b][n] = relu(LN_128(h1[b] @ fW2 + fb2))
__global__ __launch_bounds__(128) void f2_kernel(
    const float* __restrict__ h1, const float* __restrict__ W,
    const float* __restrict__ bias, const float* __restrict__ s,
    const float* __restrict__ bt, float* __restrict__ o) {
  const int b = blockIdx.x;
  const int n = threadIdx.x;  // 128
  float acc = bias[n];
  for (int k = 0; k < 256; ++k) acc = fmaf(h1[b * 256 + k], W[k * 128 + n], acc);
  const float mu = blockReduceSum(acc) * (1.0f / 128.0f);
  const float d = acc - mu;
  const float var = blockReduceSum(d * d) * (1.0f / 128.0f);
  const float y = d * rsqrtf(var + EPSf) * s[n] + bt[n];
  o[b * 128 + n] = fmaxf(y, 0.0f);
}

// out[b] = h2[b] @ fW3 + fb3
__global__ __launch_bounds__(128) void f3_kernel(const float* __restrict__ h2,
                                                 const float* __restrict__ W,
                                                 const float* __restrict__ bias,
                                                 float* __restrict__ o) {
  const int b = blockIdx.x;
  const int t = threadIdx.x;  // 128
  float v = h2[b * 128 + t] * W[t];
  v = blockReduceSum(v);
  if (t == 0) o[b] = v + bias[0];
}

extern "C" void kernel_launch(void* const* d_in, const int* in_sizes, int n_in,
                              void* d_out, int out_size, void* d_ws, size_t ws_size,
                              hipStream_t stream) {
  (void)in_sizes; (void)n_in; (void)out_size; (void)ws_size;
  const float* x_cgm  = (const float*)d_in[0];
  const float* x_other= (const float*)d_in[1];
  const float* cgm_W  = (const float*)d_in[2];
  const float* cgm_b  = (const float*)d_in[3];
  const float* rel_emb= (const float*)d_in[4];
  const float* Wq = (const float*)d_in[5];
  const float* bq = (const float*)d_in[6];
  const float* Wk = (const float*)d_in[7];
  const float* bk = (const float*)d_in[8];
  const float* Wv = (const float*)d_in[9];
  const float* bv = (const float*)d_in[10];
  const float* Wo = (const float*)d_in[11];
  const float* bo = (const float*)d_in[12];
  const float* Wg = (const float*)d_in[13];
  const float* bg = (const float*)d_in[14];
  const float* Wf1 = (const float*)d_in[15];
  const float* bf1 = (const float*)d_in[16];
  const float* Wfg = (const float*)d_in[17];
  const float* bfg = (const float*)d_in[18];
  const float* Wf2 = (const float*)d_in[19];
  const float* bf2 = (const float*)d_in[20];
  const float* ln1_s = (const float*)d_in[21];
  const float* ln1_b = (const float*)d_in[22];
  const float* ln2_s = (const float*)d_in[23];
  const float* ln2_b = (const float*)d_in[24];
  const float* other_W = (const float*)d_in[25];
  const float* other_b = (const float*)d_in[26];
  const float* fW1 = (const float*)d_in[27];
  const float* fb1 = (const float*)d_in[28];
  const float* fln1_s = (const float*)d_in[29];
  const float* fln1_b = (const float*)d_in[30];
  const float* fW2 = (const float*)d_in[31];
  const float* fb2 = (const float*)d_in[32];
  const float* fln2_s = (const float*)d_in[33];
  const float* fln2_b = (const float*)d_in[34];
  const float* fW3 = (const float*)d_in[35];
  const float* fb3 = (const float*)d_in[36];
  float* out = (float*)d_out;

  // workspace layout (floats): ~101 MB total
  float* ws   = (float*)d_ws;
  float* X    = ws;                                 // [8192,512]
  float* BUF1 = X + (size_t)8192 * 512;             // [8192,2048] multi-use
  float* Qb   = BUF1;
  float* Kb   = BUF1 + (size_t)8192 * 512;
  float* Vb   = BUF1 + (size_t)2 * 8192 * 512;
  float* ATTb = BUF1;                                // reuse (Q dead after attn)
  float* GATEb= Kb;                                  // reuse (K dead after attn)
  float* FFB  = BUF1;                                // [8192,2048] (after ln1)
  float* CTX  = BUF1 + (size_t)8192 * 2048;          // [8192,512] ctx / ff2-out
  float* RMb  = CTX + (size_t)8192 * 512;            // [1023]
  float* Hb   = RMb + 1024;                          // [16,1024]
  float* H1b  = Hb + 16 * 1024;                      // [16,256]
  float* H2b  = H1b + 16 * 256;                      // [16,128]

  embed_kernel<<<dim3(16384), dim3(256), 0, stream>>>(x_cgm, cgm_W, cgm_b, X);
  relmean_kernel<<<dim3(4), dim3(256), 0, stream>>>(rel_emb, RMb);

  for (int l = 0; l < Ln; ++l) {
    const size_t wof = (size_t)l * Dn * Dn;
    const size_t bof = (size_t)l * Dn;
    const size_t wf_of = (size_t)l * Dn * FFn;
    const size_t bf_of = (size_t)l * FFn;
    gemm_kernel<0><<<dim3(4, 64), 256, 0, stream>>>(X, Wq + wof, bq + bof, Qb, 8192, 512, 512);
    gemm_kernel<0><<<dim3(4, 64), 256, 0, stream>>>(X, Wk + wof, bk + bof, Kb, 8192, 512, 512);
    gemm_kernel<0><<<dim3(4, 64), 256, 0, stream>>>(X, Wv + wof, bv + bof, Vb, 8192, 512, 512);
    attn_kernel<<<dim3(4096), dim3(256), 0, stream>>>(Qb, Kb, Vb, RMb, CTX);
    gemm_kernel<0><<<dim3(4, 64), 256, 0, stream>>>(CTX, Wo + wof, bo + bof, ATTb, 8192, 512, 512);
    gemm_kernel<1><<<dim3(4, 64), 256, 0, stream>>>(X, Wg + wof, bg + bof, GATEb, 8192, 512, 512);
    ln_res_kernel<1><<<dim3(8192), dim3(256), 0, stream>>>(X, ATTb, GATEb, ln1_s + bof, ln1_b + bof);
    gemm_kernel<0><<<dim3(16, 64), 256, 0, stream>>>(X, Wf1 + wf_of, bf1 + bf_of, FFB, 8192, 2048, 512);
    gemm_kernel<2><<<dim3(16, 64), 256, 0, stream>>>(X, Wfg + wf_of, bfg + bf_of, FFB, 8192, 2048, 512);
    gemm_kernel<0><<<dim3(4, 64), 256, 0, stream>>>(FFB, Wf2 + wf_of, bf2 + bof, CTX, 8192, 512, 2048);
    ln_res_kernel<0><<<dim3(8192), dim3(256), 0, stream>>>(X, CTX, nullptr, ln2_s + bof, ln2_b + bof);
  }

  meanpool_kernel<<<dim3(32), dim3(256), 0, stream>>>(X, Hb);
  xo_kernel<<<dim3(32), dim3(256), 0, stream>>>(x_other, other_W, other_b, Hb);
  f1_kernel<<<dim3(16), dim3(256), 0, stream>>>(Hb, fW1, fb1, fln1_s, fln1_b, H1b);
  f2_kernel<<<dim3(16), dim3(128), 0, stream>>>(H1b, fW2, fb2, fln2_s, fln2_b, H2b);
  f3_kernel<<<dim3(16), dim3(128), 0, stream>>>(H2b, fW3, fb3, out);
}

// Round 2
// 2982.924 us; speedup vs baseline: 2.2672x; 2.2672x over previous
//
#include <hip/hip_runtime.h>
#include <math.h>

constexpr int Bn = 16;
constexpr int Sn = 512;
constexpr int FCn = 24;
constexpr int FOn = 16;
constexpr int Dn = 512;
constexpr int Hn = 8;
constexpr int DKn = 64;
constexpr int FFn = 2048;
constexpr int Ln = 4;
constexpr int MAXPOSn = 512;
constexpr float EPSf = 1e-6f;

typedef __attribute__((ext_vector_type(8))) short bf16x8;   // 8 bf16 in 4 VGPRs
typedef __attribute__((ext_vector_type(4))) float floatx4;

__device__ __forceinline__ float sigmoidf_(float x) { return 1.0f / (1.0f + __expf(-x)); }

__device__ __forceinline__ unsigned short f2bf(float f) {  // RNE
  unsigned int u = __float_as_uint(f);
  u += 0x7fffu + ((u >> 16) & 1u);
  return (unsigned short)(u >> 16);
}
__device__ __forceinline__ float b2f(unsigned short b) {
  return __uint_as_float(((unsigned int)b) << 16);
}

__device__ __forceinline__ void g2l16(const void* g, void* l) {
  // async global->LDS, 16B/lane, LDS dest = wave-uniform base + lane*16
  __builtin_amdgcn_global_load_lds((const __attribute__((address_space(1))) void*)g,
                                   (__attribute__((address_space(3))) void*)l, 16, 0, 0);
}

__device__ __forceinline__ float blockReduceSum(float v) {
  #pragma unroll
  for (int off = 32; off >= 1; off >>= 1) v += __shfl_xor(v, off);
  __shared__ float red[8];
  const int w = threadIdx.x >> 6;
  const int nw = blockDim.x >> 6;
  if ((threadIdx.x & 63) == 0) red[w] = v;
  __syncthreads();
  float r = 0.0f;
  for (int i = 0; i < nw; ++i) r += red[i];
  __syncthreads();
  return r;
}

// ---------- weight transpose-convert: out[n][k] bf16 = in[k][n] f32 ----------
__global__ __launch_bounds__(256) void wconv_kernel(
    const float* __restrict__ in, unsigned short* __restrict__ out,
    int K, int N, size_t inStride, size_t outStride) {
  __shared__ float tile[32][33];
  in += (size_t)blockIdx.z * inStride;
  out += (size_t)blockIdx.z * outStride;
  const int k0 = blockIdx.y * 32, n0 = blockIdx.x * 32;
  const int tr = threadIdx.x >> 3;         // 0..31
  const int tc4 = (threadIdx.x & 7) * 4;   // 0..28
  float4 vv = *(const float4*)&in[(size_t)(k0 + tr) * N + n0 + tc4];
  tile[tr][tc4 + 0] = vv.x; tile[tr][tc4 + 1] = vv.y;
  tile[tr][tc4 + 2] = vv.z; tile[tr][tc4 + 3] = vv.w;
  __syncthreads();
  ushort4 o4;
  o4.x = f2bf(tile[tc4 + 0][tr]); o4.y = f2bf(tile[tc4 + 1][tr]);
  o4.z = f2bf(tile[tc4 + 2][tr]); o4.w = f2bf(tile[tc4 + 3][tr]);
  *(ushort4*)&out[(size_t)(n0 + tr) * K + k0 + tc4] = o4;
}

// bias concat: [L][2048] = [bq|bk|bv|bg]
__global__ void bcat_kernel(const float* __restrict__ bq, const float* __restrict__ bk,
                            const float* __restrict__ bv, const float* __restrict__ bg,
                            float* __restrict__ out) {
  const int t = blockIdx.x * 256 + threadIdx.x;  // 8192
  const int l = t >> 11;
  const int c = t & 2047;
  float v;
  if (c < 512) v = bq[l * 512 + c];
  else if (c < 1024) v = bk[l * 512 + c - 512];
  else if (c < 1536) v = bv[l * 512 + c - 1024];
  else v = bg[l * 512 + c - 1536];
  out[t] = v;
}

// x = x_cgm @ cgm_W + cgm_b  -> fp32 X and bf16 Xb
__global__ __launch_bounds__(256) void embed_kernel(
    const float* __restrict__ xc, const float* __restrict__ W,
    const float* __restrict__ bias, float* __restrict__ x,
    unsigned short* __restrict__ xb) {
  const int idx = blockIdx.x * 256 + threadIdx.x;
  const int n = idx & (Dn - 1);
  const int m = idx >> 9;
  const float* xr = xc + m * FCn;
  float acc = bias[n];
  #pragma unroll
  for (int k = 0; k < FCn; ++k) acc = fmaf(xr[k], W[k * Dn + n], acc);
  x[idx] = acc;
  xb[idx] = f2bf(acc);
}

__global__ void relmean_kernel(const float* __restrict__ rel, float* __restrict__ rm) {
  const int p = blockIdx.x * blockDim.x + threadIdx.x;
  if (p >= 2 * MAXPOSn - 1) return;
  float s = 0.0f;
  #pragma unroll 8
  for (int d = 0; d < DKn; ++d) s += rel[p * DKn + d];
  rm[p] = s * (1.0f / DKn);
}

// ---------- bf16 MFMA GEMM: C = A[M,K] @ Bt[N,K]^T + bias ----------
// m97 structure: 128x128 tile, BK=32, global_load_lds(16B), 16x16x32 bf16 MFMA.
// EPI: 0 = fp32 out (+bias)
//      2 = ffgate: Cb[i] = bf16( b2f(Cb[i]) * sigmoid(acc+bias) )  (in-place bf16)
//      3 = bf16 out (+bias)
//      4 = qkvg: cols<1536 -> bf16 to Cb (ld 1536); cols>=1536 -> fp32 sigmoid to Cf (ld 512)
template <int EPI>
__global__ __launch_bounds__(256) void mgemm(
    const unsigned short* __restrict__ A, const unsigned short* __restrict__ Bt,
    const float* __restrict__ bias, float* __restrict__ Cf,
    unsigned short* __restrict__ Cb, int M, int N, int K, int ldc) {
  __shared__ unsigned short As[128 * 32];
  __shared__ unsigned short Bs[128 * 32];
  const int t = threadIdx.x;
  const int w = t >> 6;
  const int lane = t & 63;
  const int n0 = blockIdx.x * 128;
  const int m0 = blockIdx.y * 128;
  const int wm = (w >> 1) * 64;
  const int wn = (w & 1) * 64;
  const int lr = lane & 15;
  const int lq = lane >> 4;

  floatx4 acc[4][4];
  #pragma unroll
  for (int i = 0; i < 4; ++i)
    #pragma unroll
    for (int j = 0; j < 4; ++j) acc[i][j] = (floatx4){0.f, 0.f, 0.f, 0.f};

  const int srow = lane >> 2;   // 0..15
  const int schk = (lane & 3) * 8;

  for (int k0 = 0; k0 < K; k0 += 32) {
    __syncthreads();  // previous tile fully consumed before DMA overwrites LDS
    #pragma unroll
    for (int r = 0; r < 2; ++r) {
      const int rb = (w * 2 + r) * 16;
      g2l16(&A[(size_t)(m0 + rb + srow) * K + k0 + schk], &As[rb * 32]);
      g2l16(&Bt[(size_t)(n0 + rb + srow) * K + k0 + schk], &Bs[rb * 32]);
    }
    __syncthreads();  // drain DMA (compiler emits vmcnt(0) before s_barrier)
    bf16x8 af[4], bf[4];
    #pragma unroll
    for (int i = 0; i < 4; ++i)
      af[i] = *(const bf16x8*)&As[(wm + i * 16 + lr) * 32 + lq * 8];
    #pragma unroll
    for (int j = 0; j < 4; ++j)
      bf[j] = *(const bf16x8*)&Bs[(wn + j * 16 + lr) * 32 + lq * 8];
    #pragma unroll
    for (int i = 0; i < 4; ++i)
      #pragma unroll
      for (int j = 0; j < 4; ++j)
        acc[i][j] = __builtin_amdgcn_mfma_f32_16x16x32_bf16(af[i], bf[j], acc[i][j], 0, 0, 0);
  }

  // C/D layout: col = lane&15, row = (lane>>4)*4 + reg  [m89/m91 verified]
  #pragma unroll
  for (int i = 0; i < 4; ++i) {
    const int row = m0 + wm + i * 16 + lq * 4;
    #pragma unroll
    for (int j = 0; j < 4; ++j) {
      const int col = n0 + wn + j * 16 + lr;
      const float bv = bias[col];
      #pragma unroll
      for (int r = 0; r < 4; ++r) {
        const float va = acc[i][j][r] + bv;
        if (EPI == 0) {
          Cf[(size_t)(row + r) * ldc + col] = va;
        } else if (EPI == 3) {
          Cb[(size_t)(row + r) * ldc + col] = f2bf(va);
        } else if (EPI == 2) {
          const size_t idx = (size_t)(row + r) * ldc + col;
          Cb[idx] = f2bf(b2f(Cb[idx]) * sigmoidf_(va));
        } else if (EPI == 4) {
          if (col < 1536) Cb[(size_t)(row + r) * 1536 + col] = f2bf(va);
          else Cf[(size_t)(row + r) * 512 + (col - 1536)] = sigmoidf_(va);
        }
      }
    }
  }
}

// ---------- attention (fp32 compute, bf16 I/O from fused QKV buffer) ----------
// qkv row stride 1536: [q(512) | k(512) | v(512)]; ctx out bf16 [8192][512]
__global__ __launch_bounds__(256) void attn_kernel(
    const unsigned short* __restrict__ qkv, const float* __restrict__ rm,
    unsigned short* __restrict__ ctx) {
  __shared__ float qs[16][68];
  __shared__ float ks[64][68];
  __shared__ float sc[16][516];
  const int t = threadIdx.x;
  const int bid = blockIdx.x;
  const int qt = bid & 31;
  const int h = (bid >> 5) & 7;
  const int b = bid >> 8;
  const int q0 = qt * 16;
  const int tx = t & 15;
  const int qq = t >> 4;

  {
    const int d4 = tx * 4;
    ushort4 qv = *(const ushort4*)&qkv[((size_t)(b * Sn + q0 + qq)) * 1536 + h * DKn + d4];
    qs[qq][d4 + 0] = b2f(qv.x); qs[qq][d4 + 1] = b2f(qv.y);
    qs[qq][d4 + 2] = b2f(qv.z); qs[qq][d4 + 3] = b2f(qv.w);
  }

  const float* ksr0 = &ks[tx][0];
  const float* ksr1 = &ks[tx + 16][0];
  const float* ksr2 = &ks[tx + 32][0];
  const float* ksr3 = &ks[tx + 48][0];

  for (int kc = 0; kc < 8; ++kc) {
    __syncthreads();
    #pragma unroll
    for (int e = 0; e < 4; ++e) {
      const int l = t + 256 * e;
      const int row = l >> 4;
      const int d4 = (l & 15) * 4;
      ushort4 kv = *(const ushort4*)&qkv[((size_t)(b * Sn + kc * 64 + row)) * 1536 + 512 + h * DKn + d4];
      ks[row][d4 + 0] = b2f(kv.x); ks[row][d4 + 1] = b2f(kv.y);
      ks[row][d4 + 2] = b2f(kv.z); ks[row][d4 + 3] = b2f(kv.w);
    }
    __syncthreads();
    float a0 = 0.f, a1 = 0.f, a2 = 0.f, a3 = 0.f;
    #pragma unroll
    for (int d4 = 0; d4 < 64; d4 += 4) {
      float4 qv = *(const float4*)&qs[qq][d4];
      float4 k0v = *(const float4*)(ksr0 + d4);
      float4 k1v = *(const float4*)(ksr1 + d4);
      float4 k2v = *(const float4*)(ksr2 + d4);
      float4 k3v = *(const float4*)(ksr3 + d4);
      a0 += qv.x * k0v.x + qv.y * k0v.y + qv.z * k0v.z + qv.w * k0v.w;
      a1 += qv.x * k1v.x + qv.y * k1v.y + qv.z * k1v.z + qv.w * k1v.w;
      a2 += qv.x * k2v.x + qv.y * k2v.y + qv.z * k2v.z + qv.w * k2v.w;
      a3 += qv.x * k3v.x + qv.y * k3v.y + qv.z * k3v.z + qv.w * k3v.w;
    }
    const int rb = q0 + qq + MAXPOSn - 1 - kc * 64;
    sc[qq][kc * 64 + tx     ] = a0 * 0.125f + rm[rb - tx];
    sc[qq][kc * 64 + tx + 16] = a1 * 0.125f + rm[rb - tx - 16];
    sc[qq][kc * 64 + tx + 32] = a2 * 0.125f + rm[rb - tx - 32];
    sc[qq][kc * 64 + tx + 48] = a3 * 0.125f + rm[rb - tx - 48];
  }
  __syncthreads();

  {
    float mx = -1e30f;
    #pragma unroll
    for (int i = 0; i < 32; ++i) mx = fmaxf(mx, sc[qq][tx + i * 16]);
    #pragma unroll
    for (int off = 1; off <= 8; off <<= 1) mx = fmaxf(mx, __shfl_xor(mx, off));
    float sum = 0.0f;
    #pragma unroll
    for (int i = 0; i < 32; ++i) {
      float e = __expf(sc[qq][tx + i * 16] - mx);
      sc[qq][tx + i * 16] = e;
      sum += e;
    }
    #pragma unroll
    for (int off = 1; off <= 8; off <<= 1) sum += __shfl_xor(sum, off);
    const float rinv = 1.0f / sum;
    #pragma unroll
    for (int i = 0; i < 32; ++i) sc[qq][tx + i * 16] *= rinv;
  }

  float ca0 = 0.f, ca1 = 0.f, ca2 = 0.f, ca3 = 0.f;
  const int cd4 = tx * 4;
  for (int kc = 0; kc < 8; ++kc) {
    __syncthreads();
    #pragma unroll
    for (int e = 0; e < 4; ++e) {
      const int l = t + 256 * e;
      const int row = l >> 4;
      const int d4 = (l & 15) * 4;
      ushort4 vv = *(const ushort4*)&qkv[((size_t)(b * Sn + kc * 64 + row)) * 1536 + 1024 + h * DKn + d4];
      ks[row][d4 + 0] = b2f(vv.x); ks[row][d4 + 1] = b2f(vv.y);
      ks[row][d4 + 2] = b2f(vv.z); ks[row][d4 + 3] = b2f(vv.w);
    }
    __syncthreads();
    #pragma unroll
    for (int kk = 0; kk < 64; kk += 4) {
      float4 p = *(const float4*)&sc[qq][kc * 64 + kk];
      float4 v0 = *(const float4*)&ks[kk + 0][cd4];
      float4 v1 = *(const float4*)&ks[kk + 1][cd4];
      float4 v2 = *(const float4*)&ks[kk + 2][cd4];
      float4 v3 = *(const float4*)&ks[kk + 3][cd4];
      ca0 += p.x * v0.x + p.y * v1.x + p.z * v2.x + p.w * v3.x;
      ca1 += p.x * v0.y + p.y * v1.y + p.z * v2.y + p.w * v3.y;
      ca2 += p.x * v0.z + p.y * v1.z + p.z * v2.z + p.w * v3.z;
      ca3 += p.x * v0.w + p.y * v1.w + p.z * v2.w + p.w * v3.w;
    }
  }
  ushort4 o4;
  o4.x = f2bf(ca0); o4.y = f2bf(ca1); o4.z = f2bf(ca2); o4.w = f2bf(ca3);
  *(ushort4*)&ctx[((size_t)(b * Sn + q0 + qq)) * Dn + h * DKn + cd4] = o4;
}

// x = LN(x + (gate? gate*add : add)) in-place; also writes bf16 mirror xb
template <int HASGATE>
__global__ __launch_bounds__(256) void ln_res_kernel(
    float* __restrict__ x, unsigned short* __restrict__ xb,
    const float* __restrict__ add, const float* __restrict__ gate,
    const float* __restrict__ s, const float* __restrict__ bsh) {
  const int row = blockIdx.x;
  const int t = threadIdx.x;
  const size_t base = (size_t)row * Dn;
  float y0 = x[base + t];
  float y1 = x[base + t + 256];
  float a0 = add[base + t];
  float a1 = add[base + t + 256];
  if (HASGATE) {
    a0 *= gate[base + t];
    a1 *= gate[base + t + 256];
  }
  y0 += a0;
  y1 += a1;
  const float mu = blockReduceSum(y0 + y1) * (1.0f / Dn);
  const float d0 = y0 - mu, d1 = y1 - mu;
  const float var = blockReduceSum(d0 * d0 + d1 * d1) * (1.0f / Dn);
  const float rstd = rsqrtf(var + EPSf);
  const float o0 = d0 * rstd * s[t] + bsh[t];
  const float o1 = d1 * rstd * s[t + 256] + bsh[t + 256];
  x[base + t] = o0;
  x[base + t + 256] = o1;
  xb[base + t] = f2bf(o0);
  xb[base + t + 256] = f2bf(o1);
}

__global__ __launch_bounds__(256) void meanpool_kernel(const float* __restrict__ x,
                                                       float* __restrict__ h) {
  const int idx = blockIdx.x * 256 + threadIdx.x;  // 8192
  const int b = idx >> 9;
  const int d = idx & 511;
  float s = 0.0f;
  for (int si = 0; si < Sn; ++si) s += x[((size_t)(b * Sn + si)) * Dn + d];
  h[b * 1024 + d] = s * (1.0f / Sn);
}

__global__ __launch_bounds__(256) void xo_kernel(const float* __restrict__ xo,
                                                 const float* __restrict__ W,
                                                 const float* __restrict__ bias,
                                                 float* __restrict__ h) {
  const int idx = blockIdx.x * 256 + threadIdx.x;  // 8192
  const int b = idx >> 9;
  const int n = idx & 511;
  float acc = bias[n];
  #pragma unroll
  for (int k = 0; k < FOn; ++k) acc = fmaf(xo[b * FOn + k], W[k * Dn + n], acc);
  h[b * 1024 + 512 + n] = acc;
}

__global__ __launch_bounds__(256) void f1_kernel(
    const float* __restrict__ h, const float* __restrict__ W,
    const float* __restrict__ bias, const float* __restrict__ s,
    const float* __restrict__ bt, float* __restrict__ o) {
  const int b = blockIdx.x;
  const int n = threadIdx.x;  // 256
  float acc = bias[n];
  for (int k = 0; k < 2 * Dn; ++k) acc = fmaf(h[b * 1024 + k], W[k * 256 + n], acc);
  const float mu = blockReduceSum(acc) * (1.0f / 256.0f);
  const float d = acc - mu;
  const float var = blockReduceSum(d * d) * (1.0f / 256.0f);
  const float y = d * rsqrtf(var + EPSf) * s[n] + bt[n];
  o[b * 256 + n] = fmaxf(y, 0.0f);
}

__global__ __launch_bounds__(128) void f2_kernel(
    const float* __restrict__ h1, const float* __restrict__ W,
    const float* __restrict__ bias, const float* __restrict__ s,
    const float* __restrict__ bt, float* __restrict__ o) {
  const int b = blockIdx.x;
  const int n = threadIdx.x;  // 128
  float acc = bias[n];
  for (int k = 0; k < 256; ++k) acc = fmaf(h1[b * 256 + k], W[k * 128 + n], acc);
  const float mu = blockReduceSum(acc) * (1.0f / 128.0f);
  const float d = acc - mu;
  const float var = blockReduceSum(d * d) * (1.0f / 128.0f);
  const float y = d * rsqrtf(var + EPSf) * s[n] + bt[n];
  o[b * 128 + n] = fmaxf(y, 0.0f);
}

__global__ __launch_bounds__(128) void f3_kernel(const float* __restrict__ h2,
                                                 const float* __restrict__ W,
                                                 const float* __restrict__ bias,
                                                 float* __restrict__ o) {
  const int b = blockIdx.x;
  const int t = threadIdx.x;  // 128
  float v = h2[b * 128 + t] * W[t];
  v = blockReduceSum(v);
  if (t == 0) o[b] = v + bias[0];
}

extern "C" void kernel_launch(void* const* d_in, const int* in_sizes, int n_in,
                              void* d_out, int out_size, void* d_ws, size_t ws_size,
                              hipStream_t stream) {
  (void)in_sizes; (void)n_in; (void)out_size; (void)ws_size;
  const float* x_cgm  = (const float*)d_in[0];
  const float* x_other= (const float*)d_in[1];
  const float* cgm_W  = (const float*)d_in[2];
  const float* cgm_b  = (const float*)d_in[3];
  const float* rel_emb= (const float*)d_in[4];
  const float* Wq = (const float*)d_in[5];
  const float* bq = (const float*)d_in[6];
  const float* Wk = (const float*)d_in[7];
  const float* bk = (const float*)d_in[8];
  const float* Wv = (const float*)d_in[9];
  const float* bv = (const float*)d_in[10];
  const float* Wo = (const float*)d_in[11];
  const float* bo = (const float*)d_in[12];
  const float* Wg = (const float*)d_in[13];
  const float* bg = (const float*)d_in[14];
  const float* Wf1 = (const float*)d_in[15];
  const float* bf1 = (const float*)d_in[16];
  const float* Wfg = (const float*)d_in[17];
  const float* bfg = (const float*)d_in[18];
  const float* Wf2 = (const float*)d_in[19];
  const float* bf2 = (const float*)d_in[20];
  const float* ln1_s = (const float*)d_in[21];
  const float* ln1_b = (const float*)d_in[22];
  const float* ln2_s = (const float*)d_in[23];
  const float* ln2_b = (const float*)d_in[24];
  const float* other_W = (const float*)d_in[25];
  const float* other_b = (const float*)d_in[26];
  const float* fW1 = (const float*)d_in[27];
  const float* fb1 = (const float*)d_in[28];
  const float* fln1_s = (const float*)d_in[29];
  const float* fln1_b = (const float*)d_in[30];
  const float* fW2 = (const float*)d_in[31];
  const float* fb2 = (const float*)d_in[32];
  const float* fln2_s = (const float*)d_in[33];
  const float* fln2_b = (const float*)d_in[34];
  const float* fW3 = (const float*)d_in[35];
  const float* fb3 = (const float*)d_in[36];
  float* out = (float*)d_out;

  // ---- workspace layout (~122 MB) ----
  char* p = (char*)d_ws;
  auto alloc = [&](size_t bytes) { char* r = p; p += (bytes + 255) & ~(size_t)255; return r; };
  float*          X      = (float*)alloc((size_t)8192 * 512 * 4);
  unsigned short* Xb     = (unsigned short*)alloc((size_t)8192 * 512 * 2);
  unsigned short* QKVb   = (unsigned short*)alloc((size_t)8192 * 1536 * 2);  // also CTXo f32
  unsigned short* CTXb   = (unsigned short*)alloc((size_t)8192 * 512 * 2);
  char*           R      = alloc((size_t)8192 * 2048 * 4);  // ATTb|GATEb / FFBh overlay
  float*          ATTb   = (float*)R;
  float*          GATEb  = (float*)(R + (size_t)8192 * 512 * 4);
  unsigned short* FFBh   = (unsigned short*)R;
  float*          CTXo   = (float*)QKVb;
  unsigned short* Wqkvgt = (unsigned short*)alloc((size_t)4 * 2048 * 512 * 2);
  unsigned short* Wot    = (unsigned short*)alloc((size_t)4 * 512 * 512 * 2);
  unsigned short* Wf1t   = (unsigned short*)alloc((size_t)4 * 2048 * 512 * 2);
  unsigned short* Wfgt   = (unsigned short*)alloc((size_t)4 * 2048 * 512 * 2);
  unsigned short* Wf2t   = (unsigned short*)alloc((size_t)4 * 512 * 2048 * 2);
  float*          bqkvg  = (float*)alloc((size_t)4 * 2048 * 4);
  float*          RMb    = (float*)alloc(1024 * 4);
  float*          Hb     = (float*)alloc(16 * 1024 * 4);
  float*          H1b    = (float*)alloc(16 * 256 * 4);
  float*          H2b    = (float*)alloc(16 * 128 * 4);

  // ---- weight conversion (per launch; weights restored by harness each call) ----
  // qkvg fused: Wqkvgt[l] is [2048][512] rows = [q|k|v|g]
  wconv_kernel<<<dim3(16, 16, 4), 256, 0, stream>>>(Wq, Wqkvgt + (size_t)0 * 512, 512, 512,
                                                    (size_t)512 * 512, (size_t)2048 * 512);
  wconv_kernel<<<dim3(16, 16, 4), 256, 0, stream>>>(Wk, Wqkvgt + (size_t)512 * 512, 512, 512,
                                                    (size_t)512 * 512, (size_t)2048 * 512);
  wconv_kernel<<<dim3(16, 16, 4), 256, 0, stream>>>(Wv, Wqkvgt + (size_t)1024 * 512, 512, 512,
                                                    (size_t)512 * 512, (size_t)2048 * 512);
  wconv_kernel<<<dim3(16, 16, 4), 256, 0, stream>>>(Wg, Wqkvgt + (size_t)1536 * 512, 512, 512,
                                                    (size_t)512 * 512, (size_t)2048 * 512);
  wconv_kernel<<<dim3(16, 16, 4), 256, 0, stream>>>(Wo, Wot, 512, 512,
                                                    (size_t)512 * 512, (size_t)512 * 512);
  wconv_kernel<<<dim3(64, 16, 4), 256, 0, stream>>>(Wf1, Wf1t, 512, 2048,
                                                    (size_t)512 * 2048, (size_t)2048 * 512);
  wconv_kernel<<<dim3(64, 16, 4), 256, 0, stream>>>(Wfg, Wfgt, 512, 2048,
                                                    (size_t)512 * 2048, (size_t)2048 * 512);
  wconv_kernel<<<dim3(16, 64, 4), 256, 0, stream>>>(Wf2, Wf2t, 2048, 512,
                                                    (size_t)2048 * 512, (size_t)512 * 2048);
  bcat_kernel<<<dim3(32), 256, 0, stream>>>(bq, bk, bv, bg, bqkvg);

  embed_kernel<<<dim3(16384), dim3(256), 0, stream>>>(x_cgm, cgm_W, cgm_b, X, Xb);
  relmean_kernel<<<dim3(4), dim3(256), 0, stream>>>(rel_emb, RMb);

  for (int l = 0; l < Ln; ++l) {
    const size_t bof = (size_t)l * Dn;
    // fused q|k|v|gate GEMM: N=2048
    mgemm<4><<<dim3(16, 64), 256, 0, stream>>>(Xb, Wqkvgt + (size_t)l * 2048 * 512,
                                               bqkvg + (size_t)l * 2048, GATEb, QKVb,
                                               8192, 2048, 512, 0);
    attn_kernel<<<dim3(4096), dim3(256), 0, stream>>>(QKVb, RMb, CTXb);
    mgemm<0><<<dim3(4, 64), 256, 0, stream>>>(CTXb, Wot + (size_t)l * 512 * 512,
                                              bo + bof, ATTb, nullptr, 8192, 512, 512, 512);
    ln_res_kernel<1><<<dim3(8192), 256, 0, stream>>>(X, Xb, ATTb, GATEb, ln1_s + bof, ln1_b + bof);
    mgemm<3><<<dim3(16, 64), 256, 0, stream>>>(Xb, Wf1t + (size_t)l * 2048 * 512,
                                               bf1 + (size_t)l * FFn, nullptr, FFBh,
                                               8192, 2048, 512, 2048);
    mgemm<2><<<dim3(16, 64), 256, 0, stream>>>(Xb, Wfgt + (size_t)l * 2048 * 512,
                                               bfg + (size_t)l * FFn, nullptr, FFBh,
                                               8192, 2048, 512, 2048);
    mgemm<0><<<dim3(4, 64), 256, 0, stream>>>(FFBh, Wf2t + (size_t)l * 512 * 2048,
                                              bf2 + bof, CTXo, nullptr, 8192, 512, 2048, 512);
    ln_res_kernel<0><<<dim3(8192), 256, 0, stream>>>(X, Xb, CTXo, nullptr, ln2_s + bof, ln2_b + bof);
  }

  meanpool_kernel<<<dim3(32), dim3(256), 0, stream>>>(X, Hb);
  xo_kernel<<<dim3(32), dim3(256), 0, stream>>>(x_other, other_W, other_b, Hb);
  f1_kernel<<<dim3(16), dim3(256), 0, stream>>>(Hb, fW1, fb1, fln1_s, fln1_b, H1b);
  f2_kernel<<<dim3(16), dim3(128), 0, stream>>>(H1b, fW2, fb2, fln2_s, fln2_b, H2b);
  f3_kernel<<<dim3(16), dim3(128), 0, stream>>>(H2b, fW3, fb3, out);
}

// Round 3
// 1378.124 us; speedup vs baseline: 4.9073x; 2.1645x over previous
//
#include <hip/hip_runtime.h>
#include <math.h>

constexpr int Bn = 16;
constexpr int Sn = 512;
constexpr int FCn = 24;
constexpr int FOn = 16;
constexpr int Dn = 512;
constexpr int Hn = 8;
constexpr int DKn = 64;
constexpr int FFn = 2048;
constexpr int Ln = 4;
constexpr int MAXPOSn = 512;
constexpr float EPSf = 1e-6f;

typedef __attribute__((ext_vector_type(8))) short bf16x8;   // 8 bf16 in 4 VGPRs
typedef __attribute__((ext_vector_type(4))) float floatx4;

__device__ __forceinline__ float sigmoidf_(float x) { return 1.0f / (1.0f + __expf(-x)); }

__device__ __forceinline__ unsigned short f2bf(float f) {  // RNE
  unsigned int u = __float_as_uint(f);
  u += 0x7fffu + ((u >> 16) & 1u);
  return (unsigned short)(u >> 16);
}
__device__ __forceinline__ float b2f(unsigned short b) {
  return __uint_as_float(((unsigned int)b) << 16);
}

__device__ __forceinline__ void g2l16(const void* g, void* l) {
  // async global->LDS, 16B/lane, LDS dest = wave-uniform base + lane*16
  __builtin_amdgcn_global_load_lds((const __attribute__((address_space(1))) void*)g,
                                   (__attribute__((address_space(3))) void*)l, 16, 0, 0);
}

__device__ __forceinline__ float blockReduceSum(float v) {
  #pragma unroll
  for (int off = 32; off >= 1; off >>= 1) v += __shfl_xor(v, off);
  __shared__ float red[8];
  const int w = threadIdx.x >> 6;
  const int nw = blockDim.x >> 6;
  if ((threadIdx.x & 63) == 0) red[w] = v;
  __syncthreads();
  float r = 0.0f;
  for (int i = 0; i < nw; ++i) r += red[i];
  __syncthreads();
  return r;
}

// ---------- weight transpose-convert: out[n][k] bf16 = in[k][n] f32 ----------
__global__ __launch_bounds__(256) void wconv_kernel(
    const float* __restrict__ in, unsigned short* __restrict__ out,
    int K, int N, size_t inStride, size_t outStride) {
  __shared__ float tile[32][33];
  in += (size_t)blockIdx.z * inStride;
  out += (size_t)blockIdx.z * outStride;
  const int k0 = blockIdx.y * 32, n0 = blockIdx.x * 32;
  const int tr = threadIdx.x >> 3;         // 0..31
  const int tc4 = (threadIdx.x & 7) * 4;   // 0..28
  float4 vv = *(const float4*)&in[(size_t)(k0 + tr) * N + n0 + tc4];
  tile[tr][tc4 + 0] = vv.x; tile[tr][tc4 + 1] = vv.y;
  tile[tr][tc4 + 2] = vv.z; tile[tr][tc4 + 3] = vv.w;
  __syncthreads();
  ushort4 o4;
  o4.x = f2bf(tile[tc4 + 0][tr]); o4.y = f2bf(tile[tc4 + 1][tr]);
  o4.z = f2bf(tile[tc4 + 2][tr]); o4.w = f2bf(tile[tc4 + 3][tr]);
  *(ushort4*)&out[(size_t)(n0 + tr) * K + k0 + tc4] = o4;
}

// bias concat: [L][2048] = [bq|bk|bv|bg]
__global__ void bcat_kernel(const float* __restrict__ bq, const float* __restrict__ bk,
                            const float* __restrict__ bv, const float* __restrict__ bg,
                            float* __restrict__ out) {
  const int t = blockIdx.x * 256 + threadIdx.x;  // 8192
  const int l = t >> 11;
  const int c = t & 2047;
  float v;
  if (c < 512) v = bq[l * 512 + c];
  else if (c < 1024) v = bk[l * 512 + c - 512];
  else if (c < 1536) v = bv[l * 512 + c - 1024];
  else v = bg[l * 512 + c - 1536];
  out[t] = v;
}

// x = x_cgm @ cgm_W + cgm_b  -> fp32 X and bf16 Xb
__global__ __launch_bounds__(256) void embed_kernel(
    const float* __restrict__ xc, const float* __restrict__ W,
    const float* __restrict__ bias, float* __restrict__ x,
    unsigned short* __restrict__ xb) {
  const int idx = blockIdx.x * 256 + threadIdx.x;
  const int n = idx & (Dn - 1);
  const int m = idx >> 9;
  const float* xr = xc + m * FCn;
  float acc = bias[n];
  #pragma unroll
  for (int k = 0; k < FCn; ++k) acc = fmaf(xr[k], W[k * Dn + n], acc);
  x[idx] = acc;
  xb[idx] = f2bf(acc);
}

__global__ void relmean_kernel(const float* __restrict__ rel, float* __restrict__ rm) {
  const int p = blockIdx.x * blockDim.x + threadIdx.x;
  if (p >= 2 * MAXPOSn - 1) return;
  float s = 0.0f;
  #pragma unroll 8
  for (int d = 0; d < DKn; ++d) s += rel[p * DKn + d];
  rm[p] = s * (1.0f / DKn);
}

// ---------- bf16 MFMA GEMM: C = A[M,K] @ Bt[N,K]^T + bias ----------
template <int EPI>
__global__ __launch_bounds__(256) void mgemm(
    const unsigned short* __restrict__ A, const unsigned short* __restrict__ Bt,
    const float* __restrict__ bias, float* __restrict__ Cf,
    unsigned short* __restrict__ Cb, int M, int N, int K, int ldc) {
  __shared__ unsigned short As[128 * 32];
  __shared__ unsigned short Bs[128 * 32];
  const int t = threadIdx.x;
  const int w = t >> 6;
  const int lane = t & 63;
  const int n0 = blockIdx.x * 128;
  const int m0 = blockIdx.y * 128;
  const int wm = (w >> 1) * 64;
  const int wn = (w & 1) * 64;
  const int lr = lane & 15;
  const int lq = lane >> 4;

  floatx4 acc[4][4];
  #pragma unroll
  for (int i = 0; i < 4; ++i)
    #pragma unroll
    for (int j = 0; j < 4; ++j) acc[i][j] = (floatx4){0.f, 0.f, 0.f, 0.f};

  const int srow = lane >> 2;   // 0..15
  const int schk = (lane & 3) * 8;

  for (int k0 = 0; k0 < K; k0 += 32) {
    __syncthreads();
    #pragma unroll
    for (int r = 0; r < 2; ++r) {
      const int rb = (w * 2 + r) * 16;
      g2l16(&A[(size_t)(m0 + rb + srow) * K + k0 + schk], &As[rb * 32]);
      g2l16(&Bt[(size_t)(n0 + rb + srow) * K + k0 + schk], &Bs[rb * 32]);
    }
    __syncthreads();
    bf16x8 af[4], bf[4];
    #pragma unroll
    for (int i = 0; i < 4; ++i)
      af[i] = *(const bf16x8*)&As[(wm + i * 16 + lr) * 32 + lq * 8];
    #pragma unroll
    for (int j = 0; j < 4; ++j)
      bf[j] = *(const bf16x8*)&Bs[(wn + j * 16 + lr) * 32 + lq * 8];
    #pragma unroll
    for (int i = 0; i < 4; ++i)
      #pragma unroll
      for (int j = 0; j < 4; ++j)
        acc[i][j] = __builtin_amdgcn_mfma_f32_16x16x32_bf16(af[i], bf[j], acc[i][j], 0, 0, 0);
  }

  #pragma unroll
  for (int i = 0; i < 4; ++i) {
    const int row = m0 + wm + i * 16 + lq * 4;
    #pragma unroll
    for (int j = 0; j < 4; ++j) {
      const int col = n0 + wn + j * 16 + lr;
      const float bv = bias[col];
      #pragma unroll
      for (int r = 0; r < 4; ++r) {
        const float va = acc[i][j][r] + bv;
        if (EPI == 0) {
          Cf[(size_t)(row + r) * ldc + col] = va;
        } else if (EPI == 3) {
          Cb[(size_t)(row + r) * ldc + col] = f2bf(va);
        } else if (EPI == 2) {
          const size_t idx = (size_t)(row + r) * ldc + col;
          Cb[idx] = f2bf(b2f(Cb[idx]) * sigmoidf_(va));
        } else if (EPI == 4) {
          if (col < 1536) Cb[(size_t)(row + r) * 1536 + col] = f2bf(va);
          else Cf[(size_t)(row + r) * 512 + (col - 1536)] = sigmoidf_(va);
        }
      }
    }
  }
}

// ---------- MFMA flash attention ----------
// Block = (b, h, 64-query tile), 4 waves; wave owns 16 queries.
// qkv row stride 1536: [q(512)|k(512)|v(512)] bf16. ctx out bf16 [8192][512].
// Layouts (verified by passing mgemm): A=[m][k] frag: m=lane&15, k=(lane>>4)*8;
// B=[n][k] same; C/D: row=(lane>>4)*4+reg, col=lane&15.
__global__ __launch_bounds__(256) void attn_kernel(
    const unsigned short* __restrict__ qkv, const float* __restrict__ rm,
    unsigned short* __restrict__ ctx) {
  __shared__ unsigned short Ks[64 * 72];     // [key][dk], rows padded to 72
  __shared__ unsigned short Vt[64 * 72];     // [dk][key], rows padded to 72
  __shared__ unsigned short Pw[4][16 * 72];  // per-wave P tile [q][key]
  __shared__ float rml[576];                 // rel-bias cache rm[q0 .. q0+574]
  const int t = threadIdx.x;
  const int w = t >> 6;
  const int lane = t & 63;
  const int lr = lane & 15;
  const int lq = lane >> 4;
  const int bid = blockIdx.x;
  const int qt = bid & 7;
  const int h = (bid >> 3) & 7;
  const int b = bid >> 6;
  const int q0 = qt * 64;
  const size_t rowb = (size_t)b * Sn * 1536;

  for (int i = t; i < 576; i += 256) rml[i] = rm[q0 + i];

  // Q A-frags direct from global (once): Q[q0+w*16+lr][k]
  bf16x8 aq0, aq1;
  {
    const unsigned short* qp = &qkv[rowb + (size_t)(q0 + w * 16 + lr) * 1536 + h * 64 + lq * 8];
    aq0 = *(const bf16x8*)qp;
    aq1 = *(const bf16x8*)(qp + 32);
  }

  floatx4 o_acc[4];
  #pragma unroll
  for (int i = 0; i < 4; ++i) o_acc[i] = (floatx4){0.f, 0.f, 0.f, 0.f};
  float m_old[4] = {-1e30f, -1e30f, -1e30f, -1e30f};
  float l_sum[4] = {0.f, 0.f, 0.f, 0.f};

  const int skey = t >> 2;        // staging: key row 0..63
  const int schk = (t & 3) * 16;  // 16-short chunk
  const int vkp = t >> 4;         // V transpose: key-pair group
  const int vd4 = (t & 15) * 4;   // 4 dk values

  for (int kc = 0; kc < 8; ++kc) {
    __syncthreads();  // all waves done reading previous chunk
    {  // stage K [key][dk]
      const unsigned short* gk = &qkv[rowb + (size_t)(kc * 64 + skey) * 1536 + 512 + h * 64 + schk];
      *(bf16x8*)&Ks[skey * 72 + schk] = *(const bf16x8*)gk;
      *(bf16x8*)&Ks[skey * 72 + schk + 8] = *(const bf16x8*)(gk + 8);
    }
    #pragma unroll
    for (int pass = 0; pass < 2; ++pass) {  // stage V transposed [dk][key]
      const int kp = vkp + pass * 16;       // keys kp*2, kp*2+1
      const unsigned short* gv = &qkv[rowb + (size_t)(kc * 64 + kp * 2) * 1536 + 1024 + h * 64 + vd4];
      ushort4 v0 = *(const ushort4*)gv;
      ushort4 v1 = *(const ushort4*)(gv + 1536);
      *(ushort2*)&Vt[(vd4 + 0) * 72 + kp * 2] = make_ushort2(v0.x, v1.x);
      *(ushort2*)&Vt[(vd4 + 1) * 72 + kp * 2] = make_ushort2(v0.y, v1.y);
      *(ushort2*)&Vt[(vd4 + 2) * 72 + kp * 2] = make_ushort2(v0.z, v1.z);
      *(ushort2*)&Vt[(vd4 + 3) * 72 + kp * 2] = make_ushort2(v0.w, v1.w);
    }
    __syncthreads();

    // QK^T: S[q=16][key=64] per wave
    floatx4 s_acc[4];
    #pragma unroll
    for (int j = 0; j < 4; ++j) {
      bf16x8 b0 = *(const bf16x8*)&Ks[(j * 16 + lr) * 72 + lq * 8];
      bf16x8 b1 = *(const bf16x8*)&Ks[(j * 16 + lr) * 72 + 32 + lq * 8];
      s_acc[j] = __builtin_amdgcn_mfma_f32_16x16x32_bf16(aq0, b0, (floatx4){0.f, 0.f, 0.f, 0.f}, 0, 0, 0);
      s_acc[j] = __builtin_amdgcn_mfma_f32_16x16x32_bf16(aq1, b1, s_acc[j], 0, 0, 0);
    }

    // scale + rel bias; per-row chunk max
    float mloc[4] = {-1e30f, -1e30f, -1e30f, -1e30f};
    #pragma unroll
    for (int j = 0; j < 4; ++j) {
      const int key = kc * 64 + j * 16 + lr;
      #pragma unroll
      for (int r = 0; r < 4; ++r) {
        const float sv = s_acc[j][r] * 0.125f + rml[(w * 16 + lq * 4 + r) + 511 - key];
        s_acc[j][r] = sv;
        mloc[r] = fmaxf(mloc[r], sv);
      }
    }
    #pragma unroll
    for (int off = 1; off <= 8; off <<= 1)
      #pragma unroll
      for (int r = 0; r < 4; ++r) mloc[r] = fmaxf(mloc[r], __shfl_xor(mloc[r], off));

    float alpha[4], rsum[4];
    #pragma unroll
    for (int r = 0; r < 4; ++r) {
      const float mnew = fmaxf(m_old[r], mloc[r]);
      alpha[r] = __expf(m_old[r] - mnew);
      m_old[r] = mnew;
      rsum[r] = 0.f;
    }
    #pragma unroll
    for (int j = 0; j < 4; ++j)
      #pragma unroll
      for (int r = 0; r < 4; ++r) {
        const float p = __expf(s_acc[j][r] - m_old[r]);
        rsum[r] += p;
        Pw[w][(lq * 4 + r) * 72 + j * 16 + lr] = f2bf(p);
      }
    #pragma unroll
    for (int off = 1; off <= 8; off <<= 1)
      #pragma unroll
      for (int r = 0; r < 4; ++r) rsum[r] += __shfl_xor(rsum[r], off);
    #pragma unroll
    for (int r = 0; r < 4; ++r) l_sum[r] = l_sum[r] * alpha[r] + rsum[r];
    #pragma unroll
    for (int i = 0; i < 4; ++i)
      #pragma unroll
      for (int r = 0; r < 4; ++r) o_acc[i][r] *= alpha[r];

    // PV: O += P[16q x 64key] @ V[64key x 64d] (same-wave LDS round-trip, no barrier)
    bf16x8 ap0 = *(const bf16x8*)&Pw[w][lr * 72 + lq * 8];
    bf16x8 ap1 = *(const bf16x8*)&Pw[w][lr * 72 + 32 + lq * 8];
    #pragma unroll
    for (int i = 0; i < 4; ++i) {
      bf16x8 v0 = *(const bf16x8*)&Vt[(i * 16 + lr) * 72 + lq * 8];
      bf16x8 v1 = *(const bf16x8*)&Vt[(i * 16 + lr) * 72 + 32 + lq * 8];
      o_acc[i] = __builtin_amdgcn_mfma_f32_16x16x32_bf16(ap0, v0, o_acc[i], 0, 0, 0);
      o_acc[i] = __builtin_amdgcn_mfma_f32_16x16x32_bf16(ap1, v1, o_acc[i], 0, 0, 0);
    }
  }

  // normalize + store (C layout: row q = lq*4+r, col d = i*16+lr)
  float rinv[4];
  #pragma unroll
  for (int r = 0; r < 4; ++r) rinv[r] = 1.0f / l_sum[r];
  #pragma unroll
  for (int i = 0; i < 4; ++i)
    #pragma unroll
    for (int r = 0; r < 4; ++r) {
      const int q = q0 + w * 16 + lq * 4 + r;
      ctx[((size_t)(b * Sn + q)) * Dn + h * 64 + i * 16 + lr] = f2bf(o_acc[i][r] * rinv[r]);
    }
}

// x = LN(x + (gate? gate*add : add)) in-place; also writes bf16 mirror xb
template <int HASGATE>
__global__ __launch_bounds__(256) void ln_res_kernel(
    float* __restrict__ x, unsigned short* __restrict__ xb,
    const float* __restrict__ add, const float* __restrict__ gate,
    const float* __restrict__ s, const float* __restrict__ bsh) {
  const int row = blockIdx.x;
  const int t = threadIdx.x;
  const size_t base = (size_t)row * Dn;
  float y0 = x[base + t];
  float y1 = x[base + t + 256];
  float a0 = add[base + t];
  float a1 = add[base + t + 256];
  if (HASGATE) {
    a0 *= gate[base + t];
    a1 *= gate[base + t + 256];
  }
  y0 += a0;
  y1 += a1;
  const float mu = blockReduceSum(y0 + y1) * (1.0f / Dn);
  const float d0 = y0 - mu, d1 = y1 - mu;
  const float var = blockReduceSum(d0 * d0 + d1 * d1) * (1.0f / Dn);
  const float rstd = rsqrtf(var + EPSf);
  const float o0 = d0 * rstd * s[t] + bsh[t];
  const float o1 = d1 * rstd * s[t + 256] + bsh[t + 256];
  x[base + t] = o0;
  x[base + t + 256] = o1;
  xb[base + t] = f2bf(o0);
  xb[base + t + 256] = f2bf(o1);
}

__global__ __launch_bounds__(256) void meanpool_kernel(const float* __restrict__ x,
                                                       float* __restrict__ h) {
  const int idx = blockIdx.x * 256 + threadIdx.x;  // 8192
  const int b = idx >> 9;
  const int d = idx & 511;
  float s = 0.0f;
  for (int si = 0; si < Sn; ++si) s += x[((size_t)(b * Sn + si)) * Dn + d];
  h[b * 1024 + d] = s * (1.0f / Sn);
}

__global__ __launch_bounds__(256) void xo_kernel(const float* __restrict__ xo,
                                                 const float* __restrict__ W,
                                                 const float* __restrict__ bias,
                                                 float* __restrict__ h) {
  const int idx = blockIdx.x * 256 + threadIdx.x;  // 8192
  const int b = idx >> 9;
  const int n = idx & 511;
  float acc = bias[n];
  #pragma unroll
  for (int k = 0; k < FOn; ++k) acc = fmaf(xo[b * FOn + k], W[k * Dn + n], acc);
  h[b * 1024 + 512 + n] = acc;
}

__global__ __launch_bounds__(256) void f1_kernel(
    const float* __restrict__ h, const float* __restrict__ W,
    const float* __restrict__ bias, const float* __restrict__ s,
    const float* __restrict__ bt, float* __restrict__ o) {
  const int b = blockIdx.x;
  const int n = threadIdx.x;  // 256
  float acc = bias[n];
  for (int k = 0; k < 2 * Dn; ++k) acc = fmaf(h[b * 1024 + k], W[k * 256 + n], acc);
  const float mu = blockReduceSum(acc) * (1.0f / 256.0f);
  const float d = acc - mu;
  const float var = blockReduceSum(d * d) * (1.0f / 256.0f);
  const float y = d * rsqrtf(var + EPSf) * s[n] + bt[n];
  o[b * 256 + n] = fmaxf(y, 0.0f);
}

__global__ __launch_bounds__(128) void f2_kernel(
    const float* __restrict__ h1, const float* __restrict__ W,
    const float* __restrict__ bias, const float* __restrict__ s,
    const float* __restrict__ bt, float* __restrict__ o) {
  const int b = blockIdx.x;
  const int n = threadIdx.x;  // 128
  float acc = bias[n];
  for (int k = 0; k < 256; ++k) acc = fmaf(h1[b * 256 + k], W[k * 128 + n], acc);
  const float mu = blockReduceSum(acc) * (1.0f / 128.0f);
  const float d = acc - mu;
  const float var = blockReduceSum(d * d) * (1.0f / 128.0f);
  const float y = d * rsqrtf(var + EPSf) * s[n] + bt[n];
  o[b * 128 + n] = fmaxf(y, 0.0f);
}

__global__ __launch_bounds__(128) void f3_kernel(const float* __restrict__ h2,
                                                 const float* __restrict__ W,
                                                 const float* __restrict__ bias,
                                                 float* __restrict__ o) {
  const int b = blockIdx.x;
  const int t = threadIdx.x;  // 128
  float v = h2[b * 128 + t] * W[t];
  v = blockReduceSum(v);
  if (t == 0) o[b] = v + bias[0];
}

extern "C" void kernel_launch(void* const* d_in, const int* in_sizes, int n_in,
                              void* d_out, int out_size, void* d_ws, size_t ws_size,
                              hipStream_t stream) {
  (void)in_sizes; (void)n_in; (void)out_size; (void)ws_size;
  const float* x_cgm  = (const float*)d_in[0];
  const float* x_other= (const float*)d_in[1];
  const float* cgm_W  = (const float*)d_in[2];
  const float* cgm_b  = (const float*)d_in[3];
  const float* rel_emb= (const float*)d_in[4];
  const float* Wq = (const float*)d_in[5];
  const float* bq = (const float*)d_in[6];
  const float* Wk = (const float*)d_in[7];
  const float* bk = (const float*)d_in[8];
  const float* Wv = (const float*)d_in[9];
  const float* bv = (const float*)d_in[10];
  const float* Wo = (const float*)d_in[11];
  const float* bo = (const float*)d_in[12];
  const float* Wg = (const float*)d_in[13];
  const float* bg = (const float*)d_in[14];
  const float* Wf1 = (const float*)d_in[15];
  const float* bf1 = (const float*)d_in[16];
  const float* Wfg = (const float*)d_in[17];
  const float* bfg = (const float*)d_in[18];
  const float* Wf2 = (const float*)d_in[19];
  const float* bf2 = (const float*)d_in[20];
  const float* ln1_s = (const float*)d_in[21];
  const float* ln1_b = (const float*)d_in[22];
  const float* ln2_s = (const float*)d_in[23];
  const float* ln2_b = (const float*)d_in[24];
  const float* other_W = (const float*)d_in[25];
  const float* other_b = (const float*)d_in[26];
  const float* fW1 = (const float*)d_in[27];
  const float* fb1 = (const float*)d_in[28];
  const float* fln1_s = (const float*)d_in[29];
  const float* fln1_b = (const float*)d_in[30];
  const float* fW2 = (const float*)d_in[31];
  const float* fb2 = (const float*)d_in[32];
  const float* fln2_s = (const float*)d_in[33];
  const float* fln2_b = (const float*)d_in[34];
  const float* fW3 = (const float*)d_in[35];
  const float* fb3 = (const float*)d_in[36];
  float* out = (float*)d_out;

  char* p = (char*)d_ws;
  auto alloc = [&](size_t bytes) { char* r = p; p += (bytes + 255) & ~(size_t)255; return r; };
  float*          X      = (float*)alloc((size_t)8192 * 512 * 4);
  unsigned short* Xb     = (unsigned short*)alloc((size_t)8192 * 512 * 2);
  unsigned short* QKVb   = (unsigned short*)alloc((size_t)8192 * 1536 * 2);  // also CTXo f32
  unsigned short* CTXb   = (unsigned short*)alloc((size_t)8192 * 512 * 2);
  char*           R      = alloc((size_t)8192 * 2048 * 4);
  float*          ATTb   = (float*)R;
  float*          GATEb  = (float*)(R + (size_t)8192 * 512 * 4);
  unsigned short* FFBh   = (unsigned short*)R;
  float*          CTXo   = (float*)QKVb;
  unsigned short* Wqkvgt = (unsigned short*)alloc((size_t)4 * 2048 * 512 * 2);
  unsigned short* Wot    = (unsigned short*)alloc((size_t)4 * 512 * 512 * 2);
  unsigned short* Wf1t   = (unsigned short*)alloc((size_t)4 * 2048 * 512 * 2);
  unsigned short* Wfgt   = (unsigned short*)alloc((size_t)4 * 2048 * 512 * 2);
  unsigned short* Wf2t   = (unsigned short*)alloc((size_t)4 * 512 * 2048 * 2);
  float*          bqkvg  = (float*)alloc((size_t)4 * 2048 * 4);
  float*          RMb    = (float*)alloc(1024 * 4);
  float*          Hb     = (float*)alloc(16 * 1024 * 4);
  float*          H1b    = (float*)alloc(16 * 256 * 4);
  float*          H2b    = (float*)alloc(16 * 128 * 4);

  wconv_kernel<<<dim3(16, 16, 4), 256, 0, stream>>>(Wq, Wqkvgt + (size_t)0 * 512, 512, 512,
                                                    (size_t)512 * 512, (size_t)2048 * 512);
  wconv_kernel<<<dim3(16, 16, 4), 256, 0, stream>>>(Wk, Wqkvgt + (size_t)512 * 512, 512, 512,
                                                    (size_t)512 * 512, (size_t)2048 * 512);
  wconv_kernel<<<dim3(16, 16, 4), 256, 0, stream>>>(Wv, Wqkvgt + (size_t)1024 * 512, 512, 512,
                                                    (size_t)512 * 512, (size_t)2048 * 512);
  wconv_kernel<<<dim3(16, 16, 4), 256, 0, stream>>>(Wg, Wqkvgt + (size_t)1536 * 512, 512, 512,
                                                    (size_t)512 * 512, (size_t)2048 * 512);
  wconv_kernel<<<dim3(16, 16, 4), 256, 0, stream>>>(Wo, Wot, 512, 512,
                                                    (size_t)512 * 512, (size_t)512 * 512);
  wconv_kernel<<<dim3(64, 16, 4), 256, 0, stream>>>(Wf1, Wf1t, 512, 2048,
                                                    (size_t)512 * 2048, (size_t)2048 * 512);
  wconv_kernel<<<dim3(64, 16, 4), 256, 0, stream>>>(Wfg, Wfgt, 512, 2048,
                                                    (size_t)512 * 2048, (size_t)2048 * 512);
  wconv_kernel<<<dim3(16, 64, 4), 256, 0, stream>>>(Wf2, Wf2t, 2048, 512,
                                                    (size_t)2048 * 512, (size_t)512 * 2048);
  bcat_kernel<<<dim3(32), 256, 0, stream>>>(bq, bk, bv, bg, bqkvg);

  embed_kernel<<<dim3(16384), dim3(256), 0, stream>>>(x_cgm, cgm_W, cgm_b, X, Xb);
  relmean_kernel<<<dim3(4), dim3(256), 0, stream>>>(rel_emb, RMb);

  for (int l = 0; l < Ln; ++l) {
    const size_t bof = (size_t)l * Dn;
    mgemm<4><<<dim3(16, 64), 256, 0, stream>>>(Xb, Wqkvgt + (size_t)l * 2048 * 512,
                                               bqkvg + (size_t)l * 2048, GATEb, QKVb,
                                               8192, 2048, 512, 0);
    attn_kernel<<<dim3(1024), dim3(256), 0, stream>>>(QKVb, RMb, CTXb);
    mgemm<0><<<dim3(4, 64), 256, 0, stream>>>(CTXb, Wot + (size_t)l * 512 * 512,
                                              bo + bof, ATTb, nullptr, 8192, 512, 512, 512);
    ln_res_kernel<1><<<dim3(8192), 256, 0, stream>>>(X, Xb, ATTb, GATEb, ln1_s + bof, ln1_b + bof);
    mgemm<3><<<dim3(16, 64), 256, 0, stream>>>(Xb, Wf1t + (size_t)l * 2048 * 512,
                                               bf1 + (size_t)l * FFn, nullptr, FFBh,
                                               8192, 2048, 512, 2048);
    mgemm<2><<<dim3(16, 64), 256, 0, stream>>>(Xb, Wfgt + (size_t)l * 2048 * 512,
                                               bfg + (size_t)l * FFn, nullptr, FFBh,
                                               8192, 2048, 512, 2048);
    mgemm<0><<<dim3(4, 64), 256, 0, stream>>>(FFBh, Wf2t + (size_t)l * 512 * 2048,
                                              bf2 + bof, CTXo, nullptr, 8192, 512, 2048, 512);
    ln_res_kernel<0><<<dim3(8192), 256, 0, stream>>>(X, Xb, CTXo, nullptr, ln2_s + bof, ln2_b + bof);
  }

  meanpool_kernel<<<dim3(32), dim3(256), 0, stream>>>(X, Hb);
  xo_kernel<<<dim3(32), dim3(256), 0, stream>>>(x_other, other_W, other_b, Hb);
  f1_kernel<<<dim3(16), dim3(256), 0, stream>>>(Hb, fW1, fb1, fln1_s, fln1_b, H1b);
  f2_kernel<<<dim3(16), dim3(128), 0, stream>>>(H1b, fW2, fb2, fln2_s, fln2_b, H2b);
  f3_kernel<<<dim3(16), dim3(128), 0, stream>>>(H2b, fW3, fb3, out);
}

// Round 4
// 1332.434 us; speedup vs baseline: 5.0756x; 1.0343x over previous
//
#include <hip/hip_runtime.h>
#include <math.h>

constexpr int Bn = 16;
constexpr int Sn = 512;
constexpr int FCn = 24;
constexpr int FOn = 16;
constexpr int Dn = 512;
constexpr int Hn = 8;
constexpr int DKn = 64;
constexpr int FFn = 2048;
constexpr int Ln = 4;
constexpr int MAXPOSn = 512;
constexpr float EPSf = 1e-6f;

typedef __attribute__((ext_vector_type(8))) short bf16x8;   // 8 bf16 in 4 VGPRs
typedef __attribute__((ext_vector_type(4))) float floatx4;

__device__ __forceinline__ float sigmoidf_(float x) { return 1.0f / (1.0f + __expf(-x)); }

__device__ __forceinline__ unsigned short f2bf(float f) {  // RNE
  unsigned int u = __float_as_uint(f);
  u += 0x7fffu + ((u >> 16) & 1u);
  return (unsigned short)(u >> 16);
}
__device__ __forceinline__ float b2f(unsigned short b) {
  return __uint_as_float(((unsigned int)b) << 16);
}

__device__ __forceinline__ void g2l16(const void* g, void* l) {
  // async global->LDS, 16B/lane, LDS dest = wave-uniform base + lane*16
  __builtin_amdgcn_global_load_lds((const __attribute__((address_space(1))) void*)g,
                                   (__attribute__((address_space(3))) void*)l, 16, 0, 0);
}

// pair-pack bf16 store: even lane stores {self, lane^1} as one dword.
// `dst` must be the even lane's element address. All lanes must execute (shfl).
__device__ __forceinline__ void st_bf16_pair(unsigned short* dst, float v, int lane) {
  unsigned int us = f2bf(v);
  unsigned int other = (unsigned int)__shfl_xor((int)us, 1);
  if (!(lane & 1)) *(unsigned int*)dst = us | (other << 16);
}

__device__ __forceinline__ float blockReduceSum(float v) {
  #pragma unroll
  for (int off = 32; off >= 1; off >>= 1) v += __shfl_xor(v, off);
  __shared__ float red[8];
  const int w = threadIdx.x >> 6;
  const int nw = blockDim.x >> 6;
  if ((threadIdx.x & 63) == 0) red[w] = v;
  __syncthreads();
  float r = 0.0f;
  for (int i = 0; i < nw; ++i) r += red[i];
  __syncthreads();
  return r;
}

// ---------- weight transpose-convert: out[n][k] bf16 = in[k][n] f32 ----------
__global__ __launch_bounds__(256) void wconv_kernel(
    const float* __restrict__ in, unsigned short* __restrict__ out,
    int K, int N, size_t inStride, size_t outStride) {
  __shared__ float tile[32][33];
  in += (size_t)blockIdx.z * inStride;
  out += (size_t)blockIdx.z * outStride;
  const int k0 = blockIdx.y * 32, n0 = blockIdx.x * 32;
  const int tr = threadIdx.x >> 3;         // 0..31
  const int tc4 = (threadIdx.x & 7) * 4;   // 0..28
  float4 vv = *(const float4*)&in[(size_t)(k0 + tr) * N + n0 + tc4];
  tile[tr][tc4 + 0] = vv.x; tile[tr][tc4 + 1] = vv.y;
  tile[tr][tc4 + 2] = vv.z; tile[tr][tc4 + 3] = vv.w;
  __syncthreads();
  ushort4 o4;
  o4.x = f2bf(tile[tc4 + 0][tr]); o4.y = f2bf(tile[tc4 + 1][tr]);
  o4.z = f2bf(tile[tc4 + 2][tr]); o4.w = f2bf(tile[tc4 + 3][tr]);
  *(ushort4*)&out[(size_t)(n0 + tr) * K + k0 + tc4] = o4;
}

// bias concat: [L][2048] = [bq|bk|bv|bg]
__global__ void bcat_kernel(const float* __restrict__ bq, const float* __restrict__ bk,
                            const float* __restrict__ bv, const float* __restrict__ bg,
                            float* __restrict__ out) {
  const int t = blockIdx.x * 256 + threadIdx.x;  // 8192
  const int l = t >> 11;
  const int c = t & 2047;
  float v;
  if (c < 512) v = bq[l * 512 + c];
  else if (c < 1024) v = bk[l * 512 + c - 512];
  else if (c < 1536) v = bv[l * 512 + c - 1024];
  else v = bg[l * 512 + c - 1536];
  out[t] = v;
}

// x = x_cgm @ cgm_W + cgm_b  -> fp32 X and bf16 Xb
__global__ __launch_bounds__(256) void embed_kernel(
    const float* __restrict__ xc, const float* __restrict__ W,
    const float* __restrict__ bias, float* __restrict__ x,
    unsigned short* __restrict__ xb) {
  const int idx = blockIdx.x * 256 + threadIdx.x;
  const int n = idx & (Dn - 1);
  const int m = idx >> 9;
  const float* xr = xc + m * FCn;
  float acc = bias[n];
  #pragma unroll
  for (int k = 0; k < FCn; ++k) acc = fmaf(xr[k], W[k * Dn + n], acc);
  x[idx] = acc;
  xb[idx] = f2bf(acc);
}

__global__ void relmean_kernel(const float* __restrict__ rel, float* __restrict__ rm) {
  const int p = blockIdx.x * blockDim.x + threadIdx.x;
  if (p >= 2 * MAXPOSn - 1) return;
  float s = 0.0f;
  #pragma unroll 8
  for (int d = 0; d < DKn; ++d) s += rel[p * DKn + d];
  rm[p] = s * (1.0f / DKn);
}

// ---------- bf16 MFMA GEMM: C = A[M,K(slice)] @ Bt[N,K]^T (+ bias) ----------
// 128x128 tile, BK=32. EPI: 0 = fp32 +bias; 3 = bf16 +bias (pair-packed);
// 4 = qkvg: cols<1536 -> bf16 Cb (ld 1536), cols>=1536 -> bf16 sigmoid Cb2 (ld 512);
// 5 = fp32 accumulate into Cf (no bias) — split-K second pass.
template <int EPI>
__global__ __launch_bounds__(256) void mgemm(
    const unsigned short* __restrict__ A, const unsigned short* __restrict__ Bt,
    const float* __restrict__ bias, float* __restrict__ Cf,
    unsigned short* __restrict__ Cb, unsigned short* __restrict__ Cb2,
    int Astride, int N, int Koff, int Klen, int ldc) {
  __shared__ unsigned short As[128 * 32];
  __shared__ unsigned short Bs[128 * 32];
  const int t = threadIdx.x;
  const int w = t >> 6;
  const int lane = t & 63;
  const int n0 = blockIdx.x * 128;
  const int m0 = blockIdx.y * 128;
  const int wm = (w >> 1) * 64;
  const int wn = (w & 1) * 64;
  const int lr = lane & 15;
  const int lq = lane >> 4;

  floatx4 acc[4][4];
  #pragma unroll
  for (int i = 0; i < 4; ++i)
    #pragma unroll
    for (int j = 0; j < 4; ++j) acc[i][j] = (floatx4){0.f, 0.f, 0.f, 0.f};

  const int srow = lane >> 2;   // 0..15
  const int schk = (lane & 3) * 8;

  for (int k0 = Koff; k0 < Koff + Klen; k0 += 32) {
    __syncthreads();
    #pragma unroll
    for (int r = 0; r < 2; ++r) {
      const int rb = (w * 2 + r) * 16;
      g2l16(&A[(size_t)(m0 + rb + srow) * Astride + k0 + schk], &As[rb * 32]);
      g2l16(&Bt[(size_t)(n0 + rb + srow) * Astride + k0 + schk], &Bs[rb * 32]);
    }
    __syncthreads();
    bf16x8 af[4], bf[4];
    #pragma unroll
    for (int i = 0; i < 4; ++i)
      af[i] = *(const bf16x8*)&As[(wm + i * 16 + lr) * 32 + lq * 8];
    #pragma unroll
    for (int j = 0; j < 4; ++j)
      bf[j] = *(const bf16x8*)&Bs[(wn + j * 16 + lr) * 32 + lq * 8];
    #pragma unroll
    for (int i = 0; i < 4; ++i)
      #pragma unroll
      for (int j = 0; j < 4; ++j)
        acc[i][j] = __builtin_amdgcn_mfma_f32_16x16x32_bf16(af[i], bf[j], acc[i][j], 0, 0, 0);
  }

  // C/D layout: col = lane&15, row = (lane>>4)*4 + reg
  #pragma unroll
  for (int i = 0; i < 4; ++i) {
    const int row = m0 + wm + i * 16 + lq * 4;
    #pragma unroll
    for (int j = 0; j < 4; ++j) {
      const int col = n0 + wn + j * 16 + lr;
      const int colp = col & ~1;  // even lane's column for pair-pack
      #pragma unroll
      for (int r = 0; r < 4; ++r) {
        if (EPI == 0) {
          Cf[(size_t)(row + r) * ldc + col] = acc[i][j][r] + bias[col];
        } else if (EPI == 5) {
          const size_t idx = (size_t)(row + r) * ldc + col;
          Cf[idx] += acc[i][j][r];
        } else if (EPI == 3) {
          st_bf16_pair(&Cb[(size_t)(row + r) * ldc + colp], acc[i][j][r] + bias[col], lane);
        } else if (EPI == 4) {
          const float va = acc[i][j][r] + bias[col];
          if (col < 1536)
            st_bf16_pair(&Cb[(size_t)(row + r) * 1536 + colp], va, lane);
          else
            st_bf16_pair(&Cb2[(size_t)(row + r) * 512 + (colp - 1536)], sigmoidf_(va), lane);
        }
      }
    }
  }
}

// ---------- fused gated FF: C = (A@W1+b1) * sigmoid(A@W2+b2), bf16 out ----------
// Block 128m x 64n (grid 32x64); wave = 64m x 32n per output; dual B staging.
__global__ __launch_bounds__(256) void ffgemm(
    const unsigned short* __restrict__ A, const unsigned short* __restrict__ B1t,
    const unsigned short* __restrict__ B2t, const float* __restrict__ b1,
    const float* __restrict__ b2, unsigned short* __restrict__ C, int K) {
  __shared__ unsigned short As[128 * 32];
  __shared__ unsigned short B1s[64 * 32];
  __shared__ unsigned short B2s[64 * 32];
  const int t = threadIdx.x;
  const int w = t >> 6;
  const int lane = t & 63;
  const int n0 = blockIdx.x * 64;
  const int m0 = blockIdx.y * 128;
  const int wm = (w >> 1) * 64;
  const int wn = (w & 1) * 32;
  const int lr = lane & 15;
  const int lq = lane >> 4;

  floatx4 a1[4][2], a2[4][2];
  #pragma unroll
  for (int i = 0; i < 4; ++i)
    #pragma unroll
    for (int j = 0; j < 2; ++j) {
      a1[i][j] = (floatx4){0.f, 0.f, 0.f, 0.f};
      a2[i][j] = (floatx4){0.f, 0.f, 0.f, 0.f};
    }

  const int srow = lane >> 2;
  const int schk = (lane & 3) * 8;

  for (int k0 = 0; k0 < K; k0 += 32) {
    __syncthreads();
    g2l16(&A[(size_t)(m0 + w * 32 + srow) * K + k0 + schk], &As[(w * 32) * 32]);
    g2l16(&A[(size_t)(m0 + w * 32 + 16 + srow) * K + k0 + schk], &As[(w * 32 + 16) * 32]);
    g2l16(&B1t[(size_t)(n0 + w * 16 + srow) * K + k0 + schk], &B1s[(w * 16) * 32]);
    g2l16(&B2t[(size_t)(n0 + w * 16 + srow) * K + k0 + schk], &B2s[(w * 16) * 32]);
    __syncthreads();
    bf16x8 af[4], f1[2], f2[2];
    #pragma unroll
    for (int i = 0; i < 4; ++i)
      af[i] = *(const bf16x8*)&As[(wm + i * 16 + lr) * 32 + lq * 8];
    #pragma unroll
    for (int j = 0; j < 2; ++j) {
      f1[j] = *(const bf16x8*)&B1s[(wn + j * 16 + lr) * 32 + lq * 8];
      f2[j] = *(const bf16x8*)&B2s[(wn + j * 16 + lr) * 32 + lq * 8];
    }
    #pragma unroll
    for (int i = 0; i < 4; ++i)
      #pragma unroll
      for (int j = 0; j < 2; ++j) {
        a1[i][j] = __builtin_amdgcn_mfma_f32_16x16x32_bf16(af[i], f1[j], a1[i][j], 0, 0, 0);
        a2[i][j] = __builtin_amdgcn_mfma_f32_16x16x32_bf16(af[i], f2[j], a2[i][j], 0, 0, 0);
      }
  }

  #pragma unroll
  for (int i = 0; i < 4; ++i) {
    const int row = m0 + wm + i * 16 + lq * 4;
    #pragma unroll
    for (int j = 0; j < 2; ++j) {
      const int col = n0 + wn + j * 16 + lr;
      const int colp = col & ~1;
      const float bb1 = b1[col], bb2 = b2[col];
      #pragma unroll
      for (int r = 0; r < 4; ++r) {
        const float f = (a1[i][j][r] + bb1) * sigmoidf_(a2[i][j][r] + bb2);
        st_bf16_pair(&C[(size_t)(row + r) * 2048 + colp], f, lane);
      }
    }
  }
}

// ---------- MFMA flash attention (unchanged from round 3) ----------
__global__ __launch_bounds__(256) void attn_kernel(
    const unsigned short* __restrict__ qkv, const float* __restrict__ rm,
    unsigned short* __restrict__ ctx) {
  __shared__ unsigned short Ks[64 * 72];
  __shared__ unsigned short Vt[64 * 72];
  __shared__ unsigned short Pw[4][16 * 72];
  __shared__ float rml[576];
  const int t = threadIdx.x;
  const int w = t >> 6;
  const int lane = t & 63;
  const int lr = lane & 15;
  const int lq = lane >> 4;
  const int bid = blockIdx.x;
  const int qt = bid & 7;
  const int h = (bid >> 3) & 7;
  const int b = bid >> 6;
  const int q0 = qt * 64;
  const size_t rowb = (size_t)b * Sn * 1536;

  for (int i = t; i < 576; i += 256) rml[i] = rm[q0 + i];

  bf16x8 aq0, aq1;
  {
    const unsigned short* qp = &qkv[rowb + (size_t)(q0 + w * 16 + lr) * 1536 + h * 64 + lq * 8];
    aq0 = *(const bf16x8*)qp;
    aq1 = *(const bf16x8*)(qp + 32);
  }

  floatx4 o_acc[4];
  #pragma unroll
  for (int i = 0; i < 4; ++i) o_acc[i] = (floatx4){0.f, 0.f, 0.f, 0.f};
  float m_old[4] = {-1e30f, -1e30f, -1e30f, -1e30f};
  float l_sum[4] = {0.f, 0.f, 0.f, 0.f};

  const int skey = t >> 2;
  const int schk = (t & 3) * 16;
  const int vkp = t >> 4;
  const int vd4 = (t & 15) * 4;

  for (int kc = 0; kc < 8; ++kc) {
    __syncthreads();
    {
      const unsigned short* gk = &qkv[rowb + (size_t)(kc * 64 + skey) * 1536 + 512 + h * 64 + schk];
      *(bf16x8*)&Ks[skey * 72 + schk] = *(const bf16x8*)gk;
      *(bf16x8*)&Ks[skey * 72 + schk + 8] = *(const bf16x8*)(gk + 8);
    }
    #pragma unroll
    for (int pass = 0; pass < 2; ++pass) {
      const int kp = vkp + pass * 16;
      const unsigned short* gv = &qkv[rowb + (size_t)(kc * 64 + kp * 2) * 1536 + 1024 + h * 64 + vd4];
      ushort4 v0 = *(const ushort4*)gv;
      ushort4 v1 = *(const ushort4*)(gv + 1536);
      *(ushort2*)&Vt[(vd4 + 0) * 72 + kp * 2] = make_ushort2(v0.x, v1.x);
      *(ushort2*)&Vt[(vd4 + 1) * 72 + kp * 2] = make_ushort2(v0.y, v1.y);
      *(ushort2*)&Vt[(vd4 + 2) * 72 + kp * 2] = make_ushort2(v0.z, v1.z);
      *(ushort2*)&Vt[(vd4 + 3) * 72 + kp * 2] = make_ushort2(v0.w, v1.w);
    }
    __syncthreads();

    floatx4 s_acc[4];
    #pragma unroll
    for (int j = 0; j < 4; ++j) {
      bf16x8 b0 = *(const bf16x8*)&Ks[(j * 16 + lr) * 72 + lq * 8];
      bf16x8 b1 = *(const bf16x8*)&Ks[(j * 16 + lr) * 72 + 32 + lq * 8];
      s_acc[j] = __builtin_amdgcn_mfma_f32_16x16x32_bf16(aq0, b0, (floatx4){0.f, 0.f, 0.f, 0.f}, 0, 0, 0);
      s_acc[j] = __builtin_amdgcn_mfma_f32_16x16x32_bf16(aq1, b1, s_acc[j], 0, 0, 0);
    }

    float mloc[4] = {-1e30f, -1e30f, -1e30f, -1e30f};
    #pragma unroll
    for (int j = 0; j < 4; ++j) {
      const int key = kc * 64 + j * 16 + lr;
      #pragma unroll
      for (int r = 0; r < 4; ++r) {
        const float sv = s_acc[j][r] * 0.125f + rml[(w * 16 + lq * 4 + r) + 511 - key];
        s_acc[j][r] = sv;
        mloc[r] = fmaxf(mloc[r], sv);
      }
    }
    #pragma unroll
    for (int off = 1; off <= 8; off <<= 1)
      #pragma unroll
      for (int r = 0; r < 4; ++r) mloc[r] = fmaxf(mloc[r], __shfl_xor(mloc[r], off));

    float alpha[4], rsum[4];
    #pragma unroll
    for (int r = 0; r < 4; ++r) {
      const float mnew = fmaxf(m_old[r], mloc[r]);
      alpha[r] = __expf(m_old[r] - mnew);
      m_old[r] = mnew;
      rsum[r] = 0.f;
    }
    #pragma unroll
    for (int j = 0; j < 4; ++j)
      #pragma unroll
      for (int r = 0; r < 4; ++r) {
        const float p = __expf(s_acc[j][r] - m_old[r]);
        rsum[r] += p;
        Pw[w][(lq * 4 + r) * 72 + j * 16 + lr] = f2bf(p);
      }
    #pragma unroll
    for (int off = 1; off <= 8; off <<= 1)
      #pragma unroll
      for (int r = 0; r < 4; ++r) rsum[r] += __shfl_xor(rsum[r], off);
    #pragma unroll
    for (int r = 0; r < 4; ++r) l_sum[r] = l_sum[r] * alpha[r] + rsum[r];
    #pragma unroll
    for (int i = 0; i < 4; ++i)
      #pragma unroll
      for (int r = 0; r < 4; ++r) o_acc[i][r] *= alpha[r];

    bf16x8 ap0 = *(const bf16x8*)&Pw[w][lr * 72 + lq * 8];
    bf16x8 ap1 = *(const bf16x8*)&Pw[w][lr * 72 + 32 + lq * 8];
    #pragma unroll
    for (int i = 0; i < 4; ++i) {
      bf16x8 v0 = *(const bf16x8*)&Vt[(i * 16 + lr) * 72 + lq * 8];
      bf16x8 v1 = *(const bf16x8*)&Vt[(i * 16 + lr) * 72 + 32 + lq * 8];
      o_acc[i] = __builtin_amdgcn_mfma_f32_16x16x32_bf16(ap0, v0, o_acc[i], 0, 0, 0);
      o_acc[i] = __builtin_amdgcn_mfma_f32_16x16x32_bf16(ap1, v1, o_acc[i], 0, 0, 0);
    }
  }

  float rinv[4];
  #pragma unroll
  for (int r = 0; r < 4; ++r) rinv[r] = 1.0f / l_sum[r];
  #pragma unroll
  for (int i = 0; i < 4; ++i)
    #pragma unroll
    for (int r = 0; r < 4; ++r) {
      const int q = q0 + w * 16 + lq * 4 + r;
      ctx[((size_t)(b * Sn + q)) * Dn + h * 64 + i * 16 + lr] = f2bf(o_acc[i][r] * rinv[r]);
    }
}

// ln1: x = LN(x + gate*att), att/gate bf16
__global__ __launch_bounds__(256) void ln_res1_kernel(
    float* __restrict__ x, unsigned short* __restrict__ xb,
    const unsigned short* __restrict__ att, const unsigned short* __restrict__ gate,
    const float* __restrict__ s, const float* __restrict__ bsh) {
  const int row = blockIdx.x;
  const int t = threadIdx.x;
  const size_t base = (size_t)row * Dn;
  float y0 = x[base + t] + b2f(att[base + t]) * b2f(gate[base + t]);
  float y1 = x[base + t + 256] + b2f(att[base + t + 256]) * b2f(gate[base + t + 256]);
  const float mu = blockReduceSum(y0 + y1) * (1.0f / Dn);
  const float d0 = y0 - mu, d1 = y1 - mu;
  const float var = blockReduceSum(d0 * d0 + d1 * d1) * (1.0f / Dn);
  const float rstd = rsqrtf(var + EPSf);
  const float o0 = d0 * rstd * s[t] + bsh[t];
  const float o1 = d1 * rstd * s[t + 256] + bsh[t + 256];
  x[base + t] = o0;
  x[base + t + 256] = o1;
  xb[base + t] = f2bf(o0);
  xb[base + t + 256] = f2bf(o1);
}

// ln2: x = LN(x + add), add fp32
__global__ __launch_bounds__(256) void ln_res2_kernel(
    float* __restrict__ x, unsigned short* __restrict__ xb,
    const float* __restrict__ add, const float* __restrict__ s,
    const float* __restrict__ bsh) {
  const int row = blockIdx.x;
  const int t = threadIdx.x;
  const size_t base = (size_t)row * Dn;
  float y0 = x[base + t] + add[base + t];
  float y1 = x[base + t + 256] + add[base + t + 256];
  const float mu = blockReduceSum(y0 + y1) * (1.0f / Dn);
  const float d0 = y0 - mu, d1 = y1 - mu;
  const float var = blockReduceSum(d0 * d0 + d1 * d1) * (1.0f / Dn);
  const float rstd = rsqrtf(var + EPSf);
  const float o0 = d0 * rstd * s[t] + bsh[t];
  const float o1 = d1 * rstd * s[t + 256] + bsh[t + 256];
  x[base + t] = o0;
  x[base + t + 256] = o1;
  xb[base + t] = f2bf(o0);
  xb[base + t + 256] = f2bf(o1);
}

__global__ __launch_bounds__(256) void meanpool_kernel(const float* __restrict__ x,
                                                       float* __restrict__ h) {
  const int idx = blockIdx.x * 256 + threadIdx.x;  // 8192
  const int b = idx >> 9;
  const int d = idx & 511;
  float s = 0.0f;
  for (int si = 0; si < Sn; ++si) s += x[((size_t)(b * Sn + si)) * Dn + d];
  h[b * 1024 + d] = s * (1.0f / Sn);
}

__global__ __launch_bounds__(256) void xo_kernel(const float* __restrict__ xo,
                                                 const float* __restrict__ W,
                                                 const float* __restrict__ bias,
                                                 float* __restrict__ h) {
  const int idx = blockIdx.x * 256 + threadIdx.x;  // 8192
  const int b = idx >> 9;
  const int n = idx & 511;
  float acc = bias[n];
  #pragma unroll
  for (int k = 0; k < FOn; ++k) acc = fmaf(xo[b * FOn + k], W[k * Dn + n], acc);
  h[b * 1024 + 512 + n] = acc;
}

__global__ __launch_bounds__(256) void f1_kernel(
    const float* __restrict__ h, const float* __restrict__ W,
    const float* __restrict__ bias, const float* __restrict__ s,
    const float* __restrict__ bt, float* __restrict__ o) {
  const int b = blockIdx.x;
  const int n = threadIdx.x;  // 256
  float acc = bias[n];
  for (int k = 0; k < 2 * Dn; ++k) acc = fmaf(h[b * 1024 + k], W[k * 256 + n], acc);
  const float mu = blockReduceSum(acc) * (1.0f / 256.0f);
  const float d = acc - mu;
  const float var = blockReduceSum(d * d) * (1.0f / 256.0f);
  const float y = d * rsqrtf(var + EPSf) * s[n] + bt[n];
  o[b * 256 + n] = fmaxf(y, 0.0f);
}

__global__ __launch_bounds__(128) void f2_kernel(
    const float* __restrict__ h1, const float* __restrict__ W,
    const float* __restrict__ bias, const float* __restrict__ s,
    const float* __restrict__ bt, float* __restrict__ o) {
  const int b = blockIdx.x;
  const int n = threadIdx.x;  // 128
  float acc = bias[n];
  for (int k = 0; k < 256; ++k) acc = fmaf(h1[b * 256 + k], W[k * 128 + n], acc);
  const float mu = blockReduceSum(acc) * (1.0f / 128.0f);
  const float d = acc - mu;
  const float var = blockReduceSum(d * d) * (1.0f / 128.0f);
  const float y = d * rsqrtf(var + EPSf) * s[n] + bt[n];
  o[b * 128 + n] = fmaxf(y, 0.0f);
}

__global__ __launch_bounds__(128) void f3_kernel(const float* __restrict__ h2,
                                                 const float* __restrict__ W,
                                                 const float* __restrict__ bias,
                                                 float* __restrict__ o) {
  const int b = blockIdx.x;
  const int t = threadIdx.x;  // 128
  float v = h2[b * 128 + t] * W[t];
  v = blockReduceSum(v);
  if (t == 0) o[b] = v + bias[0];
}

extern "C" void kernel_launch(void* const* d_in, const int* in_sizes, int n_in,
                              void* d_out, int out_size, void* d_ws, size_t ws_size,
                              hipStream_t stream) {
  (void)in_sizes; (void)n_in; (void)out_size; (void)ws_size;
  const float* x_cgm  = (const float*)d_in[0];
  const float* x_other= (const float*)d_in[1];
  const float* cgm_W  = (const float*)d_in[2];
  const float* cgm_b  = (const float*)d_in[3];
  const float* rel_emb= (const float*)d_in[4];
  const float* Wq = (const float*)d_in[5];
  const float* bq = (const float*)d_in[6];
  const float* Wk = (const float*)d_in[7];
  const float* bk = (const float*)d_in[8];
  const float* Wv = (const float*)d_in[9];
  const float* bv = (const float*)d_in[10];
  const float* Wo = (const float*)d_in[11];
  const float* bo = (const float*)d_in[12];
  const float* Wg = (const float*)d_in[13];
  const float* bg = (const float*)d_in[14];
  const float* Wf1 = (const float*)d_in[15];
  const float* bf1 = (const float*)d_in[16];
  const float* Wfg = (const float*)d_in[17];
  const float* bfg = (const float*)d_in[18];
  const float* Wf2 = (const float*)d_in[19];
  const float* bf2 = (const float*)d_in[20];
  const float* ln1_s = (const float*)d_in[21];
  const float* ln1_b = (const float*)d_in[22];
  const float* ln2_s = (const float*)d_in[23];
  const float* ln2_b = (const float*)d_in[24];
  const float* other_W = (const float*)d_in[25];
  const float* other_b = (const float*)d_in[26];
  const float* fW1 = (const float*)d_in[27];
  const float* fb1 = (const float*)d_in[28];
  const float* fln1_s = (const float*)d_in[29];
  const float* fln1_b = (const float*)d_in[30];
  const float* fW2 = (const float*)d_in[31];
  const float* fb2 = (const float*)d_in[32];
  const float* fln2_s = (const float*)d_in[33];
  const float* fln2_b = (const float*)d_in[34];
  const float* fW3 = (const float*)d_in[35];
  const float* fb3 = (const float*)d_in[36];
  float* out = (float*)d_out;

  char* p = (char*)d_ws;
  auto alloc = [&](size_t bytes) { char* r = p; p += (bytes + 255) & ~(size_t)255; return r; };
  float*          X      = (float*)alloc((size_t)8192 * 512 * 4);
  unsigned short* Xb     = (unsigned short*)alloc((size_t)8192 * 512 * 2);
  unsigned short* QKVb   = (unsigned short*)alloc((size_t)8192 * 1536 * 2);  // also CTXo f32
  unsigned short* CTXb   = (unsigned short*)alloc((size_t)8192 * 512 * 2);
  char*           R      = alloc((size_t)8192 * 2048 * 2);  // ATTb|GATEb bf16 / FFBh overlay
  unsigned short* ATTb   = (unsigned short*)R;
  unsigned short* GATEb  = (unsigned short*)(R + (size_t)8192 * 512 * 2);
  unsigned short* FFBh   = (unsigned short*)R;               // [8192][2048] bf16
  float*          CTXo   = (float*)QKVb;
  unsigned short* Wqkvgt = (unsigned short*)alloc((size_t)4 * 2048 * 512 * 2);
  unsigned short* Wot    = (unsigned short*)alloc((size_t)4 * 512 * 512 * 2);
  unsigned short* Wf1t   = (unsigned short*)alloc((size_t)4 * 2048 * 512 * 2);
  unsigned short* Wfgt   = (unsigned short*)alloc((size_t)4 * 2048 * 512 * 2);
  unsigned short* Wf2t   = (unsigned short*)alloc((size_t)4 * 512 * 2048 * 2);
  float*          bqkvg  = (float*)alloc((size_t)4 * 2048 * 4);
  float*          RMb    = (float*)alloc(1024 * 4);
  float*          Hb     = (float*)alloc(16 * 1024 * 4);
  float*          H1b    = (float*)alloc(16 * 256 * 4);
  float*          H2b    = (float*)alloc(16 * 128 * 4);

  wconv_kernel<<<dim3(16, 16, 4), 256, 0, stream>>>(Wq, Wqkvgt + (size_t)0 * 512, 512, 512,
                                                    (size_t)512 * 512, (size_t)2048 * 512);
  wconv_kernel<<<dim3(16, 16, 4), 256, 0, stream>>>(Wk, Wqkvgt + (size_t)512 * 512, 512, 512,
                                                    (size_t)512 * 512, (size_t)2048 * 512);
  wconv_kernel<<<dim3(16, 16, 4), 256, 0, stream>>>(Wv, Wqkvgt + (size_t)1024 * 512, 512, 512,
                                                    (size_t)512 * 512, (size_t)2048 * 512);
  wconv_kernel<<<dim3(16, 16, 4), 256, 0, stream>>>(Wg, Wqkvgt + (size_t)1536 * 512, 512, 512,
                                                    (size_t)512 * 512, (size_t)2048 * 512);
  wconv_kernel<<<dim3(16, 16, 4), 256, 0, stream>>>(Wo, Wot, 512, 512,
                                                    (size_t)512 * 512, (size_t)512 * 512);
  wconv_kernel<<<dim3(64, 16, 4), 256, 0, stream>>>(Wf1, Wf1t, 512, 2048,
                                                    (size_t)512 * 2048, (size_t)2048 * 512);
  wconv_kernel<<<dim3(64, 16, 4), 256, 0, stream>>>(Wfg, Wfgt, 512, 2048,
                                                    (size_t)512 * 2048, (size_t)2048 * 512);
  wconv_kernel<<<dim3(16, 64, 4), 256, 0, stream>>>(Wf2, Wf2t, 2048, 512,
                                                    (size_t)2048 * 512, (size_t)512 * 2048);
  bcat_kernel<<<dim3(32), 256, 0, stream>>>(bq, bk, bv, bg, bqkvg);

  embed_kernel<<<dim3(16384), dim3(256), 0, stream>>>(x_cgm, cgm_W, cgm_b, X, Xb);
  relmean_kernel<<<dim3(4), dim3(256), 0, stream>>>(rel_emb, RMb);

  for (int l = 0; l < Ln; ++l) {
    const size_t bof = (size_t)l * Dn;
    // fused q|k|v|gate GEMM: N=2048, K=512
    mgemm<4><<<dim3(16, 64), 256, 0, stream>>>(Xb, Wqkvgt + (size_t)l * 2048 * 512,
                                               bqkvg + (size_t)l * 2048, nullptr, QKVb, GATEb,
                                               512, 2048, 0, 512, 0);
    attn_kernel<<<dim3(1024), dim3(256), 0, stream>>>(QKVb, RMb, CTXb);
    // Wo: bf16 out
    mgemm<3><<<dim3(4, 64), 256, 0, stream>>>(CTXb, Wot + (size_t)l * 512 * 512,
                                              bo + bof, nullptr, ATTb, nullptr,
                                              512, 512, 0, 512, 512);
    ln_res1_kernel<<<dim3(8192), 256, 0, stream>>>(X, Xb, ATTb, GATEb, ln1_s + bof, ln1_b + bof);
    // fused gated FF: N=2048, K=512
    ffgemm<<<dim3(32, 64), 256, 0, stream>>>(Xb, Wf1t + (size_t)l * 2048 * 512,
                                             Wfgt + (size_t)l * 2048 * 512,
                                             bf1 + (size_t)l * FFn, bfg + (size_t)l * FFn,
                                             FFBh, 512);
    // Wf2 split-K: K=2048 -> 2x1024
    mgemm<0><<<dim3(4, 64), 256, 0, stream>>>(FFBh, Wf2t + (size_t)l * 512 * 2048,
                                              bf2 + bof, CTXo, nullptr, nullptr,
                                              2048, 512, 0, 1024, 512);
    mgemm<5><<<dim3(4, 64), 256, 0, stream>>>(FFBh, Wf2t + (size_t)l * 512 * 2048,
                                              nullptr, CTXo, nullptr, nullptr,
                                              2048, 512, 1024, 1024, 512);
    ln_res2_kernel<<<dim3(8192), 256, 0, stream>>>(X, Xb, CTXo, ln2_s + bof, ln2_b + bof);
  }

  meanpool_kernel<<<dim3(32), dim3(256), 0, stream>>>(X, Hb);
  xo_kernel<<<dim3(32), dim3(256), 0, stream>>>(x_other, other_W, other_b, Hb);
  f1_kernel<<<dim3(16), dim3(256), 0, stream>>>(Hb, fW1, fb1, fln1_s, fln1_b, H1b);
  f2_kernel<<<dim3(16), dim3(128), 0, stream>>>(H1b, fW2, fb2, fln2_s, fln2_b, H2b);
  f3_kernel<<<dim3(16), dim3(128), 0, stream>>>(H2b, fW3, fb3, out);
}

// Round 5
// 1242.184 us; speedup vs baseline: 5.4444x; 1.0727x over previous
//
#include <hip/hip_runtime.h>
#include <math.h>

constexpr int Bn = 16;
constexpr int Sn = 512;
constexpr int FCn = 24;
constexpr int FOn = 16;
constexpr int Dn = 512;
constexpr int Hn = 8;
constexpr int DKn = 64;
constexpr int FFn = 2048;
constexpr int Ln = 4;
constexpr int MAXPOSn = 512;
constexpr float EPSf = 1e-6f;

typedef __attribute__((ext_vector_type(8))) short bf16x8;   // 8 bf16 in 4 VGPRs
typedef __attribute__((ext_vector_type(4))) float floatx4;

__device__ __forceinline__ float sigmoidf_(float x) { return 1.0f / (1.0f + __expf(-x)); }

__device__ __forceinline__ unsigned short f2bf(float f) {  // RNE
  unsigned int u = __float_as_uint(f);
  u += 0x7fffu + ((u >> 16) & 1u);
  return (unsigned short)(u >> 16);
}
__device__ __forceinline__ float b2f(unsigned short b) {
  return __uint_as_float(((unsigned int)b) << 16);
}

__device__ __forceinline__ void g2l16(const void* g, void* l) {
  // async global->LDS, 16B/lane, LDS dest = wave-uniform base + lane*16
  __builtin_amdgcn_global_load_lds((const __attribute__((address_space(1))) void*)g,
                                   (__attribute__((address_space(3))) void*)l, 16, 0, 0);
}

// pair-pack bf16 store: even lane stores {self, lane^1} as one dword.
__device__ __forceinline__ void st_bf16_pair(unsigned short* dst, float v, int lane) {
  unsigned int us = f2bf(v);
  unsigned int other = (unsigned int)__shfl_xor((int)us, 1);
  if (!(lane & 1)) *(unsigned int*)dst = us | (other << 16);
}

__device__ __forceinline__ float blockReduceSum(float v) {
  #pragma unroll
  for (int off = 32; off >= 1; off >>= 1) v += __shfl_xor(v, off);
  __shared__ float red[8];
  const int w = threadIdx.x >> 6;
  const int nw = blockDim.x >> 6;
  if ((threadIdx.x & 63) == 0) red[w] = v;
  __syncthreads();
  float r = 0.0f;
  for (int i = 0; i < nw; ++i) r += red[i];
  __syncthreads();
  return r;
}

// ---------- weight transpose-convert: out[n][k] bf16 = in[k][n] f32 ----------
__global__ __launch_bounds__(256) void wconv_kernel(
    const float* __restrict__ in, unsigned short* __restrict__ out,
    int K, int N, size_t inStride, size_t outStride) {
  __shared__ float tile[32][33];
  in += (size_t)blockIdx.z * inStride;
  out += (size_t)blockIdx.z * outStride;
  const int k0 = blockIdx.y * 32, n0 = blockIdx.x * 32;
  const int tr = threadIdx.x >> 3;         // 0..31
  const int tc4 = (threadIdx.x & 7) * 4;   // 0..28
  float4 vv = *(const float4*)&in[(size_t)(k0 + tr) * N + n0 + tc4];
  tile[tr][tc4 + 0] = vv.x; tile[tr][tc4 + 1] = vv.y;
  tile[tr][tc4 + 2] = vv.z; tile[tr][tc4 + 3] = vv.w;
  __syncthreads();
  ushort4 o4;
  o4.x = f2bf(tile[tc4 + 0][tr]); o4.y = f2bf(tile[tc4 + 1][tr]);
  o4.z = f2bf(tile[tc4 + 2][tr]); o4.w = f2bf(tile[tc4 + 3][tr]);
  *(ushort4*)&out[(size_t)(n0 + tr) * K + k0 + tc4] = o4;
}

// bias concat: [L][2048] = [bq|bk|bv|bg]
__global__ void bcat_kernel(const float* __restrict__ bq, const float* __restrict__ bk,
                            const float* __restrict__ bv, const float* __restrict__ bg,
                            float* __restrict__ out) {
  const int t = blockIdx.x * 256 + threadIdx.x;  // 8192
  const int l = t >> 11;
  const int c = t & 2047;
  float v;
  if (c < 512) v = bq[l * 512 + c];
  else if (c < 1024) v = bk[l * 512 + c - 512];
  else if (c < 1536) v = bv[l * 512 + c - 1024];
  else v = bg[l * 512 + c - 1536];
  out[t] = v;
}

// x = x_cgm @ cgm_W + cgm_b  -> fp32 X and bf16 Xb
__global__ __launch_bounds__(256) void embed_kernel(
    const float* __restrict__ xc, const float* __restrict__ W,
    const float* __restrict__ bias, float* __restrict__ x,
    unsigned short* __restrict__ xb) {
  const int idx = blockIdx.x * 256 + threadIdx.x;
  const int n = idx & (Dn - 1);
  const int m = idx >> 9;
  const float* xr = xc + m * FCn;
  float acc = bias[n];
  #pragma unroll
  for (int k = 0; k < FCn; ++k) acc = fmaf(xr[k], W[k * Dn + n], acc);
  x[idx] = acc;
  xb[idx] = f2bf(acc);
}

__global__ void relmean_kernel(const float* __restrict__ rel, float* __restrict__ rm) {
  const int p = blockIdx.x * blockDim.x + threadIdx.x;
  if (p >= 2 * MAXPOSn - 1) return;
  float s = 0.0f;
  #pragma unroll 8
  for (int d = 0; d < DKn; ++d) s += rel[p * DKn + d];
  rm[p] = s * (1.0f / DKn);
}

// ---------- bf16 MFMA GEMM: C = A[M,K(slice)] @ Bt[N,K]^T (+ bias) ----------
// 128x128 tile, BK=32. M fixed 8192 (64 m-tiles). 1-D grid, XCD-swizzled:
// xcd = id&7 owns m-panel [xcd*8, xcd*8+8) for all n  (A 1MB + B-panel <=2MB per L2).
// EPI: 0 fp32 +bias; 3 bf16 +bias; 4 qkvg split; 5 fp32 accumulate (split-K pass 2).
template <int EPI>
__global__ __launch_bounds__(256) void mgemm(
    const unsigned short* __restrict__ A, const unsigned short* __restrict__ Bt,
    const float* __restrict__ bias, float* __restrict__ Cf,
    unsigned short* __restrict__ Cb, unsigned short* __restrict__ Cb2,
    int Astride, int N, int Koff, int Klen, int ldc, int nt) {
  __shared__ unsigned short As[128 * 32];
  __shared__ unsigned short Bs[128 * 32];
  const int t = threadIdx.x;
  const int w = t >> 6;
  const int lane = t & 63;
  const int id = blockIdx.x;
  const int xcd = id & 7;
  const int lid = id >> 3;
  const int n0 = (lid % nt) * 128;
  const int m0 = (xcd * 8 + lid / nt) * 128;
  const int wm = (w >> 1) * 64;
  const int wn = (w & 1) * 64;
  const int lr = lane & 15;
  const int lq = lane >> 4;

  floatx4 acc[4][4];
  #pragma unroll
  for (int i = 0; i < 4; ++i)
    #pragma unroll
    for (int j = 0; j < 4; ++j) acc[i][j] = (floatx4){0.f, 0.f, 0.f, 0.f};

  const int srow = lane >> 2;   // 0..15
  const int schk = (lane & 3) * 8;

  for (int k0 = Koff; k0 < Koff + Klen; k0 += 32) {
    __syncthreads();
    #pragma unroll
    for (int r = 0; r < 2; ++r) {
      const int rb = (w * 2 + r) * 16;
      g2l16(&A[(size_t)(m0 + rb + srow) * Astride + k0 + schk], &As[rb * 32]);
      g2l16(&Bt[(size_t)(n0 + rb + srow) * Astride + k0 + schk], &Bs[rb * 32]);
    }
    __syncthreads();
    bf16x8 af[4], bf[4];
    #pragma unroll
    for (int i = 0; i < 4; ++i)
      af[i] = *(const bf16x8*)&As[(wm + i * 16 + lr) * 32 + lq * 8];
    #pragma unroll
    for (int j = 0; j < 4; ++j)
      bf[j] = *(const bf16x8*)&Bs[(wn + j * 16 + lr) * 32 + lq * 8];
    #pragma unroll
    for (int i = 0; i < 4; ++i)
      #pragma unroll
      for (int j = 0; j < 4; ++j)
        acc[i][j] = __builtin_amdgcn_mfma_f32_16x16x32_bf16(af[i], bf[j], acc[i][j], 0, 0, 0);
  }

  // C/D layout: col = lane&15, row = (lane>>4)*4 + reg
  #pragma unroll
  for (int i = 0; i < 4; ++i) {
    const int row = m0 + wm + i * 16 + lq * 4;
    #pragma unroll
    for (int j = 0; j < 4; ++j) {
      const int col = n0 + wn + j * 16 + lr;
      const int colp = col & ~1;  // even lane's column for pair-pack
      #pragma unroll
      for (int r = 0; r < 4; ++r) {
        if (EPI == 0) {
          Cf[(size_t)(row + r) * ldc + col] = acc[i][j][r] + bias[col];
        } else if (EPI == 5) {
          const size_t idx = (size_t)(row + r) * ldc + col;
          Cf[idx] += acc[i][j][r];
        } else if (EPI == 3) {
          st_bf16_pair(&Cb[(size_t)(row + r) * ldc + colp], acc[i][j][r] + bias[col], lane);
        } else if (EPI == 4) {
          const float va = acc[i][j][r] + bias[col];
          if (col < 1536)
            st_bf16_pair(&Cb[(size_t)(row + r) * 1536 + colp], va, lane);
          else
            st_bf16_pair(&Cb2[(size_t)(row + r) * 512 + (colp - 1536)], sigmoidf_(va), lane);
        }
      }
    }
  }
}

// ---------- fused gated FF: C = (A@W1+b1) * sigmoid(A@W2+b2), bf16 out ----------
// Block 128m x 64n; 1-D grid 2048, XCD-swizzled (8 m-tiles per xcd, 32 n-tiles).
__global__ __launch_bounds__(256) void ffgemm(
    const unsigned short* __restrict__ A, const unsigned short* __restrict__ B1t,
    const unsigned short* __restrict__ B2t, const float* __restrict__ b1,
    const float* __restrict__ b2, unsigned short* __restrict__ C, int K) {
  __shared__ unsigned short As[128 * 32];
  __shared__ unsigned short B1s[64 * 32];
  __shared__ unsigned short B2s[64 * 32];
  const int t = threadIdx.x;
  const int w = t >> 6;
  const int lane = t & 63;
  const int id = blockIdx.x;
  const int xcd = id & 7;
  const int lid = id >> 3;            // 0..255
  const int n0 = (lid & 31) * 64;
  const int m0 = (xcd * 8 + (lid >> 5)) * 128;
  const int wm = (w >> 1) * 64;
  const int wn = (w & 1) * 32;
  const int lr = lane & 15;
  const int lq = lane >> 4;

  floatx4 a1[4][2], a2[4][2];
  #pragma unroll
  for (int i = 0; i < 4; ++i)
    #pragma unroll
    for (int j = 0; j < 2; ++j) {
      a1[i][j] = (floatx4){0.f, 0.f, 0.f, 0.f};
      a2[i][j] = (floatx4){0.f, 0.f, 0.f, 0.f};
    }

  const int srow = lane >> 2;
  const int schk = (lane & 3) * 8;

  for (int k0 = 0; k0 < K; k0 += 32) {
    __syncthreads();
    g2l16(&A[(size_t)(m0 + w * 32 + srow) * K + k0 + schk], &As[(w * 32) * 32]);
    g2l16(&A[(size_t)(m0 + w * 32 + 16 + srow) * K + k0 + schk], &As[(w * 32 + 16) * 32]);
    g2l16(&B1t[(size_t)(n0 + w * 16 + srow) * K + k0 + schk], &B1s[(w * 16) * 32]);
    g2l16(&B2t[(size_t)(n0 + w * 16 + srow) * K + k0 + schk], &B2s[(w * 16) * 32]);
    __syncthreads();
    bf16x8 af[4], f1[2], f2[2];
    #pragma unroll
    for (int i = 0; i < 4; ++i)
      af[i] = *(const bf16x8*)&As[(wm + i * 16 + lr) * 32 + lq * 8];
    #pragma unroll
    for (int j = 0; j < 2; ++j) {
      f1[j] = *(const bf16x8*)&B1s[(wn + j * 16 + lr) * 32 + lq * 8];
      f2[j] = *(const bf16x8*)&B2s[(wn + j * 16 + lr) * 32 + lq * 8];
    }
    #pragma unroll
    for (int i = 0; i < 4; ++i)
      #pragma unroll
      for (int j = 0; j < 2; ++j) {
        a1[i][j] = __builtin_amdgcn_mfma_f32_16x16x32_bf16(af[i], f1[j], a1[i][j], 0, 0, 0);
        a2[i][j] = __builtin_amdgcn_mfma_f32_16x16x32_bf16(af[i], f2[j], a2[i][j], 0, 0, 0);
      }
  }

  #pragma unroll
  for (int i = 0; i < 4; ++i) {
    const int row = m0 + wm + i * 16 + lq * 4;
    #pragma unroll
    for (int j = 0; j < 2; ++j) {
      const int col = n0 + wn + j * 16 + lr;
      const int colp = col & ~1;
      const float bb1 = b1[col], bb2 = b2[col];
      #pragma unroll
      for (int r = 0; r < 4; ++r) {
        const float f = (a1[i][j][r] + bb1) * sigmoidf_(a2[i][j][r] + bb2);
        st_bf16_pair(&C[(size_t)(row + r) * 2048 + colp], f, lane);
      }
    }
  }
}

// ---------- MFMA flash attention ----------
// Grid 1024, XCD-swizzled: b = bid&15 (each batch's QKV stays in one XCD's L2).
__global__ __launch_bounds__(256) void attn_kernel(
    const unsigned short* __restrict__ qkv, const float* __restrict__ rm,
    unsigned short* __restrict__ ctx) {
  __shared__ unsigned short Ks[64 * 72];
  __shared__ unsigned short Vt[64 * 72];
  __shared__ unsigned short Pw[4][16 * 72];
  __shared__ float rml[576];
  const int t = threadIdx.x;
  const int w = t >> 6;
  const int lane = t & 63;
  const int lr = lane & 15;
  const int lq = lane >> 4;
  const int bid = blockIdx.x;
  const int b = bid & 15;
  const int h = (bid >> 4) & 7;
  const int qt = bid >> 7;
  const int q0 = qt * 64;
  const size_t rowb = (size_t)b * Sn * 1536;

  for (int i = t; i < 576; i += 256) rml[i] = rm[q0 + i];

  bf16x8 aq0, aq1;
  {
    const unsigned short* qp = &qkv[rowb + (size_t)(q0 + w * 16 + lr) * 1536 + h * 64 + lq * 8];
    aq0 = *(const bf16x8*)qp;
    aq1 = *(const bf16x8*)(qp + 32);
  }

  floatx4 o_acc[4];
  #pragma unroll
  for (int i = 0; i < 4; ++i) o_acc[i] = (floatx4){0.f, 0.f, 0.f, 0.f};
  float m_old[4] = {-1e30f, -1e30f, -1e30f, -1e30f};
  float l_sum[4] = {0.f, 0.f, 0.f, 0.f};

  const int skey = t >> 2;
  const int schk = (t & 3) * 16;
  const int vkp = t >> 4;
  const int vd4 = (t & 15) * 4;

  for (int kc = 0; kc < 8; ++kc) {
    __syncthreads();
    {
      const unsigned short* gk = &qkv[rowb + (size_t)(kc * 64 + skey) * 1536 + 512 + h * 64 + schk];
      *(bf16x8*)&Ks[skey * 72 + schk] = *(const bf16x8*)gk;
      *(bf16x8*)&Ks[skey * 72 + schk + 8] = *(const bf16x8*)(gk + 8);
    }
    #pragma unroll
    for (int pass = 0; pass < 2; ++pass) {
      const int kp = vkp + pass * 16;
      const unsigned short* gv = &qkv[rowb + (size_t)(kc * 64 + kp * 2) * 1536 + 1024 + h * 64 + vd4];
      ushort4 v0 = *(const ushort4*)gv;
      ushort4 v1 = *(const ushort4*)(gv + 1536);
      *(ushort2*)&Vt[(vd4 + 0) * 72 + kp * 2] = make_ushort2(v0.x, v1.x);
      *(ushort2*)&Vt[(vd4 + 1) * 72 + kp * 2] = make_ushort2(v0.y, v1.y);
      *(ushort2*)&Vt[(vd4 + 2) * 72 + kp * 2] = make_ushort2(v0.z, v1.z);
      *(ushort2*)&Vt[(vd4 + 3) * 72 + kp * 2] = make_ushort2(v0.w, v1.w);
    }
    __syncthreads();

    floatx4 s_acc[4];
    #pragma unroll
    for (int j = 0; j < 4; ++j) {
      bf16x8 b0 = *(const bf16x8*)&Ks[(j * 16 + lr) * 72 + lq * 8];
      bf16x8 b1 = *(const bf16x8*)&Ks[(j * 16 + lr) * 72 + 32 + lq * 8];
      s_acc[j] = __builtin_amdgcn_mfma_f32_16x16x32_bf16(aq0, b0, (floatx4){0.f, 0.f, 0.f, 0.f}, 0, 0, 0);
      s_acc[j] = __builtin_amdgcn_mfma_f32_16x16x32_bf16(aq1, b1, s_acc[j], 0, 0, 0);
    }

    float mloc[4] = {-1e30f, -1e30f, -1e30f, -1e30f};
    #pragma unroll
    for (int j = 0; j < 4; ++j) {
      const int key = kc * 64 + j * 16 + lr;
      #pragma unroll
      for (int r = 0; r < 4; ++r) {
        const float sv = s_acc[j][r] * 0.125f + rml[(w * 16 + lq * 4 + r) + 511 - key];
        s_acc[j][r] = sv;
        mloc[r] = fmaxf(mloc[r], sv);
      }
    }
    #pragma unroll
    for (int off = 1; off <= 8; off <<= 1)
      #pragma unroll
      for (int r = 0; r < 4; ++r) mloc[r] = fmaxf(mloc[r], __shfl_xor(mloc[r], off));

    float alpha[4], rsum[4];
    #pragma unroll
    for (int r = 0; r < 4; ++r) {
      const float mnew = fmaxf(m_old[r], mloc[r]);
      alpha[r] = __expf(m_old[r] - mnew);
      m_old[r] = mnew;
      rsum[r] = 0.f;
    }
    #pragma unroll
    for (int j = 0; j < 4; ++j)
      #pragma unroll
      for (int r = 0; r < 4; ++r) {
        const float p = __expf(s_acc[j][r] - m_old[r]);
        rsum[r] += p;
        Pw[w][(lq * 4 + r) * 72 + j * 16 + lr] = f2bf(p);
      }
    #pragma unroll
    for (int off = 1; off <= 8; off <<= 1)
      #pragma unroll
      for (int r = 0; r < 4; ++r) rsum[r] += __shfl_xor(rsum[r], off);
    #pragma unroll
    for (int r = 0; r < 4; ++r) l_sum[r] = l_sum[r] * alpha[r] + rsum[r];
    #pragma unroll
    for (int i = 0; i < 4; ++i)
      #pragma unroll
      for (int r = 0; r < 4; ++r) o_acc[i][r] *= alpha[r];

    bf16x8 ap0 = *(const bf16x8*)&Pw[w][lr * 72 + lq * 8];
    bf16x8 ap1 = *(const bf16x8*)&Pw[w][lr * 72 + 32 + lq * 8];
    #pragma unroll
    for (int i = 0; i < 4; ++i) {
      bf16x8 v0 = *(const bf16x8*)&Vt[(i * 16 + lr) * 72 + lq * 8];
      bf16x8 v1 = *(const bf16x8*)&Vt[(i * 16 + lr) * 72 + 32 + lq * 8];
      o_acc[i] = __builtin_amdgcn_mfma_f32_16x16x32_bf16(ap0, v0, o_acc[i], 0, 0, 0);
      o_acc[i] = __builtin_amdgcn_mfma_f32_16x16x32_bf16(ap1, v1, o_acc[i], 0, 0, 0);
    }
  }

  float rinv[4];
  #pragma unroll
  for (int r = 0; r < 4; ++r) rinv[r] = 1.0f / l_sum[r];
  #pragma unroll
  for (int i = 0; i < 4; ++i)
    #pragma unroll
    for (int r = 0; r < 4; ++r) {
      const int q = q0 + w * 16 + lq * 4 + r;
      ctx[((size_t)(b * Sn + q)) * Dn + h * 64 + i * 16 + lr] = f2bf(o_acc[i][r] * rinv[r]);
    }
}

// ln1: x = LN(x + gate*att), att/gate bf16
__global__ __launch_bounds__(256) void ln_res1_kernel(
    float* __restrict__ x, unsigned short* __restrict__ xb,
    const unsigned short* __restrict__ att, const unsigned short* __restrict__ gate,
    const float* __restrict__ s, const float* __restrict__ bsh) {
  const int row = blockIdx.x;
  const int t = threadIdx.x;
  const size_t base = (size_t)row * Dn;
  float y0 = x[base + t] + b2f(att[base + t]) * b2f(gate[base + t]);
  float y1 = x[base + t + 256] + b2f(att[base + t + 256]) * b2f(gate[base + t + 256]);
  const float mu = blockReduceSum(y0 + y1) * (1.0f / Dn);
  const float d0 = y0 - mu, d1 = y1 - mu;
  const float var = blockReduceSum(d0 * d0 + d1 * d1) * (1.0f / Dn);
  const float rstd = rsqrtf(var + EPSf);
  const float o0 = d0 * rstd * s[t] + bsh[t];
  const float o1 = d1 * rstd * s[t + 256] + bsh[t + 256];
  x[base + t] = o0;
  x[base + t + 256] = o1;
  xb[base + t] = f2bf(o0);
  xb[base + t + 256] = f2bf(o1);
}

// ln2: x = LN(x + add), add fp32
__global__ __launch_bounds__(256) void ln_res2_kernel(
    float* __restrict__ x, unsigned short* __restrict__ xb,
    const float* __restrict__ add, const float* __restrict__ s,
    const float* __restrict__ bsh) {
  const int row = blockIdx.x;
  const int t = threadIdx.x;
  const size_t base = (size_t)row * Dn;
  float y0 = x[base + t] + add[base + t];
  float y1 = x[base + t + 256] + add[base + t + 256];
  const float mu = blockReduceSum(y0 + y1) * (1.0f / Dn);
  const float d0 = y0 - mu, d1 = y1 - mu;
  const float var = blockReduceSum(d0 * d0 + d1 * d1) * (1.0f / Dn);
  const float rstd = rsqrtf(var + EPSf);
  const float o0 = d0 * rstd * s[t] + bsh[t];
  const float o1 = d1 * rstd * s[t + 256] + bsh[t + 256];
  x[base + t] = o0;
  x[base + t + 256] = o1;
  xb[base + t] = f2bf(o0);
  xb[base + t + 256] = f2bf(o1);
}

// meanpool partial: block (b, sc) sums 64 rows -> part[b][sc][512]
__global__ __launch_bounds__(256) void mp_part_kernel(const float* __restrict__ x,
                                                      float* __restrict__ part) {
  const int b = blockIdx.x, sc = blockIdx.y;
  const int t = threadIdx.x;
  float s0 = 0.f, s1 = 0.f;
  for (int si = sc * 64; si < sc * 64 + 64; ++si) {
    s0 += x[((size_t)(b * Sn + si)) * Dn + t];
    s1 += x[((size_t)(b * Sn + si)) * Dn + t + 256];
  }
  part[(size_t)(b * 8 + sc) * 512 + t] = s0;
  part[(size_t)(b * 8 + sc) * 512 + t + 256] = s1;
}

// combine: h[b][0:512] = mean
__global__ __launch_bounds__(256) void mp_comb_kernel(const float* __restrict__ part,
                                                      float* __restrict__ h) {
  const int idx = blockIdx.x * 256 + threadIdx.x;  // 8192
  const int b = idx >> 9, d = idx & 511;
  float s = 0.f;
  #pragma unroll
  for (int i = 0; i < 8; ++i) s += part[(size_t)(b * 8 + i) * 512 + d];
  h[b * 1024 + d] = s * (1.0f / Sn);
}

__global__ __launch_bounds__(256) void xo_kernel(const float* __restrict__ xo,
                                                 const float* __restrict__ W,
                                                 const float* __restrict__ bias,
                                                 float* __restrict__ h) {
  const int idx = blockIdx.x * 256 + threadIdx.x;  // 8192
  const int b = idx >> 9;
  const int n = idx & 511;
  float acc = bias[n];
  #pragma unroll
  for (int k = 0; k < FOn; ++k) acc = fmaf(xo[b * FOn + k], W[k * Dn + n], acc);
  h[b * 1024 + 512 + n] = acc;
}

// f1 phase A: part[b][kq][n] = sum_{k in slice} h[b][k] * W[k][n]   (grid 16x8)
__global__ __launch_bounds__(256) void f1a_kernel(
    const float* __restrict__ h, const float* __restrict__ W,
    float* __restrict__ part) {
  const int b = blockIdx.x, kq = blockIdx.y;
  const int n = threadIdx.x;  // 256
  const float* hr = h + b * 1024 + kq * 128;
  const float* Wp = W + (size_t)(kq * 128) * 256 + n;
  float acc = 0.f;
  #pragma unroll 8
  for (int k = 0; k < 128; ++k) acc = fmaf(hr[k], Wp[(size_t)k * 256], acc);
  part[(size_t)(b * 8 + kq) * 256 + n] = acc;
}

// f1 phase B: sum partials + bias, LN_256, relu
__global__ __launch_bounds__(256) void f1b_kernel(
    const float* __restrict__ part, const float* __restrict__ bias,
    const float* __restrict__ s, const float* __restrict__ bt,
    float* __restrict__ o) {
  const int b = blockIdx.x;
  const int n = threadIdx.x;  // 256
  float acc = bias[n];
  #pragma unroll
  for (int i = 0; i < 8; ++i) acc += part[(size_t)(b * 8 + i) * 256 + n];
  const float mu = blockReduceSum(acc) * (1.0f / 256.0f);
  const float d = acc - mu;
  const float var = blockReduceSum(d * d) * (1.0f / 256.0f);
  const float y = d * rsqrtf(var + EPSf) * s[n] + bt[n];
  o[b * 256 + n] = fmaxf(y, 0.0f);
}

// f2: one block per b; 512 thr = 4 k-slices x 128 n; LDS reduce; LN_128 + relu
__global__ __launch_bounds__(512) void f2_kernel(
    const float* __restrict__ h1, const float* __restrict__ W,
    const float* __restrict__ bias, const float* __restrict__ s,
    const float* __restrict__ bt, float* __restrict__ o) {
  __shared__ float h1row[256];
  __shared__ float partial[4][128];
  const int b = blockIdx.x;
  const int t = threadIdx.x;
  if (t < 256) h1row[t] = h1[b * 256 + t];
  __syncthreads();
  const int n = t & 127, ks = t >> 7;
  float acc = 0.f;
  #pragma unroll 8
  for (int k = ks * 64; k < ks * 64 + 64; ++k) acc = fmaf(h1row[k], W[k * 128 + n], acc);
  partial[ks][n] = acc;
  __syncthreads();
  float v = 0.f;
  if (t < 128)
    v = partial[0][t] + partial[1][t] + partial[2][t] + partial[3][t] + bias[t];
  const float mu = blockReduceSum(t < 128 ? v : 0.f) * (1.0f / 128.0f);
  const float d = (t < 128) ? v - mu : 0.f;
  const float var = blockReduceSum(d * d) * (1.0f / 128.0f);
  if (t < 128) o[b * 128 + t] = fmaxf(d * rsqrtf(var + EPSf) * s[t] + bt[t], 0.0f);
}

__global__ __launch_bounds__(128) void f3_kernel(const float* __restrict__ h2,
                                                 const float* __restrict__ W,
                                                 const float* __restrict__ bias,
                                                 float* __restrict__ o) {
  const int b = blockIdx.x;
  const int t = threadIdx.x;  // 128
  float v = h2[b * 128 + t] * W[t];
  v = blockReduceSum(v);
  if (t == 0) o[b] = v + bias[0];
}

extern "C" void kernel_launch(void* const* d_in, const int* in_sizes, int n_in,
                              void* d_out, int out_size, void* d_ws, size_t ws_size,
                              hipStream_t stream) {
  (void)in_sizes; (void)n_in; (void)out_size; (void)ws_size;
  const float* x_cgm  = (const float*)d_in[0];
  const float* x_other= (const float*)d_in[1];
  const float* cgm_W  = (const float*)d_in[2];
  const float* cgm_b  = (const float*)d_in[3];
  const float* rel_emb= (const float*)d_in[4];
  const float* Wq = (const float*)d_in[5];
  const float* bq = (const float*)d_in[6];
  const float* Wk = (const float*)d_in[7];
  const float* bk = (const float*)d_in[8];
  const float* Wv = (const float*)d_in[9];
  const float* bv = (const float*)d_in[10];
  const float* Wo = (const float*)d_in[11];
  const float* bo = (const float*)d_in[12];
  const float* Wg = (const float*)d_in[13];
  const float* bg = (const float*)d_in[14];
  const float* Wf1 = (const float*)d_in[15];
  const float* bf1 = (const float*)d_in[16];
  const float* Wfg = (const float*)d_in[17];
  const float* bfg = (const float*)d_in[18];
  const float* Wf2 = (const float*)d_in[19];
  const float* bf2 = (const float*)d_in[20];
  const float* ln1_s = (const float*)d_in[21];
  const float* ln1_b = (const float*)d_in[22];
  const float* ln2_s = (const float*)d_in[23];
  const float* ln2_b = (const float*)d_in[24];
  const float* other_W = (const float*)d_in[25];
  const float* other_b = (const float*)d_in[26];
  const float* fW1 = (const float*)d_in[27];
  const float* fb1 = (const float*)d_in[28];
  const float* fln1_s = (const float*)d_in[29];
  const float* fln1_b = (const float*)d_in[30];
  const float* fW2 = (const float*)d_in[31];
  const float* fb2 = (const float*)d_in[32];
  const float* fln2_s = (const float*)d_in[33];
  const float* fln2_b = (const float*)d_in[34];
  const float* fW3 = (const float*)d_in[35];
  const float* fb3 = (const float*)d_in[36];
  float* out = (float*)d_out;

  char* p = (char*)d_ws;
  auto alloc = [&](size_t bytes) { char* r = p; p += (bytes + 255) & ~(size_t)255; return r; };
  float*          X      = (float*)alloc((size_t)8192 * 512 * 4);
  unsigned short* Xb     = (unsigned short*)alloc((size_t)8192 * 512 * 2);
  unsigned short* QKVb   = (unsigned short*)alloc((size_t)8192 * 1536 * 2);  // also CTXo f32
  unsigned short* CTXb   = (unsigned short*)alloc((size_t)8192 * 512 * 2);
  char*           R      = alloc((size_t)8192 * 2048 * 2);  // ATTb|GATEb bf16 / FFBh overlay
  unsigned short* ATTb   = (unsigned short*)R;
  unsigned short* GATEb  = (unsigned short*)(R + (size_t)8192 * 512 * 2);
  unsigned short* FFBh   = (unsigned short*)R;               // [8192][2048] bf16
  float*          CTXo   = (float*)QKVb;
  unsigned short* Wqkvgt = (unsigned short*)alloc((size_t)4 * 2048 * 512 * 2);
  unsigned short* Wot    = (unsigned short*)alloc((size_t)4 * 512 * 512 * 2);
  unsigned short* Wf1t   = (unsigned short*)alloc((size_t)4 * 2048 * 512 * 2);
  unsigned short* Wfgt   = (unsigned short*)alloc((size_t)4 * 2048 * 512 * 2);
  unsigned short* Wf2t   = (unsigned short*)alloc((size_t)4 * 512 * 2048 * 2);
  float*          bqkvg  = (float*)alloc((size_t)4 * 2048 * 4);
  float*          RMb    = (float*)alloc(1024 * 4);
  float*          Hb     = (float*)alloc(16 * 1024 * 4);
  float*          H1b    = (float*)alloc(16 * 256 * 4);
  float*          H2b    = (float*)alloc(16 * 128 * 4);
  float*          MPP    = (float*)alloc((size_t)16 * 8 * 512 * 4);
  float*          F1P    = (float*)alloc((size_t)16 * 8 * 256 * 4);

  wconv_kernel<<<dim3(16, 16, 4), 256, 0, stream>>>(Wq, Wqkvgt + (size_t)0 * 512, 512, 512,
                                                    (size_t)512 * 512, (size_t)2048 * 512);
  wconv_kernel<<<dim3(16, 16, 4), 256, 0, stream>>>(Wk, Wqkvgt + (size_t)512 * 512, 512, 512,
                                                    (size_t)512 * 512, (size_t)2048 * 512);
  wconv_kernel<<<dim3(16, 16, 4), 256, 0, stream>>>(Wv, Wqkvgt + (size_t)1024 * 512, 512, 512,
                                                    (size_t)512 * 512, (size_t)2048 * 512);
  wconv_kernel<<<dim3(16, 16, 4), 256, 0, stream>>>(Wg, Wqkvgt + (size_t)1536 * 512, 512, 512,
                                                    (size_t)512 * 512, (size_t)2048 * 512);
  wconv_kernel<<<dim3(16, 16, 4), 256, 0, stream>>>(Wo, Wot, 512, 512,
                                                    (size_t)512 * 512, (size_t)512 * 512);
  wconv_kernel<<<dim3(64, 16, 4), 256, 0, stream>>>(Wf1, Wf1t, 512, 2048,
                                                    (size_t)512 * 2048, (size_t)2048 * 512);
  wconv_kernel<<<dim3(64, 16, 4), 256, 0, stream>>>(Wfg, Wfgt, 512, 2048,
                                                    (size_t)512 * 2048, (size_t)2048 * 512);
  wconv_kernel<<<dim3(16, 64, 4), 256, 0, stream>>>(Wf2, Wf2t, 2048, 512,
                                                    (size_t)2048 * 512, (size_t)512 * 2048);
  bcat_kernel<<<dim3(32), 256, 0, stream>>>(bq, bk, bv, bg, bqkvg);

  embed_kernel<<<dim3(16384), dim3(256), 0, stream>>>(x_cgm, cgm_W, cgm_b, X, Xb);
  relmean_kernel<<<dim3(4), dim3(256), 0, stream>>>(rel_emb, RMb);

  for (int l = 0; l < Ln; ++l) {
    const size_t bof = (size_t)l * Dn;
    // fused q|k|v|gate GEMM: N=2048, K=512 (grid 1024, nt=16)
    mgemm<4><<<dim3(1024), 256, 0, stream>>>(Xb, Wqkvgt + (size_t)l * 2048 * 512,
                                             bqkvg + (size_t)l * 2048, nullptr, QKVb, GATEb,
                                             512, 2048, 0, 512, 0, 16);
    attn_kernel<<<dim3(1024), dim3(256), 0, stream>>>(QKVb, RMb, CTXb);
    // Wo: bf16 out (grid 256, nt=4)
    mgemm<3><<<dim3(256), 256, 0, stream>>>(CTXb, Wot + (size_t)l * 512 * 512,
                                            bo + bof, nullptr, ATTb, nullptr,
                                            512, 512, 0, 512, 512, 4);
    ln_res1_kernel<<<dim3(8192), 256, 0, stream>>>(X, Xb, ATTb, GATEb, ln1_s + bof, ln1_b + bof);
    // fused gated FF: N=2048, K=512 (grid 2048)
    ffgemm<<<dim3(2048), 256, 0, stream>>>(Xb, Wf1t + (size_t)l * 2048 * 512,
                                           Wfgt + (size_t)l * 2048 * 512,
                                           bf1 + (size_t)l * FFn, bfg + (size_t)l * FFn,
                                           FFBh, 512);
    // Wf2 split-K: K=2048 -> 2x1024 (grid 256 each, nt=4)
    mgemm<0><<<dim3(256), 256, 0, stream>>>(FFBh, Wf2t + (size_t)l * 512 * 2048,
                                            bf2 + bof, CTXo, nullptr, nullptr,
                                            2048, 512, 0, 1024, 512, 4);
    mgemm<5><<<dim3(256), 256, 0, stream>>>(FFBh, Wf2t + (size_t)l * 512 * 2048,
                                            nullptr, CTXo, nullptr, nullptr,
                                            2048, 512, 1024, 1024, 512, 4);
    ln_res2_kernel<<<dim3(8192), 256, 0, stream>>>(X, Xb, CTXo, ln2_s + bof, ln2_b + bof);
  }

  mp_part_kernel<<<dim3(16, 8), 256, 0, stream>>>(X, MPP);
  mp_comb_kernel<<<dim3(32), 256, 0, stream>>>(MPP, Hb);
  xo_kernel<<<dim3(32), dim3(256), 0, stream>>>(x_other, other_W, other_b, Hb);
  f1a_kernel<<<dim3(16, 8), 256, 0, stream>>>(Hb, fW1, F1P);
  f1b_kernel<<<dim3(16), 256, 0, stream>>>(F1P, fb1, fln1_s, fln1_b, H1b);
  f2_kernel<<<dim3(16), 512, 0, stream>>>(H1b, fW2, fb2, fln2_s, fln2_b, H2b);
  f3_kernel<<<dim3(16), 128, 0, stream>>>(H2b, fW3, fb3, out);
}

// Round 6
// 1212.558 us; speedup vs baseline: 5.5774x; 1.0244x over previous
//
#include <hip/hip_runtime.h>
#include <math.h>

constexpr int Bn = 16;
constexpr int Sn = 512;
constexpr int FCn = 24;
constexpr int FOn = 16;
constexpr int Dn = 512;
constexpr int Hn = 8;
constexpr int DKn = 64;
constexpr int FFn = 2048;
constexpr int Ln = 4;
constexpr int MAXPOSn = 512;
constexpr float EPSf = 1e-6f;

typedef __attribute__((ext_vector_type(8))) short bf16x8;   // 8 bf16 in 4 VGPRs
typedef __attribute__((ext_vector_type(4))) float floatx4;

__device__ __forceinline__ float sigmoidf_(float x) { return 1.0f / (1.0f + __expf(-x)); }

__device__ __forceinline__ unsigned short f2bf(float f) {  // RNE
  unsigned int u = __float_as_uint(f);
  u += 0x7fffu + ((u >> 16) & 1u);
  return (unsigned short)(u >> 16);
}
__device__ __forceinline__ float b2f(unsigned short b) {
  return __uint_as_float(((unsigned int)b) << 16);
}

__device__ __forceinline__ void g2l16(const void* g, void* l) {
  // async global->LDS, 16B/lane, LDS dest = wave-uniform base + lane*16
  __builtin_amdgcn_global_load_lds((const __attribute__((address_space(1))) void*)g,
                                   (__attribute__((address_space(3))) void*)l, 16, 0, 0);
}

// pair-pack bf16 store: even lane stores {self, lane^1} as one dword.
__device__ __forceinline__ void st_bf16_pair(unsigned short* dst, float v, int lane) {
  unsigned int us = f2bf(v);
  unsigned int other = (unsigned int)__shfl_xor((int)us, 1);
  if (!(lane & 1)) *(unsigned int*)dst = us | (other << 16);
}

__device__ __forceinline__ float waveReduceSum(float v) {
  #pragma unroll
  for (int off = 32; off >= 1; off >>= 1) v += __shfl_xor(v, off);
  return v;
}

__device__ __forceinline__ float blockReduceSum(float v) {
  v = waveReduceSum(v);
  __shared__ float red[8];
  const int w = threadIdx.x >> 6;
  const int nw = blockDim.x >> 6;
  if ((threadIdx.x & 63) == 0) red[w] = v;
  __syncthreads();
  float r = 0.0f;
  for (int i = 0; i < nw; ++i) r += red[i];
  __syncthreads();
  return r;
}

// ---------- weight transpose-convert: out[n][k] bf16 = in[k][n] f32 ----------
__global__ __launch_bounds__(256) void wconv_kernel(
    const float* __restrict__ in, unsigned short* __restrict__ out,
    int K, int N, size_t inStride, size_t outStride) {
  __shared__ float tile[32][33];
  in += (size_t)blockIdx.z * inStride;
  out += (size_t)blockIdx.z * outStride;
  const int k0 = blockIdx.y * 32, n0 = blockIdx.x * 32;
  const int tr = threadIdx.x >> 3;         // 0..31
  const int tc4 = (threadIdx.x & 7) * 4;   // 0..28
  float4 vv = *(const float4*)&in[(size_t)(k0 + tr) * N + n0 + tc4];
  tile[tr][tc4 + 0] = vv.x; tile[tr][tc4 + 1] = vv.y;
  tile[tr][tc4 + 2] = vv.z; tile[tr][tc4 + 3] = vv.w;
  __syncthreads();
  ushort4 o4;
  o4.x = f2bf(tile[tc4 + 0][tr]); o4.y = f2bf(tile[tc4 + 1][tr]);
  o4.z = f2bf(tile[tc4 + 2][tr]); o4.w = f2bf(tile[tc4 + 3][tr]);
  *(ushort4*)&out[(size_t)(n0 + tr) * K + k0 + tc4] = o4;
}

// bias concat: [L][2048] = [bq|bk|bv|bg]
__global__ void bcat_kernel(const float* __restrict__ bq, const float* __restrict__ bk,
                            const float* __restrict__ bv, const float* __restrict__ bg,
                            float* __restrict__ out) {
  const int t = blockIdx.x * 256 + threadIdx.x;  // 8192
  const int l = t >> 11;
  const int c = t & 2047;
  float v;
  if (c < 512) v = bq[l * 512 + c];
  else if (c < 1024) v = bk[l * 512 + c - 512];
  else if (c < 1536) v = bv[l * 512 + c - 1024];
  else v = bg[l * 512 + c - 1536];
  out[t] = v;
}

// x = x_cgm @ cgm_W + cgm_b  -> fp32 X and bf16 Xb
__global__ __launch_bounds__(256) void embed_kernel(
    const float* __restrict__ xc, const float* __restrict__ W,
    const float* __restrict__ bias, float* __restrict__ x,
    unsigned short* __restrict__ xb) {
  const int idx = blockIdx.x * 256 + threadIdx.x;
  const int n = idx & (Dn - 1);
  const int m = idx >> 9;
  const float* xr = xc + m * FCn;
  float acc = bias[n];
  #pragma unroll
  for (int k = 0; k < FCn; ++k) acc = fmaf(xr[k], W[k * Dn + n], acc);
  x[idx] = acc;
  xb[idx] = f2bf(acc);
}

__global__ void relmean_kernel(const float* __restrict__ rel, float* __restrict__ rm) {
  const int p = blockIdx.x * blockDim.x + threadIdx.x;
  if (p >= 2 * MAXPOSn - 1) return;
  float s = 0.0f;
  #pragma unroll 8
  for (int d = 0; d < DKn; ++d) s += rel[p * DKn + d];
  rm[p] = s * (1.0f / DKn);
}

// ---------- bf16 MFMA GEMM: C = A[M,K(slice)] @ Bt[N,K]^T (+ bias) ----------
// 128x128 tile, BK=64, XOR-swizzled LDS (chunk g of row R at position g^(R&7);
// rows are 128 B so banks depend only on position — swizzle gives uniform
// 8-lanes-per-position, the wave64-b128 structural optimum).
// XCD-swizzled 1-D grid: xcd = id&7 owns m-panel [xcd*8, xcd*8+8).
// EPI: 0 fp32 +bias; 3 bf16 +bias; 4 qkvg split; 5 fp32 accumulate (split-K p2).
template <int EPI>
__global__ __launch_bounds__(256) void mgemm(
    const unsigned short* __restrict__ A, const unsigned short* __restrict__ Bt,
    const float* __restrict__ bias, float* __restrict__ Cf,
    unsigned short* __restrict__ Cb, unsigned short* __restrict__ Cb2,
    int Astride, int N, int Koff, int Klen, int ldc, int nt) {
  __shared__ unsigned short As[128 * 64];
  __shared__ unsigned short Bs[128 * 64];
  const int t = threadIdx.x;
  const int w = t >> 6;
  const int lane = t & 63;
  const int id = blockIdx.x;
  const int xcd = id & 7;
  const int lid = id >> 3;
  const int n0 = (lid % nt) * 128;
  const int m0 = (xcd * 8 + lid / nt) * 128;
  const int wm = (w >> 1) * 64;
  const int wn = (w & 1) * 64;
  const int lr = lane & 15;
  const int lq = lane >> 4;

  floatx4 acc[4][4];
  #pragma unroll
  for (int i = 0; i < 4; ++i)
    #pragma unroll
    for (int j = 0; j < 4; ++j) acc[i][j] = (floatx4){0.f, 0.f, 0.f, 0.f};

  // staging: 8 rows/call, lane -> row lane>>3, global chunk (lane&7)^(lane>>3)
  const int srow = lane >> 3;
  const int sg = ((lane & 7) ^ srow) * 8;
  // frag-read swizzled positions (shorts) for substep s=0,1
  const int r7 = lr & 7;
  const int p0 = (lq ^ r7) * 8;
  const int p1 = ((4 + lq) ^ r7) * 8;

  for (int k0 = Koff; k0 < Koff + Klen; k0 += 64) {
    __syncthreads();
    #pragma unroll
    for (int r = 0; r < 4; ++r) {
      const int rb = (w * 4 + r) * 8;
      g2l16(&A[(size_t)(m0 + rb + srow) * Astride + k0 + sg], &As[rb * 64]);
      g2l16(&Bt[(size_t)(n0 + rb + srow) * Astride + k0 + sg], &Bs[rb * 64]);
    }
    __syncthreads();
    #pragma unroll
    for (int s = 0; s < 2; ++s) {
      const int ps = s ? p1 : p0;
      bf16x8 af[4], bf[4];
      #pragma unroll
      for (int i = 0; i < 4; ++i)
        af[i] = *(const bf16x8*)&As[(wm + i * 16 + lr) * 64 + ps];
      #pragma unroll
      for (int j = 0; j < 4; ++j)
        bf[j] = *(const bf16x8*)&Bs[(wn + j * 16 + lr) * 64 + ps];
      #pragma unroll
      for (int i = 0; i < 4; ++i)
        #pragma unroll
        for (int j = 0; j < 4; ++j)
          acc[i][j] = __builtin_amdgcn_mfma_f32_16x16x32_bf16(af[i], bf[j], acc[i][j], 0, 0, 0);
    }
  }

  // C/D layout: col = lane&15, row = (lane>>4)*4 + reg
  #pragma unroll
  for (int i = 0; i < 4; ++i) {
    const int row = m0 + wm + i * 16 + lq * 4;
    #pragma unroll
    for (int j = 0; j < 4; ++j) {
      const int col = n0 + wn + j * 16 + lr;
      const int colp = col & ~1;
      #pragma unroll
      for (int r = 0; r < 4; ++r) {
        if (EPI == 0) {
          Cf[(size_t)(row + r) * ldc + col] = acc[i][j][r] + bias[col];
        } else if (EPI == 5) {
          const size_t idx = (size_t)(row + r) * ldc + col;
          Cf[idx] += acc[i][j][r];
        } else if (EPI == 3) {
          st_bf16_pair(&Cb[(size_t)(row + r) * ldc + colp], acc[i][j][r] + bias[col], lane);
        } else if (EPI == 4) {
          const float va = acc[i][j][r] + bias[col];
          if (col < 1536)
            st_bf16_pair(&Cb[(size_t)(row + r) * 1536 + colp], va, lane);
          else
            st_bf16_pair(&Cb2[(size_t)(row + r) * 512 + (colp - 1536)], sigmoidf_(va), lane);
        }
      }
    }
  }
}

// ---------- fused gated FF: C = (A@W1+b1) * sigmoid(A@W2+b2), bf16 out ----------
// Block 128m x 64n; BK=64, swizzled LDS; grid 2048 XCD-swizzled.
__global__ __launch_bounds__(256) void ffgemm(
    const unsigned short* __restrict__ A, const unsigned short* __restrict__ B1t,
    const unsigned short* __restrict__ B2t, const float* __restrict__ b1,
    const float* __restrict__ b2, unsigned short* __restrict__ C, int K) {
  __shared__ unsigned short As[128 * 64];
  __shared__ unsigned short B1s[64 * 64];
  __shared__ unsigned short B2s[64 * 64];
  const int t = threadIdx.x;
  const int w = t >> 6;
  const int lane = t & 63;
  const int id = blockIdx.x;
  const int xcd = id & 7;
  const int lid = id >> 3;            // 0..255
  const int n0 = (lid & 31) * 64;
  const int m0 = (xcd * 8 + (lid >> 5)) * 128;
  const int wm = (w >> 1) * 64;
  const int wn = (w & 1) * 32;
  const int lr = lane & 15;
  const int lq = lane >> 4;

  floatx4 a1[4][2], a2[4][2];
  #pragma unroll
  for (int i = 0; i < 4; ++i)
    #pragma unroll
    for (int j = 0; j < 2; ++j) {
      a1[i][j] = (floatx4){0.f, 0.f, 0.f, 0.f};
      a2[i][j] = (floatx4){0.f, 0.f, 0.f, 0.f};
    }

  const int srow = lane >> 3;
  const int sg = ((lane & 7) ^ srow) * 8;
  const int r7 = lr & 7;
  const int p0 = (lq ^ r7) * 8;
  const int p1 = ((4 + lq) ^ r7) * 8;

  for (int k0 = 0; k0 < K; k0 += 64) {
    __syncthreads();
    #pragma unroll
    for (int r = 0; r < 4; ++r) {
      const int rb = (w * 4 + r) * 8;
      g2l16(&A[(size_t)(m0 + rb + srow) * K + k0 + sg], &As[rb * 64]);
    }
    #pragma unroll
    for (int r = 0; r < 2; ++r) {
      const int rb = (w * 2 + r) * 8;
      g2l16(&B1t[(size_t)(n0 + rb + srow) * K + k0 + sg], &B1s[rb * 64]);
      g2l16(&B2t[(size_t)(n0 + rb + srow) * K + k0 + sg], &B2s[rb * 64]);
    }
    __syncthreads();
    #pragma unroll
    for (int s = 0; s < 2; ++s) {
      const int ps = s ? p1 : p0;
      bf16x8 af[4], f1[2], f2[2];
      #pragma unroll
      for (int i = 0; i < 4; ++i)
        af[i] = *(const bf16x8*)&As[(wm + i * 16 + lr) * 64 + ps];
      #pragma unroll
      for (int j = 0; j < 2; ++j) {
        f1[j] = *(const bf16x8*)&B1s[(wn + j * 16 + lr) * 64 + ps];
        f2[j] = *(const bf16x8*)&B2s[(wn + j * 16 + lr) * 64 + ps];
      }
      #pragma unroll
      for (int i = 0; i < 4; ++i)
        #pragma unroll
        for (int j = 0; j < 2; ++j) {
          a1[i][j] = __builtin_amdgcn_mfma_f32_16x16x32_bf16(af[i], f1[j], a1[i][j], 0, 0, 0);
          a2[i][j] = __builtin_amdgcn_mfma_f32_16x16x32_bf16(af[i], f2[j], a2[i][j], 0, 0, 0);
        }
    }
  }

  #pragma unroll
  for (int i = 0; i < 4; ++i) {
    const int row = m0 + wm + i * 16 + lq * 4;
    #pragma unroll
    for (int j = 0; j < 2; ++j) {
      const int col = n0 + wn + j * 16 + lr;
      const int colp = col & ~1;
      const float bb1 = b1[col], bb2 = b2[col];
      #pragma unroll
      for (int r = 0; r < 4; ++r) {
        const float f = (a1[i][j][r] + bb1) * sigmoidf_(a2[i][j][r] + bb2);
        st_bf16_pair(&C[(size_t)(row + r) * 2048 + colp], f, lane);
      }
    }
  }
}

// ---------- MFMA flash attention ----------
// Grid 1024, XCD-swizzled: b = bid&15.
__global__ __launch_bounds__(256) void attn_kernel(
    const unsigned short* __restrict__ qkv, const float* __restrict__ rm,
    unsigned short* __restrict__ ctx) {
  __shared__ unsigned short Ks[64 * 72];
  __shared__ unsigned short Vt[64 * 72];
  __shared__ unsigned short Pw[4][16 * 72];
  __shared__ float rml[576];
  const int t = threadIdx.x;
  const int w = t >> 6;
  const int lane = t & 63;
  const int lr = lane & 15;
  const int lq = lane >> 4;
  const int bid = blockIdx.x;
  const int b = bid & 15;
  const int h = (bid >> 4) & 7;
  const int qt = bid >> 7;
  const int q0 = qt * 64;
  const size_t rowb = (size_t)b * Sn * 1536;

  for (int i = t; i < 576; i += 256) rml[i] = rm[q0 + i];

  bf16x8 aq0, aq1;
  {
    const unsigned short* qp = &qkv[rowb + (size_t)(q0 + w * 16 + lr) * 1536 + h * 64 + lq * 8];
    aq0 = *(const bf16x8*)qp;
    aq1 = *(const bf16x8*)(qp + 32);
  }

  floatx4 o_acc[4];
  #pragma unroll
  for (int i = 0; i < 4; ++i) o_acc[i] = (floatx4){0.f, 0.f, 0.f, 0.f};
  float m_old[4] = {-1e30f, -1e30f, -1e30f, -1e30f};
  float l_sum[4] = {0.f, 0.f, 0.f, 0.f};

  const int skey = t >> 2;
  const int schk = (t & 3) * 16;
  const int vkp = t >> 4;
  const int vd4 = (t & 15) * 4;

  for (int kc = 0; kc < 8; ++kc) {
    __syncthreads();
    {
      const unsigned short* gk = &qkv[rowb + (size_t)(kc * 64 + skey) * 1536 + 512 + h * 64 + schk];
      *(bf16x8*)&Ks[skey * 72 + schk] = *(const bf16x8*)gk;
      *(bf16x8*)&Ks[skey * 72 + schk + 8] = *(const bf16x8*)(gk + 8);
    }
    #pragma unroll
    for (int pass = 0; pass < 2; ++pass) {
      const int kp = vkp + pass * 16;
      const unsigned short* gv = &qkv[rowb + (size_t)(kc * 64 + kp * 2) * 1536 + 1024 + h * 64 + vd4];
      ushort4 v0 = *(const ushort4*)gv;
      ushort4 v1 = *(const ushort4*)(gv + 1536);
      *(ushort2*)&Vt[(vd4 + 0) * 72 + kp * 2] = make_ushort2(v0.x, v1.x);
      *(ushort2*)&Vt[(vd4 + 1) * 72 + kp * 2] = make_ushort2(v0.y, v1.y);
      *(ushort2*)&Vt[(vd4 + 2) * 72 + kp * 2] = make_ushort2(v0.z, v1.z);
      *(ushort2*)&Vt[(vd4 + 3) * 72 + kp * 2] = make_ushort2(v0.w, v1.w);
    }
    __syncthreads();

    floatx4 s_acc[4];
    #pragma unroll
    for (int j = 0; j < 4; ++j) {
      bf16x8 b0 = *(const bf16x8*)&Ks[(j * 16 + lr) * 72 + lq * 8];
      bf16x8 b1 = *(const bf16x8*)&Ks[(j * 16 + lr) * 72 + 32 + lq * 8];
      s_acc[j] = __builtin_amdgcn_mfma_f32_16x16x32_bf16(aq0, b0, (floatx4){0.f, 0.f, 0.f, 0.f}, 0, 0, 0);
      s_acc[j] = __builtin_amdgcn_mfma_f32_16x16x32_bf16(aq1, b1, s_acc[j], 0, 0, 0);
    }

    float mloc[4] = {-1e30f, -1e30f, -1e30f, -1e30f};
    #pragma unroll
    for (int j = 0; j < 4; ++j) {
      const int key = kc * 64 + j * 16 + lr;
      #pragma unroll
      for (int r = 0; r < 4; ++r) {
        const float sv = s_acc[j][r] * 0.125f + rml[(w * 16 + lq * 4 + r) + 511 - key];
        s_acc[j][r] = sv;
        mloc[r] = fmaxf(mloc[r], sv);
      }
    }
    #pragma unroll
    for (int off = 1; off <= 8; off <<= 1)
      #pragma unroll
      for (int r = 0; r < 4; ++r) mloc[r] = fmaxf(mloc[r], __shfl_xor(mloc[r], off));

    float alpha[4], rsum[4];
    #pragma unroll
    for (int r = 0; r < 4; ++r) {
      const float mnew = fmaxf(m_old[r], mloc[r]);
      alpha[r] = __expf(m_old[r] - mnew);
      m_old[r] = mnew;
      rsum[r] = 0.f;
    }
    #pragma unroll
    for (int j = 0; j < 4; ++j)
      #pragma unroll
      for (int r = 0; r < 4; ++r) {
        const float p = __expf(s_acc[j][r] - m_old[r]);
        rsum[r] += p;
        Pw[w][(lq * 4 + r) * 72 + j * 16 + lr] = f2bf(p);
      }
    #pragma unroll
    for (int off = 1; off <= 8; off <<= 1)
      #pragma unroll
      for (int r = 0; r < 4; ++r) rsum[r] += __shfl_xor(rsum[r], off);
    #pragma unroll
    for (int r = 0; r < 4; ++r) l_sum[r] = l_sum[r] * alpha[r] + rsum[r];
    #pragma unroll
    for (int i = 0; i < 4; ++i)
      #pragma unroll
      for (int r = 0; r < 4; ++r) o_acc[i][r] *= alpha[r];

    bf16x8 ap0 = *(const bf16x8*)&Pw[w][lr * 72 + lq * 8];
    bf16x8 ap1 = *(const bf16x8*)&Pw[w][lr * 72 + 32 + lq * 8];
    #pragma unroll
    for (int i = 0; i < 4; ++i) {
      bf16x8 v0 = *(const bf16x8*)&Vt[(i * 16 + lr) * 72 + lq * 8];
      bf16x8 v1 = *(const bf16x8*)&Vt[(i * 16 + lr) * 72 + 32 + lq * 8];
      o_acc[i] = __builtin_amdgcn_mfma_f32_16x16x32_bf16(ap0, v0, o_acc[i], 0, 0, 0);
      o_acc[i] = __builtin_amdgcn_mfma_f32_16x16x32_bf16(ap1, v1, o_acc[i], 0, 0, 0);
    }
  }

  float rinv[4];
  #pragma unroll
  for (int r = 0; r < 4; ++r) rinv[r] = 1.0f / l_sum[r];
  #pragma unroll
  for (int i = 0; i < 4; ++i)
    #pragma unroll
    for (int r = 0; r < 4; ++r) {
      const int q = q0 + w * 16 + lq * 4 + r;
      ctx[((size_t)(b * Sn + q)) * Dn + h * 64 + i * 16 + lr] = f2bf(o_acc[i][r] * rinv[r]);
    }
}

// ---------- wave-per-row LN (no barriers): 4 rows/block ----------
// ln1: x = LN(x + gate*att) (att/gate bf16)
__global__ __launch_bounds__(256) void ln_res1_kernel(
    float* __restrict__ x, unsigned short* __restrict__ xb,
    const unsigned short* __restrict__ att, const unsigned short* __restrict__ gate,
    const float* __restrict__ s, const float* __restrict__ bsh) {
  const int w = threadIdx.x >> 6, lane = threadIdx.x & 63;
  const int row = blockIdx.x * 4 + w;
  const size_t base = (size_t)row * Dn;
  const int c = lane * 4;
  float4 xv0 = *(const float4*)&x[base + c];
  float4 xv1 = *(const float4*)&x[base + c + 256];
  ushort4 a0 = *(const ushort4*)&att[base + c];
  ushort4 a1 = *(const ushort4*)&att[base + c + 256];
  ushort4 g0 = *(const ushort4*)&gate[base + c];
  ushort4 g1 = *(const ushort4*)&gate[base + c + 256];
  float y[8];
  y[0] = xv0.x + b2f(a0.x) * b2f(g0.x);
  y[1] = xv0.y + b2f(a0.y) * b2f(g0.y);
  y[2] = xv0.z + b2f(a0.z) * b2f(g0.z);
  y[3] = xv0.w + b2f(a0.w) * b2f(g0.w);
  y[4] = xv1.x + b2f(a1.x) * b2f(g1.x);
  y[5] = xv1.y + b2f(a1.y) * b2f(g1.y);
  y[6] = xv1.z + b2f(a1.z) * b2f(g1.z);
  y[7] = xv1.w + b2f(a1.w) * b2f(g1.w);
  float sum = 0.f;
  #pragma unroll
  for (int i = 0; i < 8; ++i) sum += y[i];
  const float mu = waveReduceSum(sum) * (1.0f / Dn);
  float vs = 0.f;
  #pragma unroll
  for (int i = 0; i < 8; ++i) { y[i] -= mu; vs += y[i] * y[i]; }
  const float rstd = rsqrtf(waveReduceSum(vs) * (1.0f / Dn) + EPSf);
  float4 s0 = *(const float4*)&s[c], s1 = *(const float4*)&s[c + 256];
  float4 b0 = *(const float4*)&bsh[c], b1 = *(const float4*)&bsh[c + 256];
  float4 o0, o1;
  o0.x = y[0] * rstd * s0.x + b0.x; o0.y = y[1] * rstd * s0.y + b0.y;
  o0.z = y[2] * rstd * s0.z + b0.z; o0.w = y[3] * rstd * s0.w + b0.w;
  o1.x = y[4] * rstd * s1.x + b1.x; o1.y = y[5] * rstd * s1.y + b1.y;
  o1.z = y[6] * rstd * s1.z + b1.z; o1.w = y[7] * rstd * s1.w + b1.w;
  *(float4*)&x[base + c] = o0;
  *(float4*)&x[base + c + 256] = o1;
  ushort4 ob0, ob1;
  ob0.x = f2bf(o0.x); ob0.y = f2bf(o0.y); ob0.z = f2bf(o0.z); ob0.w = f2bf(o0.w);
  ob1.x = f2bf(o1.x); ob1.y = f2bf(o1.y); ob1.z = f2bf(o1.z); ob1.w = f2bf(o1.w);
  *(ushort4*)&xb[base + c] = ob0;
  *(ushort4*)&xb[base + c + 256] = ob1;
}

// ln2: x = LN(x + add), add fp32
__global__ __launch_bounds__(256) void ln_res2_kernel(
    float* __restrict__ x, unsigned short* __restrict__ xb,
    const float* __restrict__ add, const float* __restrict__ s,
    const float* __restrict__ bsh) {
  const int w = threadIdx.x >> 6, lane = threadIdx.x & 63;
  const int row = blockIdx.x * 4 + w;
  const size_t base = (size_t)row * Dn;
  const int c = lane * 4;
  float4 xv0 = *(const float4*)&x[base + c];
  float4 xv1 = *(const float4*)&x[base + c + 256];
  float4 a0 = *(const float4*)&add[base + c];
  float4 a1 = *(const float4*)&add[base + c + 256];
  float y[8] = {xv0.x + a0.x, xv0.y + a0.y, xv0.z + a0.z, xv0.w + a0.w,
                xv1.x + a1.x, xv1.y + a1.y, xv1.z + a1.z, xv1.w + a1.w};
  float sum = 0.f;
  #pragma unroll
  for (int i = 0; i < 8; ++i) sum += y[i];
  const float mu = waveReduceSum(sum) * (1.0f / Dn);
  float vs = 0.f;
  #pragma unroll
  for (int i = 0; i < 8; ++i) { y[i] -= mu; vs += y[i] * y[i]; }
  const float rstd = rsqrtf(waveReduceSum(vs) * (1.0f / Dn) + EPSf);
  float4 s0 = *(const float4*)&s[c], s1 = *(const float4*)&s[c + 256];
  float4 b0 = *(const float4*)&bsh[c], b1 = *(const float4*)&bsh[c + 256];
  float4 o0, o1;
  o0.x = y[0] * rstd * s0.x + b0.x; o0.y = y[1] * rstd * s0.y + b0.y;
  o0.z = y[2] * rstd * s0.z + b0.z; o0.w = y[3] * rstd * s0.w + b0.w;
  o1.x = y[4] * rstd * s1.x + b1.x; o1.y = y[5] * rstd * s1.y + b1.y;
  o1.z = y[6] * rstd * s1.z + b1.z; o1.w = y[7] * rstd * s1.w + b1.w;
  *(float4*)&x[base + c] = o0;
  *(float4*)&x[base + c + 256] = o1;
  ushort4 ob0, ob1;
  ob0.x = f2bf(o0.x); ob0.y = f2bf(o0.y); ob0.z = f2bf(o0.z); ob0.w = f2bf(o0.w);
  ob1.x = f2bf(o1.x); ob1.y = f2bf(o1.y); ob1.z = f2bf(o1.z); ob1.w = f2bf(o1.w);
  *(ushort4*)&xb[base + c] = ob0;
  *(ushort4*)&xb[base + c + 256] = ob1;
}

// meanpool partial: block (b, sc) sums 64 rows -> part[b][sc][512]
__global__ __launch_bounds__(256) void mp_part_kernel(const float* __restrict__ x,
                                                      float* __restrict__ part) {
  const int b = blockIdx.x, sc = blockIdx.y;
  const int t = threadIdx.x;
  float s0 = 0.f, s1 = 0.f;
  for (int si = sc * 64; si < sc * 64 + 64; ++si) {
    s0 += x[((size_t)(b * Sn + si)) * Dn + t];
    s1 += x[((size_t)(b * Sn + si)) * Dn + t + 256];
  }
  part[(size_t)(b * 8 + sc) * 512 + t] = s0;
  part[(size_t)(b * 8 + sc) * 512 + t + 256] = s1;
}

// combine + xo: h[b][0:512] = mean, h[b][512:1024] = x_other@W+b
__global__ __launch_bounds__(256) void mp_comb_xo_kernel(
    const float* __restrict__ part, const float* __restrict__ xo,
    const float* __restrict__ oW, const float* __restrict__ ob,
    float* __restrict__ h) {
  const int idx = blockIdx.x * 256 + threadIdx.x;  // 8192
  const int b = idx >> 9, d = idx & 511;
  float s = 0.f;
  #pragma unroll
  for (int i = 0; i < 8; ++i) s += part[(size_t)(b * 8 + i) * 512 + d];
  h[b * 1024 + d] = s * (1.0f / Sn);
  float acc = ob[d];
  #pragma unroll
  for (int k = 0; k < FOn; ++k) acc = fmaf(xo[b * FOn + k], oW[k * Dn + d], acc);
  h[b * 1024 + 512 + d] = acc;
}

// f1 phase A: part[b][kq][n] = sum_{k in slice} h[b][k] * W[k][n]   (grid 16x8)
__global__ __launch_bounds__(256) void f1a_kernel(
    const float* __restrict__ h, const float* __restrict__ W,
    float* __restrict__ part) {
  const int b = blockIdx.x, kq = blockIdx.y;
  const int n = threadIdx.x;  // 256
  const float* hr = h + b * 1024 + kq * 128;
  const float* Wp = W + (size_t)(kq * 128) * 256 + n;
  float acc = 0.f;
  #pragma unroll 8
  for (int k = 0; k < 128; ++k) acc = fmaf(hr[k], Wp[(size_t)k * 256], acc);
  part[(size_t)(b * 8 + kq) * 256 + n] = acc;
}

// tail: f1b (sum partials + LN256 + relu) -> f2 (GEMV + LN128 + relu) -> f3 (dot)
__global__ __launch_bounds__(256) void tail_kernel(
    const float* __restrict__ part, const float* __restrict__ fb1,
    const float* __restrict__ fln1_s, const float* __restrict__ fln1_b,
    const float* __restrict__ fW2, const float* __restrict__ fb2,
    const float* __restrict__ fln2_s, const float* __restrict__ fln2_b,
    const float* __restrict__ fW3, const float* __restrict__ fb3,
    float* __restrict__ out) {
  __shared__ float h1[256];
  const int b = blockIdx.x;
  const int t = threadIdx.x;  // 256
  float acc = fb1[t];
  #pragma unroll
  for (int i = 0; i < 8; ++i) acc += part[(size_t)(b * 8 + i) * 256 + t];
  float mu = blockReduceSum(acc) * (1.0f / 256.0f);
  float d = acc - mu;
  float var = blockReduceSum(d * d) * (1.0f / 256.0f);
  h1[t] = fmaxf(d * rsqrtf(var + EPSf) * fln1_s[t] + fln1_b[t], 0.0f);
  __syncthreads();
  float acc2 = 0.f;
  if (t < 128) {
    #pragma unroll 8
    for (int k = 0; k < 256; ++k) acc2 = fmaf(h1[k], fW2[k * 128 + t], acc2);
    acc2 += fb2[t];
  }
  mu = blockReduceSum(t < 128 ? acc2 : 0.f) * (1.0f / 128.0f);
  d = (t < 128) ? acc2 - mu : 0.f;
  var = blockReduceSum(d * d) * (1.0f / 128.0f);
  float v = 0.f;
  if (t < 128) {
    const float h2v = fmaxf(d * rsqrtf(var + EPSf) * fln2_s[t] + fln2_b[t], 0.0f);
    v = h2v * fW3[t];
  }
  v = blockReduceSum(v);
  if (t == 0) out[b] = v + fb3[0];
}

extern "C" void kernel_launch(void* const* d_in, const int* in_sizes, int n_in,
                              void* d_out, int out_size, void* d_ws, size_t ws_size,
                              hipStream_t stream) {
  (void)in_sizes; (void)n_in; (void)out_size; (void)ws_size;
  const float* x_cgm  = (const float*)d_in[0];
  const float* x_other= (const float*)d_in[1];
  const float* cgm_W  = (const float*)d_in[2];
  const float* cgm_b  = (const float*)d_in[3];
  const float* rel_emb= (const float*)d_in[4];
  const float* Wq = (const float*)d_in[5];
  const float* bq = (const float*)d_in[6];
  const float* Wk = (const float*)d_in[7];
  const float* bk = (const float*)d_in[8];
  const float* Wv = (const float*)d_in[9];
  const float* bv = (const float*)d_in[10];
  const float* Wo = (const float*)d_in[11];
  const float* bo = (const float*)d_in[12];
  const float* Wg = (const float*)d_in[13];
  const float* bg = (const float*)d_in[14];
  const float* Wf1 = (const float*)d_in[15];
  const float* bf1 = (const float*)d_in[16];
  const float* Wfg = (const float*)d_in[17];
  const float* bfg = (const float*)d_in[18];
  const float* Wf2 = (const float*)d_in[19];
  const float* bf2 = (const float*)d_in[20];
  const float* ln1_s = (const float*)d_in[21];
  const float* ln1_b = (const float*)d_in[22];
  const float* ln2_s = (const float*)d_in[23];
  const float* ln2_b = (const float*)d_in[24];
  const float* other_W = (const float*)d_in[25];
  const float* other_b = (const float*)d_in[26];
  const float* fW1 = (const float*)d_in[27];
  const float* fb1 = (const float*)d_in[28];
  const float* fln1_s = (const float*)d_in[29];
  const float* fln1_b = (const float*)d_in[30];
  const float* fW2 = (const float*)d_in[31];
  const float* fb2 = (const float*)d_in[32];
  const float* fln2_s = (const float*)d_in[33];
  const float* fln2_b = (const float*)d_in[34];
  const float* fW3 = (const float*)d_in[35];
  const float* fb3 = (const float*)d_in[36];
  float* out = (float*)d_out;

  char* p = (char*)d_ws;
  auto alloc = [&](size_t bytes) { char* r = p; p += (bytes + 255) & ~(size_t)255; return r; };
  float*          X      = (float*)alloc((size_t)8192 * 512 * 4);
  unsigned short* Xb     = (unsigned short*)alloc((size_t)8192 * 512 * 2);
  unsigned short* QKVb   = (unsigned short*)alloc((size_t)8192 * 1536 * 2);  // also CTXo f32
  unsigned short* CTXb   = (unsigned short*)alloc((size_t)8192 * 512 * 2);
  char*           R      = alloc((size_t)8192 * 2048 * 2);  // ATTb|GATEb bf16 / FFBh overlay
  unsigned short* ATTb   = (unsigned short*)R;
  unsigned short* GATEb  = (unsigned short*)(R + (size_t)8192 * 512 * 2);
  unsigned short* FFBh   = (unsigned short*)R;               // [8192][2048] bf16
  float*          CTXo   = (float*)QKVb;
  unsigned short* Wqkvgt = (unsigned short*)alloc((size_t)4 * 2048 * 512 * 2);
  unsigned short* Wot    = (unsigned short*)alloc((size_t)4 * 512 * 512 * 2);
  unsigned short* Wf1t   = (unsigned short*)alloc((size_t)4 * 2048 * 512 * 2);
  unsigned short* Wfgt   = (unsigned short*)alloc((size_t)4 * 2048 * 512 * 2);
  unsigned short* Wf2t   = (unsigned short*)alloc((size_t)4 * 512 * 2048 * 2);
  float*          bqkvg  = (float*)alloc((size_t)4 * 2048 * 4);
  float*          RMb    = (float*)alloc(1024 * 4);
  float*          Hb     = (float*)alloc(16 * 1024 * 4);
  float*          MPP    = (float*)alloc((size_t)16 * 8 * 512 * 4);
  float*          F1P    = (float*)alloc((size_t)16 * 8 * 256 * 4);

  wconv_kernel<<<dim3(16, 16, 4), 256, 0, stream>>>(Wq, Wqkvgt + (size_t)0 * 512, 512, 512,
                                                    (size_t)512 * 512, (size_t)2048 * 512);
  wconv_kernel<<<dim3(16, 16, 4), 256, 0, stream>>>(Wk, Wqkvgt + (size_t)512 * 512, 512, 512,
                                                    (size_t)512 * 512, (size_t)2048 * 512);
  wconv_kernel<<<dim3(16, 16, 4), 256, 0, stream>>>(Wv, Wqkvgt + (size_t)1024 * 512, 512, 512,
                                                    (size_t)512 * 512, (size_t)2048 * 512);
  wconv_kernel<<<dim3(16, 16, 4), 256, 0, stream>>>(Wg, Wqkvgt + (size_t)1536 * 512, 512, 512,
                                                    (size_t)512 * 512, (size_t)2048 * 512);
  wconv_kernel<<<dim3(16, 16, 4), 256, 0, stream>>>(Wo, Wot, 512, 512,
                                                    (size_t)512 * 512, (size_t)512 * 512);
  wconv_kernel<<<dim3(64, 16, 4), 256, 0, stream>>>(Wf1, Wf1t, 512, 2048,
                                                    (size_t)512 * 2048, (size_t)2048 * 512);
  wconv_kernel<<<dim3(64, 16, 4), 256, 0, stream>>>(Wfg, Wfgt, 512, 2048,
                                                    (size_t)512 * 2048, (size_t)2048 * 512);
  wconv_kernel<<<dim3(16, 64, 4), 256, 0, stream>>>(Wf2, Wf2t, 2048, 512,
                                                    (size_t)2048 * 512, (size_t)512 * 2048);
  bcat_kernel<<<dim3(32), 256, 0, stream>>>(bq, bk, bv, bg, bqkvg);

  embed_kernel<<<dim3(16384), dim3(256), 0, stream>>>(x_cgm, cgm_W, cgm_b, X, Xb);
  relmean_kernel<<<dim3(4), dim3(256), 0, stream>>>(rel_emb, RMb);

  for (int l = 0; l < Ln; ++l) {
    const size_t bof = (size_t)l * Dn;
    // fused q|k|v|gate GEMM: N=2048, K=512 (grid 1024, nt=16)
    mgemm<4><<<dim3(1024), 256, 0, stream>>>(Xb, Wqkvgt + (size_t)l * 2048 * 512,
                                             bqkvg + (size_t)l * 2048, nullptr, QKVb, GATEb,
                                             512, 2048, 0, 512, 0, 16);
    attn_kernel<<<dim3(1024), dim3(256), 0, stream>>>(QKVb, RMb, CTXb);
    // Wo: bf16 out (grid 256, nt=4)
    mgemm<3><<<dim3(256), 256, 0, stream>>>(CTXb, Wot + (size_t)l * 512 * 512,
                                            bo + bof, nullptr, ATTb, nullptr,
                                            512, 512, 0, 512, 512, 4);
    ln_res1_kernel<<<dim3(2048), 256, 0, stream>>>(X, Xb, ATTb, GATEb, ln1_s + bof, ln1_b + bof);
    // fused gated FF: N=2048, K=512 (grid 2048)
    ffgemm<<<dim3(2048), 256, 0, stream>>>(Xb, Wf1t + (size_t)l * 2048 * 512,
                                           Wfgt + (size_t)l * 2048 * 512,
                                           bf1 + (size_t)l * FFn, bfg + (size_t)l * FFn,
                                           FFBh, 512);
    // Wf2 split-K: K=2048 -> 2x1024 (grid 256 each, nt=4)
    mgemm<0><<<dim3(256), 256, 0, stream>>>(FFBh, Wf2t + (size_t)l * 512 * 2048,
                                            bf2 + bof, CTXo, nullptr, nullptr,
                                            2048, 512, 0, 1024, 512, 4);
    mgemm<5><<<dim3(256), 256, 0, stream>>>(FFBh, Wf2t + (size_t)l * 512 * 2048,
                                            nullptr, CTXo, nullptr, nullptr,
                                            2048, 512, 1024, 1024, 512, 4);
    ln_res2_kernel<<<dim3(2048), 256, 0, stream>>>(X, Xb, CTXo, ln2_s + bof, ln2_b + bof);
  }

  mp_part_kernel<<<dim3(16, 8), 256, 0, stream>>>(X, MPP);
  mp_comb_xo_kernel<<<dim3(32), 256, 0, stream>>>(MPP, x_other, other_W, other_b, Hb);
  f1a_kernel<<<dim3(16, 8), 256, 0, stream>>>(Hb, fW1, F1P);
  tail_kernel<<<dim3(16), 256, 0, stream>>>(F1P, fb1, fln1_s, fln1_b,
                                            fW2, fb2, fln2_s, fln2_b, fW3, fb3, out);
}

// Round 7
// 1100.956 us; speedup vs baseline: 6.1428x; 1.1014x over previous
//
#include <hip/hip_runtime.h>
#include <math.h>

constexpr int Bn = 16;
constexpr int Sn = 512;
constexpr int FCn = 24;
constexpr int FOn = 16;
constexpr int Dn = 512;
constexpr int Hn = 8;
constexpr int DKn = 64;
constexpr int FFn = 2048;
constexpr int Ln = 4;
constexpr int MAXPOSn = 512;
constexpr float EPSf = 1e-6f;

typedef __attribute__((ext_vector_type(8))) short bf16x8;   // 8 bf16 in 4 VGPRs
typedef __attribute__((ext_vector_type(4))) float floatx4;

__device__ __forceinline__ float sigmoidf_(float x) { return 1.0f / (1.0f + __expf(-x)); }

__device__ __forceinline__ unsigned short f2bf(float f) {  // RNE
  unsigned int u = __float_as_uint(f);
  u += 0x7fffu + ((u >> 16) & 1u);
  return (unsigned short)(u >> 16);
}
__device__ __forceinline__ float b2f(unsigned short b) {
  return __uint_as_float(((unsigned int)b) << 16);
}

__device__ __forceinline__ void g2l16(const void* g, void* l) {
  // async global->LDS, 16B/lane, LDS dest = wave-uniform base + lane*16
  __builtin_amdgcn_global_load_lds((const __attribute__((address_space(1))) void*)g,
                                   (__attribute__((address_space(3))) void*)l, 16, 0, 0);
}

// pair-pack bf16 store: even lane stores {self, lane^1} as one dword.
__device__ __forceinline__ void st_bf16_pair(unsigned short* dst, float v, int lane) {
  unsigned int us = f2bf(v);
  unsigned int other = (unsigned int)__shfl_xor((int)us, 1);
  if (!(lane & 1)) *(unsigned int*)dst = us | (other << 16);
}

__device__ __forceinline__ float waveReduceSum(float v) {
  #pragma unroll
  for (int off = 32; off >= 1; off >>= 1) v += __shfl_xor(v, off);
  return v;
}

__device__ __forceinline__ float blockReduceSum(float v) {
  v = waveReduceSum(v);
  __shared__ float red[8];
  const int w = threadIdx.x >> 6;
  const int nw = blockDim.x >> 6;
  if ((threadIdx.x & 63) == 0) red[w] = v;
  __syncthreads();
  float r = 0.0f;
  for (int i = 0; i < nw; ++i) r += red[i];
  __syncthreads();
  return r;
}

// ---------- weight transpose-convert: out[n][k] bf16 = in[k][n] f32 ----------
__global__ __launch_bounds__(256) void wconv_kernel(
    const float* __restrict__ in, unsigned short* __restrict__ out,
    int K, int N, size_t inStride, size_t outStride) {
  __shared__ float tile[32][33];
  in += (size_t)blockIdx.z * inStride;
  out += (size_t)blockIdx.z * outStride;
  const int k0 = blockIdx.y * 32, n0 = blockIdx.x * 32;
  const int tr = threadIdx.x >> 3;         // 0..31
  const int tc4 = (threadIdx.x & 7) * 4;   // 0..28
  float4 vv = *(const float4*)&in[(size_t)(k0 + tr) * N + n0 + tc4];
  tile[tr][tc4 + 0] = vv.x; tile[tr][tc4 + 1] = vv.y;
  tile[tr][tc4 + 2] = vv.z; tile[tr][tc4 + 3] = vv.w;
  __syncthreads();
  ushort4 o4;
  o4.x = f2bf(tile[tc4 + 0][tr]); o4.y = f2bf(tile[tc4 + 1][tr]);
  o4.z = f2bf(tile[tc4 + 2][tr]); o4.w = f2bf(tile[tc4 + 3][tr]);
  *(ushort4*)&out[(size_t)(n0 + tr) * K + k0 + tc4] = o4;
}

// bias concat: [L][2048] = [bq|bk|bv|bg]
__global__ void bcat_kernel(const float* __restrict__ bq, const float* __restrict__ bk,
                            const float* __restrict__ bv, const float* __restrict__ bg,
                            float* __restrict__ out) {
  const int t = blockIdx.x * 256 + threadIdx.x;  // 8192
  const int l = t >> 11;
  const int c = t & 2047;
  float v;
  if (c < 512) v = bq[l * 512 + c];
  else if (c < 1024) v = bk[l * 512 + c - 512];
  else if (c < 1536) v = bv[l * 512 + c - 1024];
  else v = bg[l * 512 + c - 1536];
  out[t] = v;
}

// x = x_cgm @ cgm_W + cgm_b  -> fp32 X and bf16 Xb
__global__ __launch_bounds__(256) void embed_kernel(
    const float* __restrict__ xc, const float* __restrict__ W,
    const float* __restrict__ bias, float* __restrict__ x,
    unsigned short* __restrict__ xb) {
  const int idx = blockIdx.x * 256 + threadIdx.x;
  const int n = idx & (Dn - 1);
  const int m = idx >> 9;
  const float* xr = xc + m * FCn;
  float acc = bias[n];
  #pragma unroll
  for (int k = 0; k < FCn; ++k) acc = fmaf(xr[k], W[k * Dn + n], acc);
  x[idx] = acc;
  xb[idx] = f2bf(acc);
}

__global__ void relmean_kernel(const float* __restrict__ rel, float* __restrict__ rm) {
  const int p = blockIdx.x * blockDim.x + threadIdx.x;
  if (p >= 2 * MAXPOSn - 1) return;
  float s = 0.0f;
  #pragma unroll 8
  for (int d = 0; d < DKn; ++d) s += rel[p * DKn + d];
  rm[p] = s * (1.0f / DKn);
}

// ---------- bf16 MFMA GEMM (round-5 proven): 128x128 tile, BK=32 ----------
// XCD-swizzled 1-D grid: xcd = id&7 owns m-panel [xcd*8, xcd*8+8).
// EPI: 0 fp32 +bias; 3 bf16 +bias (pair-packed); 4 qkvg split.
template <int EPI>
__global__ __launch_bounds__(256) void mgemm(
    const unsigned short* __restrict__ A, const unsigned short* __restrict__ Bt,
    const float* __restrict__ bias, float* __restrict__ Cf,
    unsigned short* __restrict__ Cb, unsigned short* __restrict__ Cb2,
    int Astride, int N, int Klen, int ldc, int nt) {
  __shared__ unsigned short As[128 * 32];
  __shared__ unsigned short Bs[128 * 32];
  const int t = threadIdx.x;
  const int w = t >> 6;
  const int lane = t & 63;
  const int id = blockIdx.x;
  const int xcd = id & 7;
  const int lid = id >> 3;
  const int n0 = (lid % nt) * 128;
  const int m0 = (xcd * 8 + lid / nt) * 128;
  const int wm = (w >> 1) * 64;
  const int wn = (w & 1) * 64;
  const int lr = lane & 15;
  const int lq = lane >> 4;

  floatx4 acc[4][4];
  #pragma unroll
  for (int i = 0; i < 4; ++i)
    #pragma unroll
    for (int j = 0; j < 4; ++j) acc[i][j] = (floatx4){0.f, 0.f, 0.f, 0.f};

  const int srow = lane >> 2;   // 0..15
  const int schk = (lane & 3) * 8;

  for (int k0 = 0; k0 < Klen; k0 += 32) {
    __syncthreads();
    #pragma unroll
    for (int r = 0; r < 2; ++r) {
      const int rb = (w * 2 + r) * 16;
      g2l16(&A[(size_t)(m0 + rb + srow) * Astride + k0 + schk], &As[rb * 32]);
      g2l16(&Bt[(size_t)(n0 + rb + srow) * Astride + k0 + schk], &Bs[rb * 32]);
    }
    __syncthreads();
    bf16x8 af[4], bf[4];
    #pragma unroll
    for (int i = 0; i < 4; ++i)
      af[i] = *(const bf16x8*)&As[(wm + i * 16 + lr) * 32 + lq * 8];
    #pragma unroll
    for (int j = 0; j < 4; ++j)
      bf[j] = *(const bf16x8*)&Bs[(wn + j * 16 + lr) * 32 + lq * 8];
    #pragma unroll
    for (int i = 0; i < 4; ++i)
      #pragma unroll
      for (int j = 0; j < 4; ++j)
        acc[i][j] = __builtin_amdgcn_mfma_f32_16x16x32_bf16(af[i], bf[j], acc[i][j], 0, 0, 0);
  }

  // C/D layout: col = lane&15, row = (lane>>4)*4 + reg
  #pragma unroll
  for (int i = 0; i < 4; ++i) {
    const int row = m0 + wm + i * 16 + lq * 4;
    #pragma unroll
    for (int j = 0; j < 4; ++j) {
      const int col = n0 + wn + j * 16 + lr;
      const int colp = col & ~1;
      #pragma unroll
      for (int r = 0; r < 4; ++r) {
        if (EPI == 0) {
          Cf[(size_t)(row + r) * ldc + col] = acc[i][j][r] + bias[col];
        } else if (EPI == 3) {
          st_bf16_pair(&Cb[(size_t)(row + r) * ldc + colp], acc[i][j][r] + bias[col], lane);
        } else if (EPI == 4) {
          const float va = acc[i][j][r] + bias[col];
          if (col < 1536)
            st_bf16_pair(&Cb[(size_t)(row + r) * 1536 + colp], va, lane);
          else
            st_bf16_pair(&Cb2[(size_t)(row + r) * 512 + (colp - 1536)], sigmoidf_(va), lane);
        }
      }
    }
  }
}

// ---------- bf16 MFMA GEMM, 128m x 64n tile (for N=512: Wo, Wf2) ----------
// Grid 512 = 2 blocks/CU, 8 waves/CU (fixes the 1-block/CU starvation of the
// 128x128 tile at N=512). Wave = 64m x 32n. 12 KB LDS. Full-K (no split).
// EPI: 0 fp32 +bias; 3 bf16 +bias (pair-packed).
template <int EPI>
__global__ __launch_bounds__(256) void mgemm_n64(
    const unsigned short* __restrict__ A, const unsigned short* __restrict__ Bt,
    const float* __restrict__ bias, float* __restrict__ Cf,
    unsigned short* __restrict__ Cb, int Astride, int Klen, int ldc) {
  __shared__ unsigned short As[128 * 32];
  __shared__ unsigned short Bs[64 * 32];
  const int t = threadIdx.x;
  const int w = t >> 6;
  const int lane = t & 63;
  const int id = blockIdx.x;
  const int xcd = id & 7;
  const int lid = id >> 3;               // 0..63
  const int n0 = (lid & 7) * 64;         // 8 n-tiles
  const int m0 = (xcd * 8 + (lid >> 3)) * 128;
  const int wm = (w >> 1) * 64;
  const int wn = (w & 1) * 32;
  const int lr = lane & 15;
  const int lq = lane >> 4;

  floatx4 acc[4][2];
  #pragma unroll
  for (int i = 0; i < 4; ++i)
    #pragma unroll
    for (int j = 0; j < 2; ++j) acc[i][j] = (floatx4){0.f, 0.f, 0.f, 0.f};

  const int srow = lane >> 2;
  const int schk = (lane & 3) * 8;

  for (int k0 = 0; k0 < Klen; k0 += 32) {
    __syncthreads();
    #pragma unroll
    for (int r = 0; r < 2; ++r) {
      const int rb = (w * 2 + r) * 16;
      g2l16(&A[(size_t)(m0 + rb + srow) * Astride + k0 + schk], &As[rb * 32]);
    }
    g2l16(&Bt[(size_t)(n0 + w * 16 + srow) * Astride + k0 + schk], &Bs[(w * 16) * 32]);
    __syncthreads();
    bf16x8 af[4], bf[2];
    #pragma unroll
    for (int i = 0; i < 4; ++i)
      af[i] = *(const bf16x8*)&As[(wm + i * 16 + lr) * 32 + lq * 8];
    #pragma unroll
    for (int j = 0; j < 2; ++j)
      bf[j] = *(const bf16x8*)&Bs[(wn + j * 16 + lr) * 32 + lq * 8];
    #pragma unroll
    for (int i = 0; i < 4; ++i)
      #pragma unroll
      for (int j = 0; j < 2; ++j)
        acc[i][j] = __builtin_amdgcn_mfma_f32_16x16x32_bf16(af[i], bf[j], acc[i][j], 0, 0, 0);
  }

  #pragma unroll
  for (int i = 0; i < 4; ++i) {
    const int row = m0 + wm + i * 16 + lq * 4;
    #pragma unroll
    for (int j = 0; j < 2; ++j) {
      const int col = n0 + wn + j * 16 + lr;
      const int colp = col & ~1;
      const float bv = bias[col];
      #pragma unroll
      for (int r = 0; r < 4; ++r) {
        if (EPI == 0) {
          Cf[(size_t)(row + r) * ldc + col] = acc[i][j][r] + bv;
        } else {
          st_bf16_pair(&Cb[(size_t)(row + r) * ldc + colp], acc[i][j][r] + bv, lane);
        }
      }
    }
  }
}

// ---------- fused gated FF (round-5 proven): C = (A@W1+b1)*sigmoid(A@W2+b2) ----------
__global__ __launch_bounds__(256) void ffgemm(
    const unsigned short* __restrict__ A, const unsigned short* __restrict__ B1t,
    const unsigned short* __restrict__ B2t, const float* __restrict__ b1,
    const float* __restrict__ b2, unsigned short* __restrict__ C, int K) {
  __shared__ unsigned short As[128 * 32];
  __shared__ unsigned short B1s[64 * 32];
  __shared__ unsigned short B2s[64 * 32];
  const int t = threadIdx.x;
  const int w = t >> 6;
  const int lane = t & 63;
  const int id = blockIdx.x;
  const int xcd = id & 7;
  const int lid = id >> 3;            // 0..255
  const int n0 = (lid & 31) * 64;
  const int m0 = (xcd * 8 + (lid >> 5)) * 128;
  const int wm = (w >> 1) * 64;
  const int wn = (w & 1) * 32;
  const int lr = lane & 15;
  const int lq = lane >> 4;

  floatx4 a1[4][2], a2[4][2];
  #pragma unroll
  for (int i = 0; i < 4; ++i)
    #pragma unroll
    for (int j = 0; j < 2; ++j) {
      a1[i][j] = (floatx4){0.f, 0.f, 0.f, 0.f};
      a2[i][j] = (floatx4){0.f, 0.f, 0.f, 0.f};
    }

  const int srow = lane >> 2;
  const int schk = (lane & 3) * 8;

  for (int k0 = 0; k0 < K; k0 += 32) {
    __syncthreads();
    g2l16(&A[(size_t)(m0 + w * 32 + srow) * K + k0 + schk], &As[(w * 32) * 32]);
    g2l16(&A[(size_t)(m0 + w * 32 + 16 + srow) * K + k0 + schk], &As[(w * 32 + 16) * 32]);
    g2l16(&B1t[(size_t)(n0 + w * 16 + srow) * K + k0 + schk], &B1s[(w * 16) * 32]);
    g2l16(&B2t[(size_t)(n0 + w * 16 + srow) * K + k0 + schk], &B2s[(w * 16) * 32]);
    __syncthreads();
    bf16x8 af[4], f1[2], f2[2];
    #pragma unroll
    for (int i = 0; i < 4; ++i)
      af[i] = *(const bf16x8*)&As[(wm + i * 16 + lr) * 32 + lq * 8];
    #pragma unroll
    for (int j = 0; j < 2; ++j) {
      f1[j] = *(const bf16x8*)&B1s[(wn + j * 16 + lr) * 32 + lq * 8];
      f2[j] = *(const bf16x8*)&B2s[(wn + j * 16 + lr) * 32 + lq * 8];
    }
    #pragma unroll
    for (int i = 0; i < 4; ++i)
      #pragma unroll
      for (int j = 0; j < 2; ++j) {
        a1[i][j] = __builtin_amdgcn_mfma_f32_16x16x32_bf16(af[i], f1[j], a1[i][j], 0, 0, 0);
        a2[i][j] = __builtin_amdgcn_mfma_f32_16x16x32_bf16(af[i], f2[j], a2[i][j], 0, 0, 0);
      }
  }

  #pragma unroll
  for (int i = 0; i < 4; ++i) {
    const int row = m0 + wm + i * 16 + lq * 4;
    #pragma unroll
    for (int j = 0; j < 2; ++j) {
      const int col = n0 + wn + j * 16 + lr;
      const int colp = col & ~1;
      const float bb1 = b1[col], bb2 = b2[col];
      #pragma unroll
      for (int r = 0; r < 4; ++r) {
        const float f = (a1[i][j][r] + bb1) * sigmoidf_(a2[i][j][r] + bb2);
        st_bf16_pair(&C[(size_t)(row + r) * 2048 + colp], f, lane);
      }
    }
  }
}

// ---------- MFMA flash attention ----------
__global__ __launch_bounds__(256) void attn_kernel(
    const unsigned short* __restrict__ qkv, const float* __restrict__ rm,
    unsigned short* __restrict__ ctx) {
  __shared__ unsigned short Ks[64 * 72];
  __shared__ unsigned short Vt[64 * 72];
  __shared__ unsigned short Pw[4][16 * 72];
  __shared__ float rml[576];
  const int t = threadIdx.x;
  const int w = t >> 6;
  const int lane = t & 63;
  const int lr = lane & 15;
  const int lq = lane >> 4;
  const int bid = blockIdx.x;
  const int b = bid & 15;
  const int h = (bid >> 4) & 7;
  const int qt = bid >> 7;
  const int q0 = qt * 64;
  const size_t rowb = (size_t)b * Sn * 1536;

  for (int i = t; i < 576; i += 256) rml[i] = rm[q0 + i];

  bf16x8 aq0, aq1;
  {
    const unsigned short* qp = &qkv[rowb + (size_t)(q0 + w * 16 + lr) * 1536 + h * 64 + lq * 8];
    aq0 = *(const bf16x8*)qp;
    aq1 = *(const bf16x8*)(qp + 32);
  }

  floatx4 o_acc[4];
  #pragma unroll
  for (int i = 0; i < 4; ++i) o_acc[i] = (floatx4){0.f, 0.f, 0.f, 0.f};
  float m_old[4] = {-1e30f, -1e30f, -1e30f, -1e30f};
  float l_sum[4] = {0.f, 0.f, 0.f, 0.f};

  const int skey = t >> 2;
  const int schk = (t & 3) * 16;
  const int vkp = t >> 4;
  const int vd4 = (t & 15) * 4;

  for (int kc = 0; kc < 8; ++kc) {
    __syncthreads();
    {
      const unsigned short* gk = &qkv[rowb + (size_t)(kc * 64 + skey) * 1536 + 512 + h * 64 + schk];
      *(bf16x8*)&Ks[skey * 72 + schk] = *(const bf16x8*)gk;
      *(bf16x8*)&Ks[skey * 72 + schk + 8] = *(const bf16x8*)(gk + 8);
    }
    #pragma unroll
    for (int pass = 0; pass < 2; ++pass) {
      const int kp = vkp + pass * 16;
      const unsigned short* gv = &qkv[rowb + (size_t)(kc * 64 + kp * 2) * 1536 + 1024 + h * 64 + vd4];
      ushort4 v0 = *(const ushort4*)gv;
      ushort4 v1 = *(const ushort4*)(gv + 1536);
      *(ushort2*)&Vt[(vd4 + 0) * 72 + kp * 2] = make_ushort2(v0.x, v1.x);
      *(ushort2*)&Vt[(vd4 + 1) * 72 + kp * 2] = make_ushort2(v0.y, v1.y);
      *(ushort2*)&Vt[(vd4 + 2) * 72 + kp * 2] = make_ushort2(v0.z, v1.z);
      *(ushort2*)&Vt[(vd4 + 3) * 72 + kp * 2] = make_ushort2(v0.w, v1.w);
    }
    __syncthreads();

    floatx4 s_acc[4];
    #pragma unroll
    for (int j = 0; j < 4; ++j) {
      bf16x8 b0 = *(const bf16x8*)&Ks[(j * 16 + lr) * 72 + lq * 8];
      bf16x8 b1 = *(const bf16x8*)&Ks[(j * 16 + lr) * 72 + 32 + lq * 8];
      s_acc[j] = __builtin_amdgcn_mfma_f32_16x16x32_bf16(aq0, b0, (floatx4){0.f, 0.f, 0.f, 0.f}, 0, 0, 0);
      s_acc[j] = __builtin_amdgcn_mfma_f32_16x16x32_bf16(aq1, b1, s_acc[j], 0, 0, 0);
    }

    float mloc[4] = {-1e30f, -1e30f, -1e30f, -1e30f};
    #pragma unroll
    for (int j = 0; j < 4; ++j) {
      const int key = kc * 64 + j * 16 + lr;
      #pragma unroll
      for (int r = 0; r < 4; ++r) {
        const float sv = s_acc[j][r] * 0.125f + rml[(w * 16 + lq * 4 + r) + 511 - key];
        s_acc[j][r] = sv;
        mloc[r] = fmaxf(mloc[r], sv);
      }
    }
    #pragma unroll
    for (int off = 1; off <= 8; off <<= 1)
      #pragma unroll
      for (int r = 0; r < 4; ++r) mloc[r] = fmaxf(mloc[r], __shfl_xor(mloc[r], off));

    float alpha[4], rsum[4];
    #pragma unroll
    for (int r = 0; r < 4; ++r) {
      const float mnew = fmaxf(m_old[r], mloc[r]);
      alpha[r] = __expf(m_old[r] - mnew);
      m_old[r] = mnew;
      rsum[r] = 0.f;
    }
    #pragma unroll
    for (int j = 0; j < 4; ++j)
      #pragma unroll
      for (int r = 0; r < 4; ++r) {
        const float p = __expf(s_acc[j][r] - m_old[r]);
        rsum[r] += p;
        Pw[w][(lq * 4 + r) * 72 + j * 16 + lr] = f2bf(p);
      }
    #pragma unroll
    for (int off = 1; off <= 8; off <<= 1)
      #pragma unroll
      for (int r = 0; r < 4; ++r) rsum[r] += __shfl_xor(rsum[r], off);
    #pragma unroll
    for (int r = 0; r < 4; ++r) l_sum[r] = l_sum[r] * alpha[r] + rsum[r];
    #pragma unroll
    for (int i = 0; i < 4; ++i)
      #pragma unroll
      for (int r = 0; r < 4; ++r) o_acc[i][r] *= alpha[r];

    bf16x8 ap0 = *(const bf16x8*)&Pw[w][lr * 72 + lq * 8];
    bf16x8 ap1 = *(const bf16x8*)&Pw[w][lr * 72 + 32 + lq * 8];
    #pragma unroll
    for (int i = 0; i < 4; ++i) {
      bf16x8 v0 = *(const bf16x8*)&Vt[(i * 16 + lr) * 72 + lq * 8];
      bf16x8 v1 = *(const bf16x8*)&Vt[(i * 16 + lr) * 72 + 32 + lq * 8];
      o_acc[i] = __builtin_amdgcn_mfma_f32_16x16x32_bf16(ap0, v0, o_acc[i], 0, 0, 0);
      o_acc[i] = __builtin_amdgcn_mfma_f32_16x16x32_bf16(ap1, v1, o_acc[i], 0, 0, 0);
    }
  }

  float rinv[4];
  #pragma unroll
  for (int r = 0; r < 4; ++r) rinv[r] = 1.0f / l_sum[r];
  #pragma unroll
  for (int i = 0; i < 4; ++i)
    #pragma unroll
    for (int r = 0; r < 4; ++r) {
      const int q = q0 + w * 16 + lq * 4 + r;
      ctx[((size_t)(b * Sn + q)) * Dn + h * 64 + i * 16 + lr] = f2bf(o_acc[i][r] * rinv[r]);
    }
}

// ---------- wave-per-row LN (no barriers): 4 rows/block ----------
__global__ __launch_bounds__(256) void ln_res1_kernel(
    float* __restrict__ x, unsigned short* __restrict__ xb,
    const unsigned short* __restrict__ att, const unsigned short* __restrict__ gate,
    const float* __restrict__ s, const float* __restrict__ bsh) {
  const int w = threadIdx.x >> 6, lane = threadIdx.x & 63;
  const int row = blockIdx.x * 4 + w;
  const size_t base = (size_t)row * Dn;
  const int c = lane * 4;
  float4 xv0 = *(const float4*)&x[base + c];
  float4 xv1 = *(const float4*)&x[base + c + 256];
  ushort4 a0 = *(const ushort4*)&att[base + c];
  ushort4 a1 = *(const ushort4*)&att[base + c + 256];
  ushort4 g0 = *(const ushort4*)&gate[base + c];
  ushort4 g1 = *(const ushort4*)&gate[base + c + 256];
  float y[8];
  y[0] = xv0.x + b2f(a0.x) * b2f(g0.x);
  y[1] = xv0.y + b2f(a0.y) * b2f(g0.y);
  y[2] = xv0.z + b2f(a0.z) * b2f(g0.z);
  y[3] = xv0.w + b2f(a0.w) * b2f(g0.w);
  y[4] = xv1.x + b2f(a1.x) * b2f(g1.x);
  y[5] = xv1.y + b2f(a1.y) * b2f(g1.y);
  y[6] = xv1.z + b2f(a1.z) * b2f(g1.z);
  y[7] = xv1.w + b2f(a1.w) * b2f(g1.w);
  float sum = 0.f;
  #pragma unroll
  for (int i = 0; i < 8; ++i) sum += y[i];
  const float mu = waveReduceSum(sum) * (1.0f / Dn);
  float vs = 0.f;
  #pragma unroll
  for (int i = 0; i < 8; ++i) { y[i] -= mu; vs += y[i] * y[i]; }
  const float rstd = rsqrtf(waveReduceSum(vs) * (1.0f / Dn) + EPSf);
  float4 s0 = *(const float4*)&s[c], s1 = *(const float4*)&s[c + 256];
  float4 b0 = *(const float4*)&bsh[c], b1 = *(const float4*)&bsh[c + 256];
  float4 o0, o1;
  o0.x = y[0] * rstd * s0.x + b0.x; o0.y = y[1] * rstd * s0.y + b0.y;
  o0.z = y[2] * rstd * s0.z + b0.z; o0.w = y[3] * rstd * s0.w + b0.w;
  o1.x = y[4] * rstd * s1.x + b1.x; o1.y = y[5] * rstd * s1.y + b1.y;
  o1.z = y[6] * rstd * s1.z + b1.z; o1.w = y[7] * rstd * s1.w + b1.w;
  *(float4*)&x[base + c] = o0;
  *(float4*)&x[base + c + 256] = o1;
  ushort4 ob0, ob1;
  ob0.x = f2bf(o0.x); ob0.y = f2bf(o0.y); ob0.z = f2bf(o0.z); ob0.w = f2bf(o0.w);
  ob1.x = f2bf(o1.x); ob1.y = f2bf(o1.y); ob1.z = f2bf(o1.z); ob1.w = f2bf(o1.w);
  *(ushort4*)&xb[base + c] = ob0;
  *(ushort4*)&xb[base + c + 256] = ob1;
}

__global__ __launch_bounds__(256) void ln_res2_kernel(
    float* __restrict__ x, unsigned short* __restrict__ xb,
    const float* __restrict__ add, const float* __restrict__ s,
    const float* __restrict__ bsh) {
  const int w = threadIdx.x >> 6, lane = threadIdx.x & 63;
  const int row = blockIdx.x * 4 + w;
  const size_t base = (size_t)row * Dn;
  const int c = lane * 4;
  float4 xv0 = *(const float4*)&x[base + c];
  float4 xv1 = *(const float4*)&x[base + c + 256];
  float4 a0 = *(const float4*)&add[base + c];
  float4 a1 = *(const float4*)&add[base + c + 256];
  float y[8] = {xv0.x + a0.x, xv0.y + a0.y, xv0.z + a0.z, xv0.w + a0.w,
                xv1.x + a1.x, xv1.y + a1.y, xv1.z + a1.z, xv1.w + a1.w};
  float sum = 0.f;
  #pragma unroll
  for (int i = 0; i < 8; ++i) sum += y[i];
  const float mu = waveReduceSum(sum) * (1.0f / Dn);
  float vs = 0.f;
  #pragma unroll
  for (int i = 0; i < 8; ++i) { y[i] -= mu; vs += y[i] * y[i]; }
  const float rstd = rsqrtf(waveReduceSum(vs) * (1.0f / Dn) + EPSf);
  float4 s0 = *(const float4*)&s[c], s1 = *(const float4*)&s[c + 256];
  float4 b0 = *(const float4*)&bsh[c], b1 = *(const float4*)&bsh[c + 256];
  float4 o0, o1;
  o0.x = y[0] * rstd * s0.x + b0.x; o0.y = y[1] * rstd * s0.y + b0.y;
  o0.z = y[2] * rstd * s0.z + b0.z; o0.w = y[3] * rstd * s0.w + b0.w;
  o1.x = y[4] * rstd * s1.x + b1.x; o1.y = y[5] * rstd * s1.y + b1.y;
  o1.z = y[6] * rstd * s1.z + b1.z; o1.w = y[7] * rstd * s1.w + b1.w;
  *(float4*)&x[base + c] = o0;
  *(float4*)&x[base + c + 256] = o1;
  ushort4 ob0, ob1;
  ob0.x = f2bf(o0.x); ob0.y = f2bf(o0.y); ob0.z = f2bf(o0.z); ob0.w = f2bf(o0.w);
  ob1.x = f2bf(o1.x); ob1.y = f2bf(o1.y); ob1.z = f2bf(o1.z); ob1.w = f2bf(o1.w);
  *(ushort4*)&xb[base + c] = ob0;
  *(ushort4*)&xb[base + c + 256] = ob1;
}

// meanpool partial: block (b, sc) sums 64 rows -> part[b][sc][512]
__global__ __launch_bounds__(256) void mp_part_kernel(const float* __restrict__ x,
                                                      float* __restrict__ part) {
  const int b = blockIdx.x, sc = blockIdx.y;
  const int t = threadIdx.x;
  float s0 = 0.f, s1 = 0.f;
  for (int si = sc * 64; si < sc * 64 + 64; ++si) {
    s0 += x[((size_t)(b * Sn + si)) * Dn + t];
    s1 += x[((size_t)(b * Sn + si)) * Dn + t + 256];
  }
  part[(size_t)(b * 8 + sc) * 512 + t] = s0;
  part[(size_t)(b * 8 + sc) * 512 + t + 256] = s1;
}

// combine + xo: h[b][0:512] = mean, h[b][512:1024] = x_other@W+b
__global__ __launch_bounds__(256) void mp_comb_xo_kernel(
    const float* __restrict__ part, const float* __restrict__ xo,
    const float* __restrict__ oW, const float* __restrict__ ob,
    float* __restrict__ h) {
  const int idx = blockIdx.x * 256 + threadIdx.x;  // 8192
  const int b = idx >> 9, d = idx & 511;
  float s = 0.f;
  #pragma unroll
  for (int i = 0; i < 8; ++i) s += part[(size_t)(b * 8 + i) * 512 + d];
  h[b * 1024 + d] = s * (1.0f / Sn);
  float acc = ob[d];
  #pragma unroll
  for (int k = 0; k < FOn; ++k) acc = fmaf(xo[b * FOn + k], oW[k * Dn + d], acc);
  h[b * 1024 + 512 + d] = acc;
}

// f1 phase A: part[b][kq][n] = sum_{k in slice} h[b][k] * W[k][n]   (grid 16x8)
__global__ __launch_bounds__(256) void f1a_kernel(
    const float* __restrict__ h, const float* __restrict__ W,
    float* __restrict__ part) {
  const int b = blockIdx.x, kq = blockIdx.y;
  const int n = threadIdx.x;  // 256
  const float* hr = h + b * 1024 + kq * 128;
  const float* Wp = W + (size_t)(kq * 128) * 256 + n;
  float acc = 0.f;
  #pragma unroll 8
  for (int k = 0; k < 128; ++k) acc = fmaf(hr[k], Wp[(size_t)k * 256], acc);
  part[(size_t)(b * 8 + kq) * 256 + n] = acc;
}

// tail: f1b (sum partials + LN256 + relu) -> f2 (GEMV + LN128 + relu) -> f3 (dot)
__global__ __launch_bounds__(256) void tail_kernel(
    const float* __restrict__ part, const float* __restrict__ fb1,
    const float* __restrict__ fln1_s, const float* __restrict__ fln1_b,
    const float* __restrict__ fW2, const float* __restrict__ fb2,
    const float* __restrict__ fln2_s, const float* __restrict__ fln2_b,
    const float* __restrict__ fW3, const float* __restrict__ fb3,
    float* __restrict__ out) {
  __shared__ float h1[256];
  const int b = blockIdx.x;
  const int t = threadIdx.x;  // 256
  float acc = fb1[t];
  #pragma unroll
  for (int i = 0; i < 8; ++i) acc += part[(size_t)(b * 8 + i) * 256 + t];
  float mu = blockReduceSum(acc) * (1.0f / 256.0f);
  float d = acc - mu;
  float var = blockReduceSum(d * d) * (1.0f / 256.0f);
  h1[t] = fmaxf(d * rsqrtf(var + EPSf) * fln1_s[t] + fln1_b[t], 0.0f);
  __syncthreads();
  float acc2 = 0.f;
  if (t < 128) {
    #pragma unroll 8
    for (int k = 0; k < 256; ++k) acc2 = fmaf(h1[k], fW2[k * 128 + t], acc2);
    acc2 += fb2[t];
  }
  mu = blockReduceSum(t < 128 ? acc2 : 0.f) * (1.0f / 128.0f);
  d = (t < 128) ? acc2 - mu : 0.f;
  var = blockReduceSum(d * d) * (1.0f / 128.0f);
  float v = 0.f;
  if (t < 128) {
    const float h2v = fmaxf(d * rsqrtf(var + EPSf) * fln2_s[t] + fln2_b[t], 0.0f);
    v = h2v * fW3[t];
  }
  v = blockReduceSum(v);
  if (t == 0) out[b] = v + fb3[0];
}

extern "C" void kernel_launch(void* const* d_in, const int* in_sizes, int n_in,
                              void* d_out, int out_size, void* d_ws, size_t ws_size,
                              hipStream_t stream) {
  (void)in_sizes; (void)n_in; (void)out_size; (void)ws_size;
  const float* x_cgm  = (const float*)d_in[0];
  const float* x_other= (const float*)d_in[1];
  const float* cgm_W  = (const float*)d_in[2];
  const float* cgm_b  = (const float*)d_in[3];
  const float* rel_emb= (const float*)d_in[4];
  const float* Wq = (const float*)d_in[5];
  const float* bq = (const float*)d_in[6];
  const float* Wk = (const float*)d_in[7];
  const float* bk = (const float*)d_in[8];
  const float* Wv = (const float*)d_in[9];
  const float* bv = (const float*)d_in[10];
  const float* Wo = (const float*)d_in[11];
  const float* bo = (const float*)d_in[12];
  const float* Wg = (const float*)d_in[13];
  const float* bg = (const float*)d_in[14];
  const float* Wf1 = (const float*)d_in[15];
  const float* bf1 = (const float*)d_in[16];
  const float* Wfg = (const float*)d_in[17];
  const float* bfg = (const float*)d_in[18];
  const float* Wf2 = (const float*)d_in[19];
  const float* bf2 = (const float*)d_in[20];
  const float* ln1_s = (const float*)d_in[21];
  const float* ln1_b = (const float*)d_in[22];
  const float* ln2_s = (const float*)d_in[23];
  const float* ln2_b = (const float*)d_in[24];
  const float* other_W = (const float*)d_in[25];
  const float* other_b = (const float*)d_in[26];
  const float* fW1 = (const float*)d_in[27];
  const float* fb1 = (const float*)d_in[28];
  const float* fln1_s = (const float*)d_in[29];
  const float* fln1_b = (const float*)d_in[30];
  const float* fW2 = (const float*)d_in[31];
  const float* fb2 = (const float*)d_in[32];
  const float* fln2_s = (const float*)d_in[33];
  const float* fln2_b = (const float*)d_in[34];
  const float* fW3 = (const float*)d_in[35];
  const float* fb3 = (const float*)d_in[36];
  float* out = (float*)d_out;

  char* p = (char*)d_ws;
  auto alloc = [&](size_t bytes) { char* r = p; p += (bytes + 255) & ~(size_t)255; return r; };
  float*          X      = (float*)alloc((size_t)8192 * 512 * 4);
  unsigned short* Xb     = (unsigned short*)alloc((size_t)8192 * 512 * 2);
  unsigned short* QKVb   = (unsigned short*)alloc((size_t)8192 * 1536 * 2);  // also CTXo f32
  unsigned short* CTXb   = (unsigned short*)alloc((size_t)8192 * 512 * 2);
  char*           R      = alloc((size_t)8192 * 2048 * 2);  // ATTb|GATEb bf16 / FFBh overlay
  unsigned short* ATTb   = (unsigned short*)R;
  unsigned short* GATEb  = (unsigned short*)(R + (size_t)8192 * 512 * 2);
  unsigned short* FFBh   = (unsigned short*)R;               // [8192][2048] bf16
  float*          CTXo   = (float*)QKVb;
  unsigned short* Wqkvgt = (unsigned short*)alloc((size_t)4 * 2048 * 512 * 2);
  unsigned short* Wot    = (unsigned short*)alloc((size_t)4 * 512 * 512 * 2);
  unsigned short* Wf1t   = (unsigned short*)alloc((size_t)4 * 2048 * 512 * 2);
  unsigned short* Wfgt   = (unsigned short*)alloc((size_t)4 * 2048 * 512 * 2);
  unsigned short* Wf2t   = (unsigned short*)alloc((size_t)4 * 512 * 2048 * 2);
  float*          bqkvg  = (float*)alloc((size_t)4 * 2048 * 4);
  float*          RMb    = (float*)alloc(1024 * 4);
  float*          Hb     = (float*)alloc(16 * 1024 * 4);
  float*          MPP    = (float*)alloc((size_t)16 * 8 * 512 * 4);
  float*          F1P    = (float*)alloc((size_t)16 * 8 * 256 * 4);

  wconv_kernel<<<dim3(16, 16, 4), 256, 0, stream>>>(Wq, Wqkvgt + (size_t)0 * 512, 512, 512,
                                                    (size_t)512 * 512, (size_t)2048 * 512);
  wconv_kernel<<<dim3(16, 16, 4), 256, 0, stream>>>(Wk, Wqkvgt + (size_t)512 * 512, 512, 512,
                                                    (size_t)512 * 512, (size_t)2048 * 512);
  wconv_kernel<<<dim3(16, 16, 4), 256, 0, stream>>>(Wv, Wqkvgt + (size_t)1024 * 512, 512, 512,
                                                    (size_t)512 * 512, (size_t)2048 * 512);
  wconv_kernel<<<dim3(16, 16, 4), 256, 0, stream>>>(Wg, Wqkvgt + (size_t)1536 * 512, 512, 512,
                                                    (size_t)512 * 512, (size_t)2048 * 512);
  wconv_kernel<<<dim3(16, 16, 4), 256, 0, stream>>>(Wo, Wot, 512, 512,
                                                    (size_t)512 * 512, (size_t)512 * 512);
  wconv_kernel<<<dim3(64, 16, 4), 256, 0, stream>>>(Wf1, Wf1t, 512, 2048,
                                                    (size_t)512 * 2048, (size_t)2048 * 512);
  wconv_kernel<<<dim3(64, 16, 4), 256, 0, stream>>>(Wfg, Wfgt, 512, 2048,
                                                    (size_t)512 * 2048, (size_t)2048 * 512);
  wconv_kernel<<<dim3(16, 64, 4), 256, 0, stream>>>(Wf2, Wf2t, 2048, 512,
                                                    (size_t)2048 * 512, (size_t)512 * 2048);
  bcat_kernel<<<dim3(32), 256, 0, stream>>>(bq, bk, bv, bg, bqkvg);

  embed_kernel<<<dim3(16384), dim3(256), 0, stream>>>(x_cgm, cgm_W, cgm_b, X, Xb);
  relmean_kernel<<<dim3(4), dim3(256), 0, stream>>>(rel_emb, RMb);

  for (int l = 0; l < Ln; ++l) {
    const size_t bof = (size_t)l * Dn;
    // fused q|k|v|gate GEMM: N=2048, K=512 (grid 1024, nt=16)
    mgemm<4><<<dim3(1024), 256, 0, stream>>>(Xb, Wqkvgt + (size_t)l * 2048 * 512,
                                             bqkvg + (size_t)l * 2048, nullptr, QKVb, GATEb,
                                             512, 2048, 512, 0, 16);
    attn_kernel<<<dim3(1024), dim3(256), 0, stream>>>(QKVb, RMb, CTXb);
    // Wo: N=512, 128x64 tiles (grid 512, 2 blocks/CU)
    mgemm_n64<3><<<dim3(512), 256, 0, stream>>>(CTXb, Wot + (size_t)l * 512 * 512,
                                                bo + bof, nullptr, ATTb, 512, 512, 512);
    ln_res1_kernel<<<dim3(2048), 256, 0, stream>>>(X, Xb, ATTb, GATEb, ln1_s + bof, ln1_b + bof);
    // fused gated FF: N=2048, K=512 (grid 2048)
    ffgemm<<<dim3(2048), 256, 0, stream>>>(Xb, Wf1t + (size_t)l * 2048 * 512,
                                           Wfgt + (size_t)l * 2048 * 512,
                                           bf1 + (size_t)l * FFn, bfg + (size_t)l * FFn,
                                           FFBh, 512);
    // Wf2: N=512, K=2048 full-K single pass (grid 512, 64 K-iters)
    mgemm_n64<0><<<dim3(512), 256, 0, stream>>>(FFBh, Wf2t + (size_t)l * 512 * 2048,
                                                bf2 + bof, CTXo, nullptr, 2048, 2048, 512);
    ln_res2_kernel<<<dim3(2048), 256, 0, stream>>>(X, Xb, CTXo, ln2_s + bof, ln2_b + bof);
  }

  mp_part_kernel<<<dim3(16, 8), 256, 0, stream>>>(X, MPP);
  mp_comb_xo_kernel<<<dim3(32), 256, 0, stream>>>(MPP, x_other, other_W, other_b, Hb);
  f1a_kernel<<<dim3(16, 8), 256, 0, stream>>>(Hb, fW1, F1P);
  tail_kernel<<<dim3(16), 256, 0, stream>>>(F1P, fb1, fln1_s, fln1_b,
                                            fW2, fb2, fln2_s, fln2_b, fW3, fb3, out);
}